// Round 1
// baseline (3370.279 us; speedup 1.0000x reference)
//
#include <hip/hip_runtime.h>
#include <math.h>

#define NN 20000
#define NE 256000
#define IN_DIM 64
#define HID 128
#define DE 289     // 2*HID + 1 + 32
#define D0 320     // IN_DIM + 2*HID

// ---------------- init: x copy + cnt histogram ----------------
__global__ __launch_bounds__(256) void init_kernel(
    const float* __restrict__ X_t, const int* __restrict__ edges,
    float* __restrict__ x, float* __restrict__ cnt)
{
    int gid = blockIdx.x * blockDim.x + threadIdx.x;
    int stride = gridDim.x * blockDim.x;
    for (int i = gid; i < NN * 3; i += stride) x[i] = X_t[i];
    for (int e = gid; e < NE; e += stride)
        atomicAdd(&cnt[edges[NE + e]], 1.0f);
}

// ---------------- node MLP: h = mlp(feat) ----------------
// 128 threads (thread = output feature), 16 nodes per block.
__global__ __launch_bounds__(128) void node_mlp_kernel(
    const float* __restrict__ H_t, const float* __restrict__ cond,
    const float* __restrict__ t_in,
    const float* __restrict__ W0, const float* __restrict__ b0,
    const float* __restrict__ W1, const float* __restrict__ b1,
    const float* __restrict__ W2, const float* __restrict__ b2,
    float* __restrict__ h)
{
    __shared__ float s_feat[D0][20];   // [k][node], pad 20 keeps float4 16B-aligned
    __shared__ float s_h0[HID][20];
    __shared__ float s_h1[HID][20];
    int n0 = blockIdx.x * 16;
    int tx = threadIdx.x;

    for (int idx = tx; idx < 16 * IN_DIM; idx += 128) {
        int i = idx >> 6, k = idx & 63;
        s_feat[k][i] = H_t[(n0 + i) * IN_DIM + k];
    }
    for (int idx = tx; idx < 16 * HID; idx += 128) {
        int i = idx >> 7, k = idx & 127;
        s_feat[IN_DIM + k][i] = cond[(n0 + i) * HID + k];
    }
    const float cfr = -logf(10000.f) / 63.f;
    for (int idx = tx; idx < 16 * HID; idx += 128) {
        int i = idx >> 7, k = idx & 127;
        float tv = t_in[n0 + i];
        int jj = k & 63;
        float ang = tv * __expf(cfr * (float)jj);
        s_feat[IN_DIM + HID + k][i] = (k < 64) ? __sinf(ang) : __cosf(ang);
    }
    __syncthreads();

    float acc[16];
    // ---- layer 0: K=320, relu ----
    {
        float bv = b0[tx];
        #pragma unroll
        for (int i = 0; i < 16; ++i) acc[i] = bv;
        for (int k = 0; k < D0; ++k) {
            float w = W0[k * HID + tx];
            float4 f0 = *(const float4*)&s_feat[k][0];
            float4 f1 = *(const float4*)&s_feat[k][4];
            float4 f2 = *(const float4*)&s_feat[k][8];
            float4 f3 = *(const float4*)&s_feat[k][12];
            acc[0] += f0.x*w; acc[1] += f0.y*w; acc[2] += f0.z*w; acc[3] += f0.w*w;
            acc[4] += f1.x*w; acc[5] += f1.y*w; acc[6] += f1.z*w; acc[7] += f1.w*w;
            acc[8] += f2.x*w; acc[9] += f2.y*w; acc[10]+= f2.z*w; acc[11]+= f2.w*w;
            acc[12]+= f3.x*w; acc[13]+= f3.y*w; acc[14]+= f3.z*w; acc[15]+= f3.w*w;
        }
        #pragma unroll
        for (int i = 0; i < 16; ++i) s_h0[tx][i] = fmaxf(acc[i], 0.f);
    }
    __syncthreads();
    // ---- layer 1: K=128, relu ----
    {
        float bv = b1[tx];
        #pragma unroll
        for (int i = 0; i < 16; ++i) acc[i] = bv;
        for (int k = 0; k < HID; ++k) {
            float w = W1[k * HID + tx];
            float4 f0 = *(const float4*)&s_h0[k][0];
            float4 f1 = *(const float4*)&s_h0[k][4];
            float4 f2 = *(const float4*)&s_h0[k][8];
            float4 f3 = *(const float4*)&s_h0[k][12];
            acc[0] += f0.x*w; acc[1] += f0.y*w; acc[2] += f0.z*w; acc[3] += f0.w*w;
            acc[4] += f1.x*w; acc[5] += f1.y*w; acc[6] += f1.z*w; acc[7] += f1.w*w;
            acc[8] += f2.x*w; acc[9] += f2.y*w; acc[10]+= f2.z*w; acc[11]+= f2.w*w;
            acc[12]+= f3.x*w; acc[13]+= f3.y*w; acc[14]+= f3.z*w; acc[15]+= f3.w*w;
        }
        #pragma unroll
        for (int i = 0; i < 16; ++i) s_h1[tx][i] = fmaxf(acc[i], 0.f);
    }
    __syncthreads();
    // ---- layer 2: K=128, linear ----
    {
        float bv = b2[tx];
        #pragma unroll
        for (int i = 0; i < 16; ++i) acc[i] = bv;
        for (int k = 0; k < HID; ++k) {
            float w = W2[k * HID + tx];
            float4 f0 = *(const float4*)&s_h1[k][0];
            float4 f1 = *(const float4*)&s_h1[k][4];
            float4 f2 = *(const float4*)&s_h1[k][8];
            float4 f3 = *(const float4*)&s_h1[k][12];
            acc[0] += f0.x*w; acc[1] += f0.y*w; acc[2] += f0.z*w; acc[3] += f0.w*w;
            acc[4] += f1.x*w; acc[5] += f1.y*w; acc[6] += f1.z*w; acc[7] += f1.w*w;
            acc[8] += f2.x*w; acc[9] += f2.y*w; acc[10]+= f2.z*w; acc[11]+= f2.w*w;
            acc[12]+= f3.x*w; acc[13]+= f3.y*w; acc[14]+= f3.z*w; acc[15]+= f3.w*w;
        }
        #pragma unroll
        for (int i = 0; i < 16; ++i) h[(n0 + i) * HID + tx] = acc[i];
    }
}

// ---------------- per-layer edge GEMM + silu + atomic aggregation ----------------
// 256 threads, 64 edges/block. Thread computes 4 edges x 8 features.
#define TILE_E 64
__global__ __launch_bounds__(256) void edge_gemm_kernel(
    const float* __restrict__ h, const float* __restrict__ x,
    const int* __restrict__ edges, const int* __restrict__ etype,
    const float* __restrict__ edge_table,
    const float* __restrict__ We_l, const float* __restrict__ be_l,
    const float* __restrict__ Wx_l, const float* __restrict__ bx_l,
    float* __restrict__ agg_m, float* __restrict__ agg_x)
{
    __shared__ int s_src[TILE_E], s_dst[TILE_E];
    __shared__ float s_diff[TILE_E][3];
    __shared__ float s_tail[TILE_E][36];   // [e][0]=d2, [e][1..32]=eemb
    __shared__ float s_A[TILE_E][36];      // [e][kk] K-tile of m_in
    __shared__ float s_B[33][HID];         // K-tile of We
    __shared__ float s_wx[HID];

    int e0 = blockIdx.x * TILE_E;
    int tx = threadIdx.x;
    int tf = tx & 15;    // feature group: f = tf*8 + j
    int te = tx >> 4;    // edge group:    e = te*4 + i

    if (tx < TILE_E) {
        int s = edges[e0 + tx];
        int d = edges[NE + e0 + tx];
        s_src[tx] = s; s_dst[tx] = d;
        float dx = x[s * 3 + 0] - x[d * 3 + 0];
        float dy = x[s * 3 + 1] - x[d * 3 + 1];
        float dz = x[s * 3 + 2] - x[d * 3 + 2];
        s_diff[tx][0] = dx; s_diff[tx][1] = dy; s_diff[tx][2] = dz;
        s_tail[tx][0] = dx * dx + dy * dy + dz * dz;
        int et = etype[e0 + tx];
        #pragma unroll
        for (int j = 0; j < 32; ++j) s_tail[tx][1 + j] = edge_table[et * 32 + j];
    }
    if (tx < HID) s_wx[tx] = Wx_l[tx];
    __syncthreads();

    float acc[4][8];
    #pragma unroll
    for (int i = 0; i < 4; ++i)
        #pragma unroll
        for (int j = 0; j < 8; ++j) acc[i][j] = 0.f;

    for (int t = 0; t < 9; ++t) {
        int k0 = t * 32;
        int klen = (t == 8) ? 33 : 32;
        __syncthreads();
        if (t < 8) {
            const bool use_src = (t < 4);
            int kbase = (t & 3) * 32;
            for (int q4 = tx; q4 < TILE_E * 8; q4 += 256) {
                int e = q4 >> 3, q = q4 & 7;
                int row = use_src ? s_src[e] : s_dst[e];
                float4 v = *(const float4*)&h[row * HID + kbase + q * 4];
                *(float4*)&s_A[e][q * 4] = v;
            }
        }
        for (int q4 = tx; q4 < klen * 32; q4 += 256) {
            int kk = q4 >> 5, c4 = q4 & 31;
            float4 v = *(const float4*)&We_l[(k0 + kk) * HID + c4 * 4];
            *(float4*)&s_B[kk][c4 * 4] = v;
        }
        __syncthreads();
        const float (*Asrc)[36] = (t == 8) ? (const float (*)[36])s_tail
                                           : (const float (*)[36])s_A;
        for (int kk = 0; kk < klen; ++kk) {
            float a0 = Asrc[te * 4 + 0][kk];
            float a1 = Asrc[te * 4 + 1][kk];
            float a2 = Asrc[te * 4 + 2][kk];
            float a3 = Asrc[te * 4 + 3][kk];
            float4 bv0 = *(const float4*)&s_B[kk][tf * 8];
            float4 bv1 = *(const float4*)&s_B[kk][tf * 8 + 4];
            float b[8] = {bv0.x, bv0.y, bv0.z, bv0.w, bv1.x, bv1.y, bv1.z, bv1.w};
            #pragma unroll
            for (int j = 0; j < 8; ++j) {
                acc[0][j] += a0 * b[j];
                acc[1][j] += a1 * b[j];
                acc[2][j] += a2 * b[j];
                acc[3][j] += a3 * b[j];
            }
        }
    }

    // epilogue: silu, w = msg @ Wx + bx, atomics
    float wsum[4];
    #pragma unroll
    for (int i = 0; i < 4; ++i) {
        float p = 0.f;
        #pragma unroll
        for (int j = 0; j < 8; ++j) {
            int f = tf * 8 + j;
            float v = acc[i][j] + be_l[f];
            float m = v * (1.f / (1.f + __expf(-v)));
            acc[i][j] = m;
            p += m * s_wx[f];
        }
        wsum[i] = p;
    }
    #pragma unroll
    for (int off = 1; off < 16; off <<= 1) {
        #pragma unroll
        for (int i = 0; i < 4; ++i) wsum[i] += __shfl_xor(wsum[i], off);
    }
    float bxv = bx_l[0];
    if (tf < 3) {
        #pragma unroll
        for (int i = 0; i < 4; ++i) {
            int e = te * 4 + i;
            float w = wsum[i] + bxv;
            atomicAdd(&agg_x[s_dst[e] * 3 + tf], s_diff[e][tf] * w);
        }
    }
    #pragma unroll
    for (int i = 0; i < 4; ++i) {
        int d = s_dst[te * 4 + i];
        #pragma unroll
        for (int j = 0; j < 8; ++j)
            atomicAdd(&agg_m[d * HID + tf * 8 + j], acc[i][j]);
    }
}

// ---------------- per-layer node update ----------------
// 128 threads (thread = output feature), 16 nodes/block.
__global__ __launch_bounds__(128) void node_update_kernel(
    float* __restrict__ h, float* __restrict__ x,
    const float* __restrict__ agg_m, const float* __restrict__ agg_x,
    const float* __restrict__ cnt,
    const float* __restrict__ Wh_l, const float* __restrict__ bh_l)
{
    __shared__ float s_in[256][20];  // [k][node]: rows 0..127 = h, 128..255 = agg_m
    int n0 = blockIdx.x * 16;
    int tx = threadIdx.x;
    for (int idx = tx; idx < 16 * HID; idx += 128) {
        int i = idx >> 7, k = idx & 127;
        s_in[k][i] = h[(n0 + i) * HID + k];
    }
    for (int idx = tx; idx < 16 * HID; idx += 128) {
        int i = idx >> 7, k = idx & 127;
        s_in[HID + k][i] = agg_m[(n0 + i) * HID + k];
    }
    __syncthreads();
    float acc[16];
    float bv = bh_l[tx];
    #pragma unroll
    for (int i = 0; i < 16; ++i) acc[i] = bv;
    for (int k = 0; k < 256; ++k) {
        float w = Wh_l[k * HID + tx];
        float4 f0 = *(const float4*)&s_in[k][0];
        float4 f1 = *(const float4*)&s_in[k][4];
        float4 f2 = *(const float4*)&s_in[k][8];
        float4 f3 = *(const float4*)&s_in[k][12];
        acc[0] += f0.x*w; acc[1] += f0.y*w; acc[2] += f0.z*w; acc[3] += f0.w*w;
        acc[4] += f1.x*w; acc[5] += f1.y*w; acc[6] += f1.z*w; acc[7] += f1.w*w;
        acc[8] += f2.x*w; acc[9] += f2.y*w; acc[10]+= f2.z*w; acc[11]+= f2.w*w;
        acc[12]+= f3.x*w; acc[13]+= f3.y*w; acc[14]+= f3.z*w; acc[15]+= f3.w*w;
    }
    #pragma unroll
    for (int i = 0; i < 16; ++i) {
        float v = acc[i];
        float m = v * (1.f / (1.f + __expf(-v)));
        h[(n0 + i) * HID + tx] = s_in[tx][i] + m;   // s_in[tx][i] == old h
    }
    if (tx < 48) {
        int i = tx / 3, c = tx % 3;
        int n = n0 + i;
        x[n * 3 + c] += agg_x[n * 3 + c] / (cnt[n] + 1.f);
    }
}

// ---------------- final: v_H = mask ? h@h2i+b : 0 ; v_X = mask ? x : 0 ----------------
// 64 threads (thread = output feature), 8 nodes/block.
__global__ __launch_bounds__(64) void final_kernel(
    const float* __restrict__ h, const float* __restrict__ x,
    const int* __restrict__ gmask,
    const float* __restrict__ W, const float* __restrict__ b,
    float* __restrict__ out)
{
    __shared__ float s_h[8][HID];
    int n0 = blockIdx.x * 8;
    int tx = threadIdx.x;
    for (int idx = tx; idx < 8 * HID; idx += 64) {
        int i = idx >> 7, k = idx & 127;
        s_h[i][k] = h[(n0 + i) * HID + k];
    }
    __syncthreads();
    float acc[8];
    float bv = b[tx];
    #pragma unroll
    for (int i = 0; i < 8; ++i) acc[i] = bv;
    for (int k = 0; k < HID; ++k) {
        float w = W[k * IN_DIM + tx];
        #pragma unroll
        for (int i = 0; i < 8; ++i) acc[i] += s_h[i][k] * w;
    }
    #pragma unroll
    for (int i = 0; i < 8; ++i) {
        int n = n0 + i;
        out[n * IN_DIM + tx] = gmask[n] ? acc[i] : 0.f;
    }
    if (tx < 24) {
        int i = tx / 3, c = tx % 3;
        int n = n0 + i;
        out[NN * IN_DIM + n * 3 + c] = gmask[n] ? x[n * 3 + c] : 0.f;
    }
}

extern "C" void kernel_launch(void* const* d_in, const int* in_sizes, int n_in,
                              void* d_out, int out_size, void* d_ws, size_t ws_size,
                              hipStream_t stream) {
    const float* H_t   = (const float*)d_in[0];
    const float* X_t   = (const float*)d_in[1];
    const float* cond  = (const float*)d_in[2];
    const float* t_in  = (const float*)d_in[3];
    const int*   edges = (const int*)d_in[4];
    const int*   etype = (const int*)d_in[5];
    const int*   gmask = (const int*)d_in[6];
    // d_in[7] = batch_ids (unused by reference)
    const float* W0 = (const float*)d_in[8];
    const float* b0 = (const float*)d_in[9];
    const float* W1 = (const float*)d_in[10];
    const float* b1 = (const float*)d_in[11];
    const float* W2 = (const float*)d_in[12];
    const float* b2 = (const float*)d_in[13];
    const float* edge_table = (const float*)d_in[14];
    const float* We = (const float*)d_in[15];
    const float* be = (const float*)d_in[16];
    const float* Wx = (const float*)d_in[17];
    const float* bx = (const float*)d_in[18];
    const float* Wh = (const float*)d_in[19];
    const float* bh = (const float*)d_in[20];
    const float* h2i_W = (const float*)d_in[21];
    const float* h2i_b = (const float*)d_in[22];

    float* ws    = (float*)d_ws;
    float* h     = ws;                 // N*128
    float* x     = h + NN * HID;       // N*3
    float* cnt   = x + NN * 3;         // N
    float* agg_m = cnt + NN;           // N*128
    float* agg_x = agg_m + NN * HID;   // N*3

    hipMemsetAsync(cnt, 0, NN * sizeof(float), stream);
    init_kernel<<<256, 256, 0, stream>>>(X_t, edges, x, cnt);
    node_mlp_kernel<<<NN / 16, 128, 0, stream>>>(H_t, cond, t_in,
                                                 W0, b0, W1, b1, W2, b2, h);
    for (int l = 0; l < 3; ++l) {
        hipMemsetAsync(agg_m, 0, (size_t)NN * 131 * sizeof(float), stream);
        edge_gemm_kernel<<<NE / TILE_E, 256, 0, stream>>>(
            h, x, edges, etype, edge_table,
            We + (size_t)l * DE * HID, be + l * HID,
            Wx + l * HID, bx + l, agg_m, agg_x);
        node_update_kernel<<<NN / 16, 128, 0, stream>>>(
            h, x, agg_m, agg_x, cnt,
            Wh + (size_t)l * 256 * HID, bh + l * HID);
    }
    final_kernel<<<NN / 8, 64, 0, stream>>>(h, x, gmask, h2i_W, h2i_b, (float*)d_out);
}

// Round 2
// 1485.001 us; speedup vs baseline: 2.2695x; 2.2695x over previous
//
#include <hip/hip_runtime.h>
#include <math.h>

#define NN 20000
#define NE 256000
#define IN_DIM 64
#define HID 128
#define DE 289     // 2*HID + 1 + 32
#define D0 320     // IN_DIM + 2*HID
#define TILE_E 64

static __device__ __forceinline__ unsigned short f2bf(float f) {
    unsigned int u = __float_as_uint(f);
    u += 0x7fffu + ((u >> 16) & 1u);
    return (unsigned short)(u >> 16);
}
static __device__ __forceinline__ float bf2f(unsigned short s) {
    return __uint_as_float(((unsigned int)s) << 16);
}

// ================= CSR build =================
__global__ __launch_bounds__(256) void hist_kernel(
    const float* __restrict__ X_t, const int* __restrict__ edges,
    float* __restrict__ x, int* __restrict__ deg)
{
    int gid = blockIdx.x * blockDim.x + threadIdx.x;
    int stride = gridDim.x * blockDim.x;
    for (int i = gid; i < NN * 3; i += stride) x[i] = X_t[i];
    for (int e = gid; e < NE; e += stride)
        atomicAdd(&deg[edges[NE + e]], 1);
}

__global__ __launch_bounds__(256) void scan_kernel(
    const int* __restrict__ deg, int* __restrict__ row_start, int* __restrict__ head)
{
    __shared__ int s[256];
    int tx = threadIdx.x;
    const int per = (NN + 255) / 256;
    int st = tx * per, en = st + per;
    if (st > NN) st = NN;
    if (en > NN) en = NN;
    int sum = 0;
    for (int i = st; i < en; ++i) sum += deg[i];
    s[tx] = sum;
    __syncthreads();
    for (int off = 1; off < 256; off <<= 1) {
        int t = (tx >= off) ? s[tx - off] : 0;
        __syncthreads();
        s[tx] += t;
        __syncthreads();
    }
    int run = (tx == 0) ? 0 : s[tx - 1];
    for (int i = st; i < en; ++i) {
        row_start[i] = run; head[i] = run; run += deg[i];
    }
    if (tx == 255) row_start[NN] = run;
}

__global__ __launch_bounds__(256) void scatter_kernel(
    const int* __restrict__ edges, int* __restrict__ head, int* __restrict__ pos)
{
    int gid = blockIdx.x * blockDim.x + threadIdx.x;
    int stride = gridDim.x * blockDim.x;
    for (int e = gid; e < NE; e += stride)
        pos[e] = atomicAdd(&head[edges[NE + e]], 1);
}

// ================= node MLP (h init) =================
__global__ __launch_bounds__(128) void node_mlp_kernel(
    const float* __restrict__ H_t, const float* __restrict__ cond,
    const float* __restrict__ t_in,
    const float* __restrict__ W0, const float* __restrict__ b0,
    const float* __restrict__ W1, const float* __restrict__ b1,
    const float* __restrict__ W2, const float* __restrict__ b2,
    float* __restrict__ h)
{
    __shared__ float s_feat[D0][20];
    __shared__ float s_h0[HID][20];
    __shared__ float s_h1[HID][20];
    int n0 = blockIdx.x * 16;
    int tx = threadIdx.x;

    for (int idx = tx; idx < 16 * IN_DIM; idx += 128) {
        int i = idx >> 6, k = idx & 63;
        s_feat[k][i] = H_t[(n0 + i) * IN_DIM + k];
    }
    for (int idx = tx; idx < 16 * HID; idx += 128) {
        int i = idx >> 7, k = idx & 127;
        s_feat[IN_DIM + k][i] = cond[(n0 + i) * HID + k];
    }
    const float cfr = -logf(10000.f) / 63.f;
    for (int idx = tx; idx < 16 * HID; idx += 128) {
        int i = idx >> 7, k = idx & 127;
        float tv = t_in[n0 + i];
        int jj = k & 63;
        float ang = tv * __expf(cfr * (float)jj);
        s_feat[IN_DIM + HID + k][i] = (k < 64) ? __sinf(ang) : __cosf(ang);
    }
    __syncthreads();

    float acc[16];
    {
        float bv = b0[tx];
        #pragma unroll
        for (int i = 0; i < 16; ++i) acc[i] = bv;
        for (int k = 0; k < D0; ++k) {
            float w = W0[k * HID + tx];
            float4 f0 = *(const float4*)&s_feat[k][0];
            float4 f1 = *(const float4*)&s_feat[k][4];
            float4 f2 = *(const float4*)&s_feat[k][8];
            float4 f3 = *(const float4*)&s_feat[k][12];
            acc[0] += f0.x*w; acc[1] += f0.y*w; acc[2] += f0.z*w; acc[3] += f0.w*w;
            acc[4] += f1.x*w; acc[5] += f1.y*w; acc[6] += f1.z*w; acc[7] += f1.w*w;
            acc[8] += f2.x*w; acc[9] += f2.y*w; acc[10]+= f2.z*w; acc[11]+= f2.w*w;
            acc[12]+= f3.x*w; acc[13]+= f3.y*w; acc[14]+= f3.z*w; acc[15]+= f3.w*w;
        }
        #pragma unroll
        for (int i = 0; i < 16; ++i) s_h0[tx][i] = fmaxf(acc[i], 0.f);
    }
    __syncthreads();
    {
        float bv = b1[tx];
        #pragma unroll
        for (int i = 0; i < 16; ++i) acc[i] = bv;
        for (int k = 0; k < HID; ++k) {
            float w = W1[k * HID + tx];
            float4 f0 = *(const float4*)&s_h0[k][0];
            float4 f1 = *(const float4*)&s_h0[k][4];
            float4 f2 = *(const float4*)&s_h0[k][8];
            float4 f3 = *(const float4*)&s_h0[k][12];
            acc[0] += f0.x*w; acc[1] += f0.y*w; acc[2] += f0.z*w; acc[3] += f0.w*w;
            acc[4] += f1.x*w; acc[5] += f1.y*w; acc[6] += f1.z*w; acc[7] += f1.w*w;
            acc[8] += f2.x*w; acc[9] += f2.y*w; acc[10]+= f2.z*w; acc[11]+= f2.w*w;
            acc[12]+= f3.x*w; acc[13]+= f3.y*w; acc[14]+= f3.z*w; acc[15]+= f3.w*w;
        }
        #pragma unroll
        for (int i = 0; i < 16; ++i) s_h1[tx][i] = fmaxf(acc[i], 0.f);
    }
    __syncthreads();
    {
        float bv = b2[tx];
        #pragma unroll
        for (int i = 0; i < 16; ++i) acc[i] = bv;
        for (int k = 0; k < HID; ++k) {
            float w = W2[k * HID + tx];
            float4 f0 = *(const float4*)&s_h1[k][0];
            float4 f1 = *(const float4*)&s_h1[k][4];
            float4 f2 = *(const float4*)&s_h1[k][8];
            float4 f3 = *(const float4*)&s_h1[k][12];
            acc[0] += f0.x*w; acc[1] += f0.y*w; acc[2] += f0.z*w; acc[3] += f0.w*w;
            acc[4] += f1.x*w; acc[5] += f1.y*w; acc[6] += f1.z*w; acc[7] += f1.w*w;
            acc[8] += f2.x*w; acc[9] += f2.y*w; acc[10]+= f2.z*w; acc[11]+= f2.w*w;
            acc[12]+= f3.x*w; acc[13]+= f3.y*w; acc[14]+= f3.z*w; acc[15]+= f3.w*w;
        }
        #pragma unroll
        for (int i = 0; i < 16; ++i) h[(n0 + i) * HID + tx] = acc[i];
    }
}

// ================= edge GEMM (CSR output, no atomics) =================
__global__ __launch_bounds__(256) void edge_gemm_kernel(
    const float* __restrict__ h, const float* __restrict__ x,
    const int* __restrict__ edges, const int* __restrict__ etype,
    const float* __restrict__ edge_table,
    const float* __restrict__ We_l, const float* __restrict__ be_l,
    const float* __restrict__ Wx_l, const float* __restrict__ bx_l,
    const int* __restrict__ pos,
    unsigned short* __restrict__ msg, float* __restrict__ wdiff)
{
    __shared__ int s_src[TILE_E], s_dst[TILE_E], s_pos[TILE_E];
    __shared__ float s_diff[TILE_E][3];
    __shared__ float s_tail[TILE_E][36];
    __shared__ float s_A[TILE_E][36];
    __shared__ float s_B[33][HID];
    __shared__ float s_wx[HID];

    int e0 = blockIdx.x * TILE_E;
    int tx = threadIdx.x;
    int tf = tx & 15;
    int te = tx >> 4;

    if (tx < TILE_E) {
        int s = edges[e0 + tx];
        int d = edges[NE + e0 + tx];
        s_src[tx] = s; s_dst[tx] = d;
        s_pos[tx] = pos[e0 + tx];
        float dx = x[s * 3 + 0] - x[d * 3 + 0];
        float dy = x[s * 3 + 1] - x[d * 3 + 1];
        float dz = x[s * 3 + 2] - x[d * 3 + 2];
        s_diff[tx][0] = dx; s_diff[tx][1] = dy; s_diff[tx][2] = dz;
        s_tail[tx][0] = dx * dx + dy * dy + dz * dz;
        int et = etype[e0 + tx];
        #pragma unroll
        for (int j = 0; j < 32; ++j) s_tail[tx][1 + j] = edge_table[et * 32 + j];
    }
    if (tx < HID) s_wx[tx] = Wx_l[tx];
    __syncthreads();

    float acc[4][8];
    #pragma unroll
    for (int i = 0; i < 4; ++i)
        #pragma unroll
        for (int j = 0; j < 8; ++j) acc[i][j] = 0.f;

    for (int t = 0; t < 9; ++t) {
        int k0 = t * 32;
        int klen = (t == 8) ? 33 : 32;
        __syncthreads();
        if (t < 8) {
            const bool use_src = (t < 4);
            int kbase = (t & 3) * 32;
            for (int q4 = tx; q4 < TILE_E * 8; q4 += 256) {
                int e = q4 >> 3, q = q4 & 7;
                int row = use_src ? s_src[e] : s_dst[e];
                float4 v = *(const float4*)&h[row * HID + kbase + q * 4];
                *(float4*)&s_A[e][q * 4] = v;
            }
        }
        for (int q4 = tx; q4 < klen * 32; q4 += 256) {
            int kk = q4 >> 5, c4 = q4 & 31;
            float4 v = *(const float4*)&We_l[(k0 + kk) * HID + c4 * 4];
            *(float4*)&s_B[kk][c4 * 4] = v;
        }
        __syncthreads();
        const float (*Asrc)[36] = (t == 8) ? (const float (*)[36])s_tail
                                           : (const float (*)[36])s_A;
        for (int kk = 0; kk < klen; ++kk) {
            float a0 = Asrc[te * 4 + 0][kk];
            float a1 = Asrc[te * 4 + 1][kk];
            float a2 = Asrc[te * 4 + 2][kk];
            float a3 = Asrc[te * 4 + 3][kk];
            float4 bv0 = *(const float4*)&s_B[kk][tf * 8];
            float4 bv1 = *(const float4*)&s_B[kk][tf * 8 + 4];
            float b[8] = {bv0.x, bv0.y, bv0.z, bv0.w, bv1.x, bv1.y, bv1.z, bv1.w};
            #pragma unroll
            for (int j = 0; j < 8; ++j) {
                acc[0][j] += a0 * b[j];
                acc[1][j] += a1 * b[j];
                acc[2][j] += a2 * b[j];
                acc[3][j] += a3 * b[j];
            }
        }
    }

    // epilogue: silu, w = msg @ Wx + bx, sorted stores
    float wsum[4];
    #pragma unroll
    for (int i = 0; i < 4; ++i) {
        float p = 0.f;
        #pragma unroll
        for (int j = 0; j < 8; ++j) {
            int f = tf * 8 + j;
            float v = acc[i][j] + be_l[f];
            float m = v * (1.f / (1.f + __expf(-v)));
            acc[i][j] = m;
            p += m * s_wx[f];
        }
        wsum[i] = p;
    }
    #pragma unroll
    for (int off = 1; off < 16; off <<= 1) {
        #pragma unroll
        for (int i = 0; i < 4; ++i) wsum[i] += __shfl_xor(wsum[i], off);
    }
    #pragma unroll
    for (int i = 0; i < 4; ++i) {
        int e = te * 4 + i;
        int p = s_pos[e];
        unsigned int pk0 = (unsigned int)f2bf(acc[i][0]) | ((unsigned int)f2bf(acc[i][1]) << 16);
        unsigned int pk1 = (unsigned int)f2bf(acc[i][2]) | ((unsigned int)f2bf(acc[i][3]) << 16);
        unsigned int pk2 = (unsigned int)f2bf(acc[i][4]) | ((unsigned int)f2bf(acc[i][5]) << 16);
        unsigned int pk3 = (unsigned int)f2bf(acc[i][6]) | ((unsigned int)f2bf(acc[i][7]) << 16);
        uint4 pk = make_uint4(pk0, pk1, pk2, pk3);
        *(uint4*)&msg[(size_t)p * HID + tf * 8] = pk;
    }
    float bxv = bx_l[0];
    if (tf < 3) {
        #pragma unroll
        for (int i = 0; i < 4; ++i) {
            int e = te * 4 + i;
            float w = wsum[i] + bxv;
            wdiff[s_pos[e] * 4 + tf] = s_diff[e][tf] * w;
        }
    }
}

// ================= node update (fused CSR aggregation + Wh GEMM) =================
__global__ __launch_bounds__(128) void node_update_kernel(
    float* __restrict__ h, float* __restrict__ x,
    const unsigned short* __restrict__ msg, const float* __restrict__ wdiff,
    const int* __restrict__ row_start,
    const float* __restrict__ Wh_l, const float* __restrict__ bh_l)
{
    __shared__ float s_in[256][20];  // rows 0..127 = h, 128..255 = agg_m
    __shared__ int s_rs[17];
    int n0 = blockIdx.x * 16;
    int tx = threadIdx.x;
    if (tx < 17) s_rs[tx] = row_start[n0 + tx];
    for (int idx = tx; idx < 16 * HID; idx += 128) {
        int i = idx >> 7, k = idx & 127;
        s_in[k][i] = h[(n0 + i) * HID + k];
    }
    __syncthreads();
    for (int i = 0; i < 16; ++i) {
        int rs = s_rs[i], re = s_rs[i + 1];
        float a = 0.f;
        for (int j = rs; j < re; ++j) a += bf2f(msg[(size_t)j * HID + tx]);
        s_in[HID + tx][i] = a;
    }
    if (tx < 48) {
        int i = tx / 3, c = tx % 3, n = n0 + i;
        int rs = s_rs[i], re = s_rs[i + 1];
        float sxx = 0.f;
        for (int j = rs; j < re; ++j) sxx += wdiff[j * 4 + c];
        x[n * 3 + c] += sxx / ((float)(re - rs) + 1.f);
    }
    __syncthreads();
    float acc[16];
    float bv = bh_l[tx];
    #pragma unroll
    for (int i = 0; i < 16; ++i) acc[i] = bv;
    for (int k = 0; k < 256; ++k) {
        float w = Wh_l[k * HID + tx];
        float4 f0 = *(const float4*)&s_in[k][0];
        float4 f1 = *(const float4*)&s_in[k][4];
        float4 f2 = *(const float4*)&s_in[k][8];
        float4 f3 = *(const float4*)&s_in[k][12];
        acc[0] += f0.x*w; acc[1] += f0.y*w; acc[2] += f0.z*w; acc[3] += f0.w*w;
        acc[4] += f1.x*w; acc[5] += f1.y*w; acc[6] += f1.z*w; acc[7] += f1.w*w;
        acc[8] += f2.x*w; acc[9] += f2.y*w; acc[10]+= f2.z*w; acc[11]+= f2.w*w;
        acc[12]+= f3.x*w; acc[13]+= f3.y*w; acc[14]+= f3.z*w; acc[15]+= f3.w*w;
    }
    #pragma unroll
    for (int i = 0; i < 16; ++i) {
        float v = acc[i];
        float m = v * (1.f / (1.f + __expf(-v)));
        h[(n0 + i) * HID + tx] = s_in[tx][i] + m;
    }
}

// ================= final =================
__global__ __launch_bounds__(64) void final_kernel(
    const float* __restrict__ h, const float* __restrict__ x,
    const int* __restrict__ gmask,
    const float* __restrict__ W, const float* __restrict__ b,
    float* __restrict__ out)
{
    __shared__ float s_h[8][HID];
    int n0 = blockIdx.x * 8;
    int tx = threadIdx.x;
    for (int idx = tx; idx < 8 * HID; idx += 64) {
        int i = idx >> 7, k = idx & 127;
        s_h[i][k] = h[(n0 + i) * HID + k];
    }
    __syncthreads();
    float acc[8];
    float bv = b[tx];
    #pragma unroll
    for (int i = 0; i < 8; ++i) acc[i] = bv;
    for (int k = 0; k < HID; ++k) {
        float w = W[k * IN_DIM + tx];
        #pragma unroll
        for (int i = 0; i < 8; ++i) acc[i] += s_h[i][k] * w;
    }
    #pragma unroll
    for (int i = 0; i < 8; ++i) {
        int n = n0 + i;
        out[n * IN_DIM + tx] = gmask[n] ? acc[i] : 0.f;
    }
    if (tx < 24) {
        int i = tx / 3, c = tx % 3;
        int n = n0 + i;
        out[NN * IN_DIM + n * 3 + c] = gmask[n] ? x[n * 3 + c] : 0.f;
    }
}

// ================= fallback path (round-1 atomic version) =================
__global__ __launch_bounds__(256) void init_fb_kernel(
    const float* __restrict__ X_t, const int* __restrict__ edges,
    float* __restrict__ x, float* __restrict__ cnt)
{
    int gid = blockIdx.x * blockDim.x + threadIdx.x;
    int stride = gridDim.x * blockDim.x;
    for (int i = gid; i < NN * 3; i += stride) x[i] = X_t[i];
    for (int e = gid; e < NE; e += stride)
        atomicAdd(&cnt[edges[NE + e]], 1.0f);
}

__global__ __launch_bounds__(256) void edge_gemm_fb_kernel(
    const float* __restrict__ h, const float* __restrict__ x,
    const int* __restrict__ edges, const int* __restrict__ etype,
    const float* __restrict__ edge_table,
    const float* __restrict__ We_l, const float* __restrict__ be_l,
    const float* __restrict__ Wx_l, const float* __restrict__ bx_l,
    float* __restrict__ agg_m, float* __restrict__ agg_x)
{
    __shared__ int s_src[TILE_E], s_dst[TILE_E];
    __shared__ float s_diff[TILE_E][3];
    __shared__ float s_tail[TILE_E][36];
    __shared__ float s_A[TILE_E][36];
    __shared__ float s_B[33][HID];
    __shared__ float s_wx[HID];

    int e0 = blockIdx.x * TILE_E;
    int tx = threadIdx.x;
    int tf = tx & 15;
    int te = tx >> 4;

    if (tx < TILE_E) {
        int s = edges[e0 + tx];
        int d = edges[NE + e0 + tx];
        s_src[tx] = s; s_dst[tx] = d;
        float dx = x[s * 3 + 0] - x[d * 3 + 0];
        float dy = x[s * 3 + 1] - x[d * 3 + 1];
        float dz = x[s * 3 + 2] - x[d * 3 + 2];
        s_diff[tx][0] = dx; s_diff[tx][1] = dy; s_diff[tx][2] = dz;
        s_tail[tx][0] = dx * dx + dy * dy + dz * dz;
        int et = etype[e0 + tx];
        #pragma unroll
        for (int j = 0; j < 32; ++j) s_tail[tx][1 + j] = edge_table[et * 32 + j];
    }
    if (tx < HID) s_wx[tx] = Wx_l[tx];
    __syncthreads();

    float acc[4][8];
    #pragma unroll
    for (int i = 0; i < 4; ++i)
        #pragma unroll
        for (int j = 0; j < 8; ++j) acc[i][j] = 0.f;

    for (int t = 0; t < 9; ++t) {
        int k0 = t * 32;
        int klen = (t == 8) ? 33 : 32;
        __syncthreads();
        if (t < 8) {
            const bool use_src = (t < 4);
            int kbase = (t & 3) * 32;
            for (int q4 = tx; q4 < TILE_E * 8; q4 += 256) {
                int e = q4 >> 3, q = q4 & 7;
                int row = use_src ? s_src[e] : s_dst[e];
                float4 v = *(const float4*)&h[row * HID + kbase + q * 4];
                *(float4*)&s_A[e][q * 4] = v;
            }
        }
        for (int q4 = tx; q4 < klen * 32; q4 += 256) {
            int kk = q4 >> 5, c4 = q4 & 31;
            float4 v = *(const float4*)&We_l[(k0 + kk) * HID + c4 * 4];
            *(float4*)&s_B[kk][c4 * 4] = v;
        }
        __syncthreads();
        const float (*Asrc)[36] = (t == 8) ? (const float (*)[36])s_tail
                                           : (const float (*)[36])s_A;
        for (int kk = 0; kk < klen; ++kk) {
            float a0 = Asrc[te * 4 + 0][kk];
            float a1 = Asrc[te * 4 + 1][kk];
            float a2 = Asrc[te * 4 + 2][kk];
            float a3 = Asrc[te * 4 + 3][kk];
            float4 bv0 = *(const float4*)&s_B[kk][tf * 8];
            float4 bv1 = *(const float4*)&s_B[kk][tf * 8 + 4];
            float b[8] = {bv0.x, bv0.y, bv0.z, bv0.w, bv1.x, bv1.y, bv1.z, bv1.w};
            #pragma unroll
            for (int j = 0; j < 8; ++j) {
                acc[0][j] += a0 * b[j];
                acc[1][j] += a1 * b[j];
                acc[2][j] += a2 * b[j];
                acc[3][j] += a3 * b[j];
            }
        }
    }

    float wsum[4];
    #pragma unroll
    for (int i = 0; i < 4; ++i) {
        float p = 0.f;
        #pragma unroll
        for (int j = 0; j < 8; ++j) {
            int f = tf * 8 + j;
            float v = acc[i][j] + be_l[f];
            float m = v * (1.f / (1.f + __expf(-v)));
            acc[i][j] = m;
            p += m * s_wx[f];
        }
        wsum[i] = p;
    }
    #pragma unroll
    for (int off = 1; off < 16; off <<= 1) {
        #pragma unroll
        for (int i = 0; i < 4; ++i) wsum[i] += __shfl_xor(wsum[i], off);
    }
    float bxv = bx_l[0];
    if (tf < 3) {
        #pragma unroll
        for (int i = 0; i < 4; ++i) {
            int e = te * 4 + i;
            float w = wsum[i] + bxv;
            atomicAdd(&agg_x[s_dst[e] * 3 + tf], s_diff[e][tf] * w);
        }
    }
    #pragma unroll
    for (int i = 0; i < 4; ++i) {
        int d = s_dst[te * 4 + i];
        #pragma unroll
        for (int j = 0; j < 8; ++j)
            atomicAdd(&agg_m[d * HID + tf * 8 + j], acc[i][j]);
    }
}

__global__ __launch_bounds__(128) void node_update_fb_kernel(
    float* __restrict__ h, float* __restrict__ x,
    const float* __restrict__ agg_m, const float* __restrict__ agg_x,
    const float* __restrict__ cnt,
    const float* __restrict__ Wh_l, const float* __restrict__ bh_l)
{
    __shared__ float s_in[256][20];
    int n0 = blockIdx.x * 16;
    int tx = threadIdx.x;
    for (int idx = tx; idx < 16 * HID; idx += 128) {
        int i = idx >> 7, k = idx & 127;
        s_in[k][i] = h[(n0 + i) * HID + k];
    }
    for (int idx = tx; idx < 16 * HID; idx += 128) {
        int i = idx >> 7, k = idx & 127;
        s_in[HID + k][i] = agg_m[(n0 + i) * HID + k];
    }
    __syncthreads();
    float acc[16];
    float bv = bh_l[tx];
    #pragma unroll
    for (int i = 0; i < 16; ++i) acc[i] = bv;
    for (int k = 0; k < 256; ++k) {
        float w = Wh_l[k * HID + tx];
        float4 f0 = *(const float4*)&s_in[k][0];
        float4 f1 = *(const float4*)&s_in[k][4];
        float4 f2 = *(const float4*)&s_in[k][8];
        float4 f3 = *(const float4*)&s_in[k][12];
        acc[0] += f0.x*w; acc[1] += f0.y*w; acc[2] += f0.z*w; acc[3] += f0.w*w;
        acc[4] += f1.x*w; acc[5] += f1.y*w; acc[6] += f1.z*w; acc[7] += f1.w*w;
        acc[8] += f2.x*w; acc[9] += f2.y*w; acc[10]+= f2.z*w; acc[11]+= f2.w*w;
        acc[12]+= f3.x*w; acc[13]+= f3.y*w; acc[14]+= f3.z*w; acc[15]+= f3.w*w;
    }
    #pragma unroll
    for (int i = 0; i < 16; ++i) {
        float v = acc[i];
        float m = v * (1.f / (1.f + __expf(-v)));
        h[(n0 + i) * HID + tx] = s_in[tx][i] + m;
    }
    if (tx < 48) {
        int i = tx / 3, c = tx % 3;
        int n = n0 + i;
        x[n * 3 + c] += agg_x[n * 3 + c] / (cnt[n] + 1.f);
    }
}

extern "C" void kernel_launch(void* const* d_in, const int* in_sizes, int n_in,
                              void* d_out, int out_size, void* d_ws, size_t ws_size,
                              hipStream_t stream) {
    const float* H_t   = (const float*)d_in[0];
    const float* X_t   = (const float*)d_in[1];
    const float* cond  = (const float*)d_in[2];
    const float* t_in  = (const float*)d_in[3];
    const int*   edges = (const int*)d_in[4];
    const int*   etype = (const int*)d_in[5];
    const int*   gmask = (const int*)d_in[6];
    const float* W0 = (const float*)d_in[8];
    const float* b0 = (const float*)d_in[9];
    const float* W1 = (const float*)d_in[10];
    const float* b1 = (const float*)d_in[11];
    const float* W2 = (const float*)d_in[12];
    const float* b2 = (const float*)d_in[13];
    const float* edge_table = (const float*)d_in[14];
    const float* We = (const float*)d_in[15];
    const float* be = (const float*)d_in[16];
    const float* Wx = (const float*)d_in[17];
    const float* bx = (const float*)d_in[18];
    const float* Wh = (const float*)d_in[19];
    const float* bh = (const float*)d_in[20];
    const float* h2i_W = (const float*)d_in[21];
    const float* h2i_b = (const float*)d_in[22];

    // primary workspace layout
    char* p = (char*)d_ws;
    float* h = (float*)p;                      p += (size_t)NN * HID * 4;
    float* x = (float*)p;                      p += (size_t)NN * 3 * 4;
    float* wdiff = (float*)p;                  p += (size_t)NE * 4 * 4;
    unsigned short* msg = (unsigned short*)p;  p += (size_t)NE * HID * 2;
    int* row_start = (int*)p;                  p += (size_t)(NN + 1) * 4;
    int* deg = (int*)p;                        p += (size_t)NN * 4;
    int* head = (int*)p;                       p += (size_t)NN * 4;
    int* pos = (int*)p;                        p += (size_t)NE * 4;
    size_t need = (size_t)(p - (char*)d_ws);

    if (ws_size >= need) {
        hipMemsetAsync(deg, 0, NN * sizeof(int), stream);
        hist_kernel<<<256, 256, 0, stream>>>(X_t, edges, x, deg);
        scan_kernel<<<1, 256, 0, stream>>>(deg, row_start, head);
        scatter_kernel<<<256, 256, 0, stream>>>(edges, head, pos);
        node_mlp_kernel<<<NN / 16, 128, 0, stream>>>(H_t, cond, t_in,
                                                     W0, b0, W1, b1, W2, b2, h);
        for (int l = 0; l < 3; ++l) {
            edge_gemm_kernel<<<NE / TILE_E, 256, 0, stream>>>(
                h, x, edges, etype, edge_table,
                We + (size_t)l * DE * HID, be + l * HID,
                Wx + l * HID, bx + l, pos, msg, wdiff);
            node_update_kernel<<<NN / 16, 128, 0, stream>>>(
                h, x, msg, wdiff, row_start,
                Wh + (size_t)l * 256 * HID, bh + l * HID);
        }
        final_kernel<<<NN / 8, 64, 0, stream>>>(h, x, gmask, h2i_W, h2i_b, (float*)d_out);
    } else {
        // fallback: round-1 atomic path (~21.4 MB)
        float* ws    = (float*)d_ws;
        float* fh    = ws;
        float* fx    = fh + NN * HID;
        float* cnt   = fx + NN * 3;
        float* agg_m = cnt + NN;
        float* agg_x = agg_m + NN * HID;

        hipMemsetAsync(cnt, 0, NN * sizeof(float), stream);
        init_fb_kernel<<<256, 256, 0, stream>>>(X_t, edges, fx, cnt);
        node_mlp_kernel<<<NN / 16, 128, 0, stream>>>(H_t, cond, t_in,
                                                     W0, b0, W1, b1, W2, b2, fh);
        for (int l = 0; l < 3; ++l) {
            hipMemsetAsync(agg_m, 0, (size_t)NN * 131 * sizeof(float), stream);
            edge_gemm_fb_kernel<<<NE / TILE_E, 256, 0, stream>>>(
                fh, fx, edges, etype, edge_table,
                We + (size_t)l * DE * HID, be + l * HID,
                Wx + l * HID, bx + l, agg_m, agg_x);
            node_update_fb_kernel<<<NN / 16, 128, 0, stream>>>(
                fh, fx, agg_m, agg_x, cnt,
                Wh + (size_t)l * 256 * HID, bh + l * HID);
        }
        final_kernel<<<NN / 8, 64, 0, stream>>>(fh, fx, gmask, h2i_W, h2i_b, (float*)d_out);
    }
}

// Round 3
// 631.991 us; speedup vs baseline: 5.3328x; 2.3497x over previous
//
#include <hip/hip_runtime.h>
#include <math.h>

#define NN 20000
#define NE 256000
#define IN_DIM 64
#define HID 128
#define DE 289     // 2*HID + 1 + 32
#define D0 320     // IN_DIM + 2*HID
#define KPAD 320   // DE padded to 5 K-tiles of 64
#define TILE_E 64

typedef unsigned short u16;
typedef __attribute__((ext_vector_type(8))) short short8;
typedef __attribute__((ext_vector_type(4))) float float4v;

static __device__ __forceinline__ u16 f2bf(float f) {
    unsigned int u = __float_as_uint(f);
    u += 0x7fffu + ((u >> 16) & 1u);
    return (u16)(u >> 16);
}
static __device__ __forceinline__ float bf2f(u16 s) {
    return __uint_as_float(((unsigned int)s) << 16);
}

// ================= CSR build =================
__global__ __launch_bounds__(256) void hist_kernel(
    const float* __restrict__ X_t, const int* __restrict__ edges,
    float* __restrict__ x, int* __restrict__ deg)
{
    int gid = blockIdx.x * blockDim.x + threadIdx.x;
    int stride = gridDim.x * blockDim.x;
    for (int i = gid; i < NN * 3; i += stride) x[i] = X_t[i];
    for (int e = gid; e < NE; e += stride)
        atomicAdd(&deg[edges[NE + e]], 1);
}

__global__ __launch_bounds__(256) void scan_kernel(
    const int* __restrict__ deg, int* __restrict__ row_start, int* __restrict__ head)
{
    __shared__ int s[256];
    int tx = threadIdx.x;
    const int per = (NN + 255) / 256;
    int st = tx * per, en = st + per;
    if (st > NN) st = NN;
    if (en > NN) en = NN;
    int sum = 0;
    for (int i = st; i < en; ++i) sum += deg[i];
    s[tx] = sum;
    __syncthreads();
    for (int off = 1; off < 256; off <<= 1) {
        int t = (tx >= off) ? s[tx - off] : 0;
        __syncthreads();
        s[tx] += t;
        __syncthreads();
    }
    int run = (tx == 0) ? 0 : s[tx - 1];
    for (int i = st; i < en; ++i) {
        row_start[i] = run; head[i] = run; run += deg[i];
    }
    if (tx == 255) row_start[NN] = run;
}

__global__ __launch_bounds__(256) void scatter_kernel(
    const int* __restrict__ edges, int* __restrict__ head, int* __restrict__ pos)
{
    int gid = blockIdx.x * blockDim.x + threadIdx.x;
    int stride = gridDim.x * blockDim.x;
    for (int e = gid; e < NE; e += stride)
        pos[e] = atomicAdd(&head[edges[NE + e]], 1);
}

// ================= We fragment-order packing (once per call) =================
// Bpack[layer][ks][nt][lane][j] = bf16(We[layer][ks*32+(lane>>4)*8+j][nt*16+(lane&15)])
// ks in 0..9, nt in 0..7, lane in 0..63, j in 0..7 ; zero-padded past k=288.
__global__ __launch_bounds__(256) void pack_we_kernel(
    const float* __restrict__ We, u16* __restrict__ Bpack)
{
    int idx = blockIdx.x * 256 + threadIdx.x;   // 3*40960 total
    int layer = idx / 40960;
    int r = idx - layer * 40960;
    int j = r & 7, lane = (r >> 3) & 63, nt = (r >> 9) & 7, ks = r >> 12;
    int k = ks * 32 + ((lane >> 4) * 8) + j;
    int c = nt * 16 + (lane & 15);
    float v = (k < DE) ? We[(size_t)layer * DE * HID + (size_t)k * HID + c] : 0.f;
    Bpack[idx] = f2bf(v);
}

// ================= node MLP (h init, + bf16 mirror) =================
__global__ __launch_bounds__(128) void node_mlp_kernel(
    const float* __restrict__ H_t, const float* __restrict__ cond,
    const float* __restrict__ t_in,
    const float* __restrict__ W0, const float* __restrict__ b0,
    const float* __restrict__ W1, const float* __restrict__ b1,
    const float* __restrict__ W2, const float* __restrict__ b2,
    float* __restrict__ h, u16* __restrict__ h_bf)
{
    __shared__ float s_feat[D0][20];
    __shared__ float s_h0[HID][20];
    __shared__ float s_h1[HID][20];
    int n0 = blockIdx.x * 16;
    int tx = threadIdx.x;

    for (int idx = tx; idx < 16 * IN_DIM; idx += 128) {
        int i = idx >> 6, k = idx & 63;
        s_feat[k][i] = H_t[(n0 + i) * IN_DIM + k];
    }
    for (int idx = tx; idx < 16 * HID; idx += 128) {
        int i = idx >> 7, k = idx & 127;
        s_feat[IN_DIM + k][i] = cond[(n0 + i) * HID + k];
    }
    const float cfr = -logf(10000.f) / 63.f;
    for (int idx = tx; idx < 16 * HID; idx += 128) {
        int i = idx >> 7, k = idx & 127;
        float tv = t_in[n0 + i];
        int jj = k & 63;
        float ang = tv * __expf(cfr * (float)jj);
        s_feat[IN_DIM + HID + k][i] = (k < 64) ? __sinf(ang) : __cosf(ang);
    }
    __syncthreads();

    float acc[16];
    {
        float bv = b0[tx];
        #pragma unroll
        for (int i = 0; i < 16; ++i) acc[i] = bv;
        for (int k = 0; k < D0; ++k) {
            float w = W0[k * HID + tx];
            float4 f0 = *(const float4*)&s_feat[k][0];
            float4 f1 = *(const float4*)&s_feat[k][4];
            float4 f2 = *(const float4*)&s_feat[k][8];
            float4 f3 = *(const float4*)&s_feat[k][12];
            acc[0] += f0.x*w; acc[1] += f0.y*w; acc[2] += f0.z*w; acc[3] += f0.w*w;
            acc[4] += f1.x*w; acc[5] += f1.y*w; acc[6] += f1.z*w; acc[7] += f1.w*w;
            acc[8] += f2.x*w; acc[9] += f2.y*w; acc[10]+= f2.z*w; acc[11]+= f2.w*w;
            acc[12]+= f3.x*w; acc[13]+= f3.y*w; acc[14]+= f3.z*w; acc[15]+= f3.w*w;
        }
        #pragma unroll
        for (int i = 0; i < 16; ++i) s_h0[tx][i] = fmaxf(acc[i], 0.f);
    }
    __syncthreads();
    {
        float bv = b1[tx];
        #pragma unroll
        for (int i = 0; i < 16; ++i) acc[i] = bv;
        for (int k = 0; k < HID; ++k) {
            float w = W1[k * HID + tx];
            float4 f0 = *(const float4*)&s_h0[k][0];
            float4 f1 = *(const float4*)&s_h0[k][4];
            float4 f2 = *(const float4*)&s_h0[k][8];
            float4 f3 = *(const float4*)&s_h0[k][12];
            acc[0] += f0.x*w; acc[1] += f0.y*w; acc[2] += f0.z*w; acc[3] += f0.w*w;
            acc[4] += f1.x*w; acc[5] += f1.y*w; acc[6] += f1.z*w; acc[7] += f1.w*w;
            acc[8] += f2.x*w; acc[9] += f2.y*w; acc[10]+= f2.z*w; acc[11]+= f2.w*w;
            acc[12]+= f3.x*w; acc[13]+= f3.y*w; acc[14]+= f3.z*w; acc[15]+= f3.w*w;
        }
        #pragma unroll
        for (int i = 0; i < 16; ++i) s_h1[tx][i] = fmaxf(acc[i], 0.f);
    }
    __syncthreads();
    {
        float bv = b2[tx];
        #pragma unroll
        for (int i = 0; i < 16; ++i) acc[i] = bv;
        for (int k = 0; k < HID; ++k) {
            float w = W2[k * HID + tx];
            float4 f0 = *(const float4*)&s_h1[k][0];
            float4 f1 = *(const float4*)&s_h1[k][4];
            float4 f2 = *(const float4*)&s_h1[k][8];
            float4 f3 = *(const float4*)&s_h1[k][12];
            acc[0] += f0.x*w; acc[1] += f0.y*w; acc[2] += f0.z*w; acc[3] += f0.w*w;
            acc[4] += f1.x*w; acc[5] += f1.y*w; acc[6] += f1.z*w; acc[7] += f1.w*w;
            acc[8] += f2.x*w; acc[9] += f2.y*w; acc[10]+= f2.z*w; acc[11]+= f2.w*w;
            acc[12]+= f3.x*w; acc[13]+= f3.y*w; acc[14]+= f3.z*w; acc[15]+= f3.w*w;
        }
        #pragma unroll
        for (int i = 0; i < 16; ++i) {
            h[(n0 + i) * HID + tx] = acc[i];
            h_bf[(n0 + i) * HID + tx] = f2bf(acc[i]);
        }
    }
}

// ================= edge MFMA GEMM (bf16) =================
// 64 edges x 128 feats per block; 4 waves, each 2 M-tiles x 4 N-tiles of 16x16.
// A-frag (16x16x32 bf16): lane holds A[m=lane&15][k=(lane>>4)*8+j]
// B-frag:                  lane holds B[k=(lane>>4)*8+j][n=lane&15]
// C/D:                     col=lane&15, row=(lane>>4)*4+reg   [m89]
__global__ __launch_bounds__(256) void edge_mfma_kernel(
    const u16* __restrict__ h_bf, const float* __restrict__ x,
    const int* __restrict__ edges, const int* __restrict__ etype,
    const float* __restrict__ edge_table,
    const u16* __restrict__ Bpack_l, const float* __restrict__ be_l,
    const float* __restrict__ Wx_l, const float* __restrict__ bx_l,
    const int* __restrict__ pos,
    u16* __restrict__ msg, float* __restrict__ wdiff)
{
    __shared__ u16 s_A[64 * 64];     // [edge][64k] xor-chunk-swizzled, per K-tile
    __shared__ u16 s_B[64 * 128];    // B tile (frag order); reused as out tile
    __shared__ u16 s_tail[64 * 64];  // tail K-tile (d2, eemb, zeros), same swizzle
    __shared__ float s_wx[128], s_be[128];
    __shared__ int s_src[64], s_dst[64], s_pos[64], s_et[64];
    __shared__ float s_diff[64][3], s_d2[64];

    int tx = threadIdx.x;
    int e0 = blockIdx.x * 64;
    int l = tx & 63, w = tx >> 6;

    if (tx < 64) {
        int s = edges[e0 + tx], d = edges[NE + e0 + tx];
        s_src[tx] = s; s_dst[tx] = d;
        s_pos[tx] = pos[e0 + tx]; s_et[tx] = etype[e0 + tx];
        float dx = x[s*3+0]-x[d*3+0], dy = x[s*3+1]-x[d*3+1], dz = x[s*3+2]-x[d*3+2];
        s_diff[tx][0] = dx; s_diff[tx][1] = dy; s_diff[tx][2] = dz;
        s_d2[tx] = dx*dx + dy*dy + dz*dz;
    }
    if (tx < 128) s_wx[tx] = Wx_l[tx];
    else          s_be[tx - 128] = be_l[tx - 128];
    __syncthreads();

    // tail tile fill: k=0 -> d2, k=1..32 -> eemb, rest 0 (xor-swizzled chunks)
    {
        int e = tx & 63, kq = tx >> 6;
        float d2 = s_d2[e]; int et = s_et[e];
        for (int k = kq * 16; k < kq * 16 + 16; ++k) {
            float v = (k == 0) ? d2 : ((k <= 32) ? edge_table[et * 32 + (k - 1)] : 0.f);
            int slot = (k >> 3) ^ (e & 7);
            s_tail[e * 64 + slot * 8 + (k & 7)] = f2bf(v);
        }
    }

    float4v acc[2][4];
    #pragma unroll
    for (int mi = 0; mi < 2; ++mi)
        #pragma unroll
        for (int ni = 0; ni < 4; ++ni)
            acc[mi][ni] = (float4v){0.f, 0.f, 0.f, 0.f};

    int mt_base = (w & 1) * 2;
    int nt_base = (w >> 1) * 4;

    for (int t = 0; t < 5; ++t) {
        __syncthreads();
        if (t < 4) {
            // A tile: gather 64 edge-rows x 128B from h_bf, xor-swizzle chunks
            #pragma unroll
            for (int it = 0; it < 2; ++it) {
                int flat = it * 256 + tx;
                int e = flat >> 3, s = flat & 7;
                int c = s ^ (e & 7);
                int row = (t < 2) ? s_src[e] : s_dst[e];
                uint4 v = *(const uint4*)(h_bf + (size_t)row * 128 + (t & 1) * 64 + c * 8);
                *(uint4*)(&s_A[e * 64 + s * 8]) = v;
            }
        }
        // B tile: contiguous frag-order copy
        #pragma unroll
        for (int it = 0; it < 4; ++it) {
            int flat = it * 256 + tx;
            ((uint4*)s_B)[flat] = ((const uint4*)(Bpack_l + (size_t)t * 8192))[flat];
        }
        __syncthreads();

        const u16* At = (t == 4) ? s_tail : s_A;
        #pragma unroll
        for (int s = 0; s < 2; ++s) {
            short8 af[2], bfv[4];
            #pragma unroll
            for (int mi = 0; mi < 2; ++mi) {
                int e = (mt_base + mi) * 16 + (l & 15);
                int c = s * 4 + (l >> 4);
                int slot = c ^ (e & 7);
                af[mi] = *(const short8*)(At + e * 64 + slot * 8);
            }
            #pragma unroll
            for (int ni = 0; ni < 4; ++ni)
                bfv[ni] = *(const short8*)(s_B + ((s * 8 + nt_base + ni) * 64 + l) * 8);
            #pragma unroll
            for (int mi = 0; mi < 2; ++mi)
                #pragma unroll
                for (int ni = 0; ni < 4; ++ni)
                    acc[mi][ni] = __builtin_amdgcn_mfma_f32_16x16x32_bf16(
                        af[mi], bfv[ni], acc[mi][ni], 0, 0, 0);
        }
    }
    __syncthreads();

    // epilogue: bias + silu, dump bf16 out tile into s_B ([edge][feat])
    #pragma unroll
    for (int mi = 0; mi < 2; ++mi) {
        int ebase = (mt_base + mi) * 16 + (l >> 4) * 4;
        #pragma unroll
        for (int ni = 0; ni < 4; ++ni) {
            int f = (nt_base + ni) * 16 + (l & 15);
            float bev = s_be[f];
            #pragma unroll
            for (int r = 0; r < 4; ++r) {
                float v = acc[mi][ni][r] + bev;
                float m = v * (1.f / (1.f + __expf(-v)));
                s_B[(ebase + r) * 128 + f] = f2bf(m);
            }
        }
    }
    __syncthreads();

    // wsum = msg @ Wx ; wdiff stores
    {
        int tf = tx & 15, te = tx >> 4;
        float wsum[4];
        #pragma unroll
        for (int i = 0; i < 4; ++i) {
            int e = te * 4 + i;
            const u16* rp = s_B + e * 128 + tf * 8;
            float p = 0.f;
            #pragma unroll
            for (int j = 0; j < 8; ++j) p += bf2f(rp[j]) * s_wx[tf * 8 + j];
            wsum[i] = p;
        }
        #pragma unroll
        for (int off = 1; off < 16; off <<= 1) {
            #pragma unroll
            for (int i = 0; i < 4; ++i) wsum[i] += __shfl_xor(wsum[i], off);
        }
        float bxv = bx_l[0];
        if (tf < 3) {
            #pragma unroll
            for (int i = 0; i < 4; ++i) {
                int e = te * 4 + i;
                wdiff[s_pos[e] * 3 + tf] = s_diff[e][tf] * (wsum[i] + bxv);
            }
        }
    }
    // msg stores: 64 rows x 256B, coalesced uint4
    #pragma unroll
    for (int it = 0; it < 4; ++it) {
        int flat = it * 256 + tx;
        int e = flat >> 4, c = flat & 15;
        *((uint4*)(msg + (size_t)s_pos[e] * 128) + c) = ((const uint4*)s_B)[flat];
    }
}

// ================= node update (CSR agg + Wh GEMM, 16 nodes, 512 thr) =================
__global__ __launch_bounds__(512) void node_update_kernel(
    float* __restrict__ h, u16* __restrict__ h_bf, float* __restrict__ x,
    const u16* __restrict__ msg, const float* __restrict__ wdiff,
    const int* __restrict__ row_start,
    const float* __restrict__ Wh_l, const float* __restrict__ bh_l)
{
    __shared__ float s_in[256][20];  // rows 0..127 = h, 128..255 = agg_m
    __shared__ int s_rs[17];
    int n0 = blockIdx.x * 16;
    int tx = threadIdx.x;
    if (tx < 17) s_rs[tx] = row_start[n0 + tx];
    for (int idx = tx; idx < 16 * HID; idx += 512) {
        int i = idx >> 7, k = idx & 127;
        s_in[k][i] = h[(n0 + i) * HID + k];
    }
    __syncthreads();
    // aggregation: wave wv handles nodes 2*wv, 2*wv+1; lane l covers feats l, l+64
    {
        int wv = tx >> 6, l = tx & 63;
        #pragma unroll
        for (int ii = 0; ii < 2; ++ii) {
            int i = wv * 2 + ii;
            int rs = s_rs[i], re = s_rs[i + 1];
            float a0 = 0.f, a1 = 0.f;
            for (int j = rs; j < re; ++j) {
                a0 += bf2f(msg[(size_t)j * HID + l]);
                a1 += bf2f(msg[(size_t)j * HID + l + 64]);
            }
            s_in[128 + l][i] = a0;
            s_in[192 + l][i] = a1;
        }
    }
    if (tx < 48) {
        int i = tx / 3, c = tx % 3, n = n0 + i;
        int rs = s_rs[i], re = s_rs[i + 1];
        float sxx = 0.f;
        for (int j = rs; j < re; ++j) sxx += wdiff[j * 3 + c];
        x[n * 3 + c] += sxx / ((float)(re - rs) + 1.f);
    }
    __syncthreads();
    // Wh GEMM: f = tx&127, quarter q = tx>>7 -> nodes q*4..q*4+3
    {
        int f = tx & 127, q = tx >> 7;
        float acc0 = bh_l[f], acc1 = acc0, acc2 = acc0, acc3 = acc0;
        for (int k = 0; k < 256; ++k) {
            float wv = Wh_l[k * HID + f];
            float4 v = *(const float4*)&s_in[k][q * 4];
            acc0 += v.x * wv; acc1 += v.y * wv; acc2 += v.z * wv; acc3 += v.w * wv;
        }
        float a[4] = {acc0, acc1, acc2, acc3};
        #pragma unroll
        for (int r = 0; r < 4; ++r) {
            int i = q * 4 + r;
            float v = a[r];
            float m = v * (1.f / (1.f + __expf(-v)));
            float hn = s_in[f][i] + m;
            h[(n0 + i) * HID + f] = hn;
            h_bf[(n0 + i) * HID + f] = f2bf(hn);
        }
    }
}

// ================= final =================
__global__ __launch_bounds__(64) void final_kernel(
    const float* __restrict__ h, const float* __restrict__ x,
    const int* __restrict__ gmask,
    const float* __restrict__ W, const float* __restrict__ b,
    float* __restrict__ out)
{
    __shared__ float s_h[8][HID];
    int n0 = blockIdx.x * 8;
    int tx = threadIdx.x;
    for (int idx = tx; idx < 8 * HID; idx += 64) {
        int i = idx >> 7, k = idx & 127;
        s_h[i][k] = h[(n0 + i) * HID + k];
    }
    __syncthreads();
    float acc[8];
    float bv = b[tx];
    #pragma unroll
    for (int i = 0; i < 8; ++i) acc[i] = bv;
    for (int k = 0; k < HID; ++k) {
        float w = W[k * IN_DIM + tx];
        #pragma unroll
        for (int i = 0; i < 8; ++i) acc[i] += s_h[i][k] * w;
    }
    #pragma unroll
    for (int i = 0; i < 8; ++i) {
        int n = n0 + i;
        out[n * IN_DIM + tx] = gmask[n] ? acc[i] : 0.f;
    }
    if (tx < 24) {
        int i = tx / 3, c = tx % 3;
        int n = n0 + i;
        out[NN * IN_DIM + n * 3 + c] = gmask[n] ? x[n * 3 + c] : 0.f;
    }
}

// ================= fallback path (round-1 atomic version, ~21 MB ws) =================
__global__ __launch_bounds__(256) void init_fb_kernel(
    const float* __restrict__ X_t, const int* __restrict__ edges,
    float* __restrict__ x, float* __restrict__ cnt)
{
    int gid = blockIdx.x * blockDim.x + threadIdx.x;
    int stride = gridDim.x * blockDim.x;
    for (int i = gid; i < NN * 3; i += stride) x[i] = X_t[i];
    for (int e = gid; e < NE; e += stride)
        atomicAdd(&cnt[edges[NE + e]], 1.0f);
}

__global__ __launch_bounds__(256) void edge_gemm_fb_kernel(
    const float* __restrict__ h, const float* __restrict__ x,
    const int* __restrict__ edges, const int* __restrict__ etype,
    const float* __restrict__ edge_table,
    const float* __restrict__ We_l, const float* __restrict__ be_l,
    const float* __restrict__ Wx_l, const float* __restrict__ bx_l,
    float* __restrict__ agg_m, float* __restrict__ agg_x)
{
    __shared__ int s_src[TILE_E], s_dst[TILE_E];
    __shared__ float s_diff[TILE_E][3];
    __shared__ float s_tail[TILE_E][36];
    __shared__ float s_A[TILE_E][36];
    __shared__ float s_Bf[33][HID];
    __shared__ float s_wx[HID];

    int e0 = blockIdx.x * TILE_E;
    int tx = threadIdx.x;
    int tf = tx & 15;
    int te = tx >> 4;

    if (tx < TILE_E) {
        int s = edges[e0 + tx];
        int d = edges[NE + e0 + tx];
        s_src[tx] = s; s_dst[tx] = d;
        float dx = x[s * 3 + 0] - x[d * 3 + 0];
        float dy = x[s * 3 + 1] - x[d * 3 + 1];
        float dz = x[s * 3 + 2] - x[d * 3 + 2];
        s_diff[tx][0] = dx; s_diff[tx][1] = dy; s_diff[tx][2] = dz;
        s_tail[tx][0] = dx * dx + dy * dy + dz * dz;
        int et = etype[e0 + tx];
        #pragma unroll
        for (int j = 0; j < 32; ++j) s_tail[tx][1 + j] = edge_table[et * 32 + j];
    }
    if (tx < HID) s_wx[tx] = Wx_l[tx];
    __syncthreads();

    float acc[4][8];
    #pragma unroll
    for (int i = 0; i < 4; ++i)
        #pragma unroll
        for (int j = 0; j < 8; ++j) acc[i][j] = 0.f;

    for (int t = 0; t < 9; ++t) {
        int k0 = t * 32;
        int klen = (t == 8) ? 33 : 32;
        __syncthreads();
        if (t < 8) {
            const bool use_src = (t < 4);
            int kbase = (t & 3) * 32;
            for (int q4 = tx; q4 < TILE_E * 8; q4 += 256) {
                int e = q4 >> 3, q = q4 & 7;
                int row = use_src ? s_src[e] : s_dst[e];
                float4 v = *(const float4*)&h[row * HID + kbase + q * 4];
                *(float4*)&s_A[e][q * 4] = v;
            }
        }
        for (int q4 = tx; q4 < klen * 32; q4 += 256) {
            int kk = q4 >> 5, c4 = q4 & 31;
            float4 v = *(const float4*)&We_l[(k0 + kk) * HID + c4 * 4];
            *(float4*)&s_Bf[kk][c4 * 4] = v;
        }
        __syncthreads();
        const float (*Asrc)[36] = (t == 8) ? (const float (*)[36])s_tail
                                           : (const float (*)[36])s_A;
        for (int kk = 0; kk < klen; ++kk) {
            float a0 = Asrc[te * 4 + 0][kk];
            float a1 = Asrc[te * 4 + 1][kk];
            float a2 = Asrc[te * 4 + 2][kk];
            float a3 = Asrc[te * 4 + 3][kk];
            float4 bv0 = *(const float4*)&s_Bf[kk][tf * 8];
            float4 bv1 = *(const float4*)&s_Bf[kk][tf * 8 + 4];
            float b[8] = {bv0.x, bv0.y, bv0.z, bv0.w, bv1.x, bv1.y, bv1.z, bv1.w};
            #pragma unroll
            for (int j = 0; j < 8; ++j) {
                acc[0][j] += a0 * b[j];
                acc[1][j] += a1 * b[j];
                acc[2][j] += a2 * b[j];
                acc[3][j] += a3 * b[j];
            }
        }
    }

    float wsum[4];
    #pragma unroll
    for (int i = 0; i < 4; ++i) {
        float p = 0.f;
        #pragma unroll
        for (int j = 0; j < 8; ++j) {
            int f = tf * 8 + j;
            float v = acc[i][j] + be_l[f];
            float m = v * (1.f / (1.f + __expf(-v)));
            acc[i][j] = m;
            p += m * s_wx[f];
        }
        wsum[i] = p;
    }
    #pragma unroll
    for (int off = 1; off < 16; off <<= 1) {
        #pragma unroll
        for (int i = 0; i < 4; ++i) wsum[i] += __shfl_xor(wsum[i], off);
    }
    float bxv = bx_l[0];
    if (tf < 3) {
        #pragma unroll
        for (int i = 0; i < 4; ++i) {
            int e = te * 4 + i;
            float w = wsum[i] + bxv;
            atomicAdd(&agg_x[s_dst[e] * 3 + tf], s_diff[e][tf] * w);
        }
    }
    #pragma unroll
    for (int i = 0; i < 4; ++i) {
        int d = s_dst[te * 4 + i];
        #pragma unroll
        for (int j = 0; j < 8; ++j)
            atomicAdd(&agg_m[d * HID + tf * 8 + j], acc[i][j]);
    }
}

__global__ __launch_bounds__(128) void node_update_fb_kernel(
    float* __restrict__ h, float* __restrict__ x,
    const float* __restrict__ agg_m, const float* __restrict__ agg_x,
    const float* __restrict__ cnt,
    const float* __restrict__ Wh_l, const float* __restrict__ bh_l)
{
    __shared__ float s_in[256][20];
    int n0 = blockIdx.x * 16;
    int tx = threadIdx.x;
    for (int idx = tx; idx < 16 * HID; idx += 128) {
        int i = idx >> 7, k = idx & 127;
        s_in[k][i] = h[(n0 + i) * HID + k];
    }
    for (int idx = tx; idx < 16 * HID; idx += 128) {
        int i = idx >> 7, k = idx & 127;
        s_in[HID + k][i] = agg_m[(n0 + i) * HID + k];
    }
    __syncthreads();
    float acc[16];
    float bv = bh_l[tx];
    #pragma unroll
    for (int i = 0; i < 16; ++i) acc[i] = bv;
    for (int k = 0; k < 256; ++k) {
        float w = Wh_l[k * HID + tx];
        float4 f0 = *(const float4*)&s_in[k][0];
        float4 f1 = *(const float4*)&s_in[k][4];
        float4 f2 = *(const float4*)&s_in[k][8];
        float4 f3 = *(const float4*)&s_in[k][12];
        acc[0] += f0.x*w; acc[1] += f0.y*w; acc[2] += f0.z*w; acc[3] += f0.w*w;
        acc[4] += f1.x*w; acc[5] += f1.y*w; acc[6] += f1.z*w; acc[7] += f1.w*w;
        acc[8] += f2.x*w; acc[9] += f2.y*w; acc[10]+= f2.z*w; acc[11]+= f2.w*w;
        acc[12]+= f3.x*w; acc[13]+= f3.y*w; acc[14]+= f3.z*w; acc[15]+= f3.w*w;
    }
    #pragma unroll
    for (int i = 0; i < 16; ++i) {
        float v = acc[i];
        float m = v * (1.f / (1.f + __expf(-v)));
        h[(n0 + i) * HID + tx] = s_in[tx][i] + m;
    }
    if (tx < 48) {
        int i = tx / 3, c = tx % 3;
        int n = n0 + i;
        x[n * 3 + c] += agg_x[n * 3 + c] / (cnt[n] + 1.f);
    }
}

extern "C" void kernel_launch(void* const* d_in, const int* in_sizes, int n_in,
                              void* d_out, int out_size, void* d_ws, size_t ws_size,
                              hipStream_t stream) {
    const float* H_t   = (const float*)d_in[0];
    const float* X_t   = (const float*)d_in[1];
    const float* cond  = (const float*)d_in[2];
    const float* t_in  = (const float*)d_in[3];
    const int*   edges = (const int*)d_in[4];
    const int*   etype = (const int*)d_in[5];
    const int*   gmask = (const int*)d_in[6];
    const float* W0 = (const float*)d_in[8];
    const float* b0 = (const float*)d_in[9];
    const float* W1 = (const float*)d_in[10];
    const float* b1 = (const float*)d_in[11];
    const float* W2 = (const float*)d_in[12];
    const float* b2 = (const float*)d_in[13];
    const float* edge_table = (const float*)d_in[14];
    const float* We = (const float*)d_in[15];
    const float* be = (const float*)d_in[16];
    const float* Wx = (const float*)d_in[17];
    const float* bx = (const float*)d_in[18];
    const float* Wh = (const float*)d_in[19];
    const float* bh = (const float*)d_in[20];
    const float* h2i_W = (const float*)d_in[21];
    const float* h2i_b = (const float*)d_in[22];

    // primary workspace layout (all 16B-aligned chunks first)
    char* p = (char*)d_ws;
    float* h = (float*)p;           p += (size_t)NN * HID * 4;      // 10.24 MB
    u16* h_bf = (u16*)p;            p += (size_t)NN * HID * 2;      // 5.12 MB
    float* x = (float*)p;           p += (size_t)NN * 3 * 4;        // 0.24 MB
    float* wdiff = (float*)p;       p += (size_t)NE * 3 * 4;        // 3.07 MB
    u16* msg = (u16*)p;             p += (size_t)NE * HID * 2;      // 65.54 MB
    u16* Bpack = (u16*)p;           p += (size_t)3 * 40960 * 2;     // 0.25 MB
    int* row_start = (int*)p;       p += (size_t)(NN + 4) * 4;
    int* deg = (int*)p;             p += (size_t)NN * 4;
    int* head = (int*)p;            p += (size_t)NN * 4;
    int* pos = (int*)p;             p += (size_t)NE * 4;            // 1.02 MB
    size_t need = (size_t)(p - (char*)d_ws);

    if (ws_size >= need) {
        hipMemsetAsync(deg, 0, NN * sizeof(int), stream);
        hist_kernel<<<256, 256, 0, stream>>>(X_t, edges, x, deg);
        scan_kernel<<<1, 256, 0, stream>>>(deg, row_start, head);
        scatter_kernel<<<256, 256, 0, stream>>>(edges, head, pos);
        pack_we_kernel<<<480, 256, 0, stream>>>(We, Bpack);
        node_mlp_kernel<<<NN / 16, 128, 0, stream>>>(H_t, cond, t_in,
                                                     W0, b0, W1, b1, W2, b2, h, h_bf);
        for (int l = 0; l < 3; ++l) {
            edge_mfma_kernel<<<NE / 64, 256, 0, stream>>>(
                h_bf, x, edges, etype, edge_table,
                Bpack + (size_t)l * 40960, be + l * HID,
                Wx + l * HID, bx + l, pos, msg, wdiff);
            node_update_kernel<<<NN / 16, 512, 0, stream>>>(
                h, h_bf, x, msg, wdiff, row_start,
                Wh + (size_t)l * 256 * HID, bh + l * HID);
        }
        final_kernel<<<NN / 8, 64, 0, stream>>>(h, x, gmask, h2i_W, h2i_b, (float*)d_out);
    } else {
        // fallback: atomic path (~21 MB)
        float* ws    = (float*)d_ws;
        float* fh    = ws;
        float* fx    = fh + NN * HID;
        float* cnt   = fx + NN * 3;
        float* agg_m = cnt + NN;
        float* agg_x = agg_m + NN * HID;

        hipMemsetAsync(cnt, 0, NN * sizeof(float), stream);
        init_fb_kernel<<<256, 256, 0, stream>>>(X_t, edges, fx, cnt);
        node_mlp_kernel<<<NN / 16, 128, 0, stream>>>(H_t, cond, t_in,
                                                     W0, b0, W1, b1, W2, b2, fh,
                                                     (u16*)(agg_x + NN * 3)); // scratch, unused
        for (int l = 0; l < 3; ++l) {
            hipMemsetAsync(agg_m, 0, (size_t)NN * 131 * sizeof(float), stream);
            edge_gemm_fb_kernel<<<NE / TILE_E, 256, 0, stream>>>(
                fh, fx, edges, etype, edge_table,
                We + (size_t)l * DE * HID, be + l * HID,
                Wx + l * HID, bx + l, agg_m, agg_x);
            node_update_fb_kernel<<<NN / 16, 128, 0, stream>>>(
                fh, fx, agg_m, agg_x, cnt,
                Wh + (size_t)l * 256 * HID, bh + l * HID);
        }
        final_kernel<<<NN / 8, 64, 0, stream>>>(fh, fx, gmask, h2i_W, h2i_b, (float*)d_out);
    }
}

// Round 6
// 484.726 us; speedup vs baseline: 6.9530x; 1.3038x over previous
//
#include <hip/hip_runtime.h>
#include <math.h>

#define NN 20000
#define NE 256000
#define IN_DIM 64
#define HID 128
#define DE 289     // 2*HID + 1 + 32
#define D0 320     // IN_DIM + 2*HID
#define TILE_E 64
#define NB64 313   // ceil(NN/64)

typedef unsigned short u16;
typedef unsigned int u32;
typedef __attribute__((ext_vector_type(8))) short short8;
typedef __attribute__((ext_vector_type(4))) float float4v;

// Bpack layout offsets (u16 elements)
#define OFF_WE   0          // 3 x 40960 (K=289 pad 320, N=128)
#define OFF_W0   122880     // 40960 (K=320, N=128)
#define OFF_W1   163840     // 16384 (K=128, N=128)
#define OFF_W2   180224     // 16384
#define OFF_WH   196608     // 3 x 32768 (K=256, N=128)
#define OFF_H2I  294912     // 8192 (K=128, N=64)
#define PACK_TOT 303104

static __device__ __forceinline__ u16 f2bf(float f) {
    unsigned int u = __float_as_uint(f);
    u += 0x7fffu + ((u >> 16) & 1u);
    return (u16)(u >> 16);
}
static __device__ __forceinline__ float bf2f(u16 s) {
    return __uint_as_float(((unsigned int)s) << 16);
}
static __device__ __forceinline__ uint4 pack8(const float* v) {
    uint4 r;
    r.x = (u32)f2bf(v[0]) | ((u32)f2bf(v[1]) << 16);
    r.y = (u32)f2bf(v[2]) | ((u32)f2bf(v[3]) << 16);
    r.z = (u32)f2bf(v[4]) | ((u32)f2bf(v[5]) << 16);
    r.w = (u32)f2bf(v[6]) | ((u32)f2bf(v[7]) << 16);
    return r;
}
static __device__ __forceinline__ float silu(float v) {
    return v * (1.f / (1.f + __expf(-v)));
}

// ================= CSR build =================
__global__ __launch_bounds__(256) void hist_kernel(
    const float* __restrict__ X_t, const int* __restrict__ edges,
    float* __restrict__ x, int* __restrict__ deg)
{
    int gid = blockIdx.x * blockDim.x + threadIdx.x;
    int stride = gridDim.x * blockDim.x;
    for (int i = gid; i < NN * 3; i += stride) x[i] = X_t[i];
    for (int e = gid; e < NE; e += stride)
        atomicAdd(&deg[edges[NE + e]], 1);
}

__global__ __launch_bounds__(256) void scan_kernel(
    const int* __restrict__ deg, int* __restrict__ row_start, int* __restrict__ head)
{
    __shared__ int s[256];
    int tx = threadIdx.x;
    const int per = (NN + 255) / 256;
    int st = tx * per, en = st + per;
    if (st > NN) st = NN;
    if (en > NN) en = NN;
    int sum = 0;
    for (int i = st; i < en; ++i) sum += deg[i];
    s[tx] = sum;
    __syncthreads();
    for (int off = 1; off < 256; off <<= 1) {
        int t = (tx >= off) ? s[tx - off] : 0;
        __syncthreads();
        s[tx] += t;
        __syncthreads();
    }
    int run = (tx == 0) ? 0 : s[tx - 1];
    for (int i = st; i < en; ++i) {
        row_start[i] = run; head[i] = run; run += deg[i];
    }
    if (tx == 255) row_start[NN] = run;
}

__global__ __launch_bounds__(256) void scatter_kernel(
    const int* __restrict__ edges, int* __restrict__ head, int* __restrict__ pos)
{
    int gid = blockIdx.x * blockDim.x + threadIdx.x;
    int stride = gridDim.x * blockDim.x;
    for (int e = gid; e < NE; e += stride)
        pos[e] = atomicAdd(&head[edges[NE + e]], 1);
}

// ================= weight frag-order packing (one launch) =================
__global__ __launch_bounds__(256) void pack_all_kernel(
    const float* __restrict__ We, const float* __restrict__ W0,
    const float* __restrict__ W1, const float* __restrict__ W2,
    const float* __restrict__ Wh, const float* __restrict__ h2i,
    u16* __restrict__ Bp)
{
    int idx = blockIdx.x * 256 + threadIdx.x;
    if (idx >= PACK_TOT) return;
    const float* src; int N = 128, Ksrc; int r;
    if (idx < OFF_W0) {
        int layer = idx / 40960; r = idx - layer * 40960;
        src = We + (size_t)layer * DE * HID; Ksrc = DE;
    } else if (idx < OFF_W1) { r = idx - OFF_W0; src = W0; Ksrc = 320; }
    else if (idx < OFF_W2)   { r = idx - OFF_W1; src = W1; Ksrc = 128; }
    else if (idx < OFF_WH)   { r = idx - OFF_W2; src = W2; Ksrc = 128; }
    else if (idx < OFF_H2I) {
        int t = idx - OFF_WH; int layer = t / 32768; r = t - layer * 32768;
        src = Wh + (size_t)layer * 256 * HID; Ksrc = 256;
    } else { r = idx - OFF_H2I; src = h2i; Ksrc = 128; N = 64; }
    int ntc = N / 16;
    int j = r & 7, lane = (r >> 3) & 63;
    int rem = r >> 9;
    int nt = rem % ntc, ks = rem / ntc;
    int k = ks * 32 + ((lane >> 4) << 3) + j;
    int c = nt * 16 + (lane & 15);
    Bp[idx] = f2bf((k < Ksrc) ? src[(size_t)k * N + c] : 0.f);
}

// ================= node MLP: MFMA, 64 nodes/block =================
__global__ __launch_bounds__(256) void node_mlp_mfma_kernel(
    const float* __restrict__ H_t, const float* __restrict__ cond,
    const float* __restrict__ t_in,
    const u16* __restrict__ W0p, const float* __restrict__ b0,
    const u16* __restrict__ W1p, const float* __restrict__ b1,
    const u16* __restrict__ W2p, const float* __restrict__ b2,
    float* __restrict__ h, u16* __restrict__ h_bf)
{
    __shared__ u16 s_A[64 * 64];     // staging K-tile, xor-swizzled
    __shared__ u16 s_B[64 * 128];    // one K64 N128 B-tile (frag order) = 1024 uint4
    __shared__ u16 s_h[64 * 128];    // activations, xor-swizzled
    __shared__ float s_t[64];

    int tx = threadIdx.x;
    int n0 = blockIdx.x * 64;
    int l = tx & 63, w = tx >> 6;
    int mt_base = (w & 1) * 2, nt_base = (w >> 1) * 4;
    const float cfr = -logf(10000.f) / 63.f;

    if (tx < 64) s_t[tx] = (n0 + tx < NN) ? t_in[n0 + tx] : 0.f;

    float4v acc[2][4];
    #pragma unroll
    for (int mi = 0; mi < 2; ++mi)
        #pragma unroll
        for (int ni = 0; ni < 4; ++ni) acc[mi][ni] = (float4v){0.f,0.f,0.f,0.f};

    // ---- layer 0: K=320, 5 K-tiles ----
    for (int t = 0; t < 5; ++t) {
        __syncthreads();
        #pragma unroll
        for (int it = 0; it < 2; ++it) {
            int flat = it * 256 + tx;
            int n = flat >> 3, sl = flat & 7;
            int c = sl ^ (n & 7);
            int k0 = t * 64 + c * 8;
            float tv8[8];
            int gn = n0 + n;
            if (gn < NN) {
                if (k0 < 192) {
                    const float* src = (k0 < 64) ? &H_t[(size_t)gn * IN_DIM + k0]
                                                 : &cond[(size_t)gn * HID + (k0 - 64)];
                    float4 a = *(const float4*)src;
                    float4 b = *(const float4*)(src + 4);
                    tv8[0]=a.x; tv8[1]=a.y; tv8[2]=a.z; tv8[3]=a.w;
                    tv8[4]=b.x; tv8[5]=b.y; tv8[6]=b.z; tv8[7]=b.w;
                } else {
                    float tv = s_t[n];
                    int jj = (k0 - 192) & 63;
                    bool is_sin = (k0 < 256);
                    #pragma unroll
                    for (int jx = 0; jx < 8; ++jx) {
                        float ang = tv * __expf(cfr * (float)(jj + jx));
                        tv8[jx] = is_sin ? __sinf(ang) : __cosf(ang);
                    }
                }
            } else {
                #pragma unroll
                for (int jx = 0; jx < 8; ++jx) tv8[jx] = 0.f;
            }
            *(uint4*)&s_A[n * 64 + sl * 8] = pack8(tv8);
        }
        #pragma unroll
        for (int it = 0; it < 4; ++it) {     // 1024 uint4 = full N128 tile
            int flat = it * 256 + tx;
            ((uint4*)s_B)[flat] = ((const uint4*)(W0p + (size_t)t * 8192))[flat];
        }
        __syncthreads();
        #pragma unroll
        for (int s = 0; s < 2; ++s) {
            short8 af[2], bfv[4];
            #pragma unroll
            for (int mi = 0; mi < 2; ++mi) {
                int m = (mt_base + mi) * 16 + (l & 15);
                int c = s * 4 + (l >> 4);
                int slot = c ^ (l & 7);
                af[mi] = *(const short8*)(s_A + m * 64 + slot * 8);
            }
            #pragma unroll
            for (int ni = 0; ni < 4; ++ni)
                bfv[ni] = *(const short8*)(s_B + ((s * 8 + nt_base + ni) * 64 + l) * 8);
            #pragma unroll
            for (int mi = 0; mi < 2; ++mi)
                #pragma unroll
                for (int ni = 0; ni < 4; ++ni)
                    acc[mi][ni] = __builtin_amdgcn_mfma_f32_16x16x32_bf16(
                        af[mi], bfv[ni], acc[mi][ni], 0, 0, 0);
        }
    }
    // epilogue L0 -> s_h (relu)
    #pragma unroll
    for (int mi = 0; mi < 2; ++mi) {
        #pragma unroll
        for (int ni = 0; ni < 4; ++ni) {
            int f = (nt_base + ni) * 16 + (l & 15);
            float bv = b0[f];
            #pragma unroll
            for (int r = 0; r < 4; ++r) {
                int m = (mt_base + mi) * 16 + (l >> 4) * 4 + r;
                float v = fmaxf(acc[mi][ni][r] + bv, 0.f);
                int slot = (f >> 3) ^ (m & 7);
                s_h[m * 128 + slot * 8 + (f & 7)] = f2bf(v);
            }
            acc[mi][ni] = (float4v){0.f,0.f,0.f,0.f};
        }
    }
    // ---- layer 1: K=128, 2 K-tiles ----
    for (int t = 0; t < 2; ++t) {
        __syncthreads();
        #pragma unroll
        for (int it = 0; it < 4; ++it) {
            int flat = it * 256 + tx;
            ((uint4*)s_B)[flat] = ((const uint4*)(W1p + (size_t)t * 8192))[flat];
        }
        __syncthreads();
        #pragma unroll
        for (int s = 0; s < 2; ++s) {
            short8 af[2], bfv[4];
            #pragma unroll
            for (int mi = 0; mi < 2; ++mi) {
                int m = (mt_base + mi) * 16 + (l & 15);
                int c = t * 8 + s * 4 + (l >> 4);
                int slot = c ^ (l & 7);
                af[mi] = *(const short8*)(s_h + m * 128 + slot * 8);
            }
            #pragma unroll
            for (int ni = 0; ni < 4; ++ni)
                bfv[ni] = *(const short8*)(s_B + ((s * 8 + nt_base + ni) * 64 + l) * 8);
            #pragma unroll
            for (int mi = 0; mi < 2; ++mi)
                #pragma unroll
                for (int ni = 0; ni < 4; ++ni)
                    acc[mi][ni] = __builtin_amdgcn_mfma_f32_16x16x32_bf16(
                        af[mi], bfv[ni], acc[mi][ni], 0, 0, 0);
        }
    }
    __syncthreads();  // all reads of s_h done before overwrite
    #pragma unroll
    for (int mi = 0; mi < 2; ++mi) {
        #pragma unroll
        for (int ni = 0; ni < 4; ++ni) {
            int f = (nt_base + ni) * 16 + (l & 15);
            float bv = b1[f];
            #pragma unroll
            for (int r = 0; r < 4; ++r) {
                int m = (mt_base + mi) * 16 + (l >> 4) * 4 + r;
                float v = fmaxf(acc[mi][ni][r] + bv, 0.f);
                int slot = (f >> 3) ^ (m & 7);
                s_h[m * 128 + slot * 8 + (f & 7)] = f2bf(v);
            }
            acc[mi][ni] = (float4v){0.f,0.f,0.f,0.f};
        }
    }
    // ---- layer 2: K=128, linear ----
    for (int t = 0; t < 2; ++t) {
        __syncthreads();
        #pragma unroll
        for (int it = 0; it < 4; ++it) {
            int flat = it * 256 + tx;
            ((uint4*)s_B)[flat] = ((const uint4*)(W2p + (size_t)t * 8192))[flat];
        }
        __syncthreads();
        #pragma unroll
        for (int s = 0; s < 2; ++s) {
            short8 af[2], bfv[4];
            #pragma unroll
            for (int mi = 0; mi < 2; ++mi) {
                int m = (mt_base + mi) * 16 + (l & 15);
                int c = t * 8 + s * 4 + (l >> 4);
                int slot = c ^ (l & 7);
                af[mi] = *(const short8*)(s_h + m * 128 + slot * 8);
            }
            #pragma unroll
            for (int ni = 0; ni < 4; ++ni)
                bfv[ni] = *(const short8*)(s_B + ((s * 8 + nt_base + ni) * 64 + l) * 8);
            #pragma unroll
            for (int mi = 0; mi < 2; ++mi)
                #pragma unroll
                for (int ni = 0; ni < 4; ++ni)
                    acc[mi][ni] = __builtin_amdgcn_mfma_f32_16x16x32_bf16(
                        af[mi], bfv[ni], acc[mi][ni], 0, 0, 0);
        }
    }
    #pragma unroll
    for (int mi = 0; mi < 2; ++mi) {
        #pragma unroll
        for (int ni = 0; ni < 4; ++ni) {
            int f = (nt_base + ni) * 16 + (l & 15);
            float bv = b2[f];
            #pragma unroll
            for (int r = 0; r < 4; ++r) {
                int m = (mt_base + mi) * 16 + (l >> 4) * 4 + r;
                int gn = n0 + m;
                if (gn < NN) {
                    float v = acc[mi][ni][r] + bv;
                    h[(size_t)gn * HID + f] = v;
                    h_bf[(size_t)gn * HID + f] = f2bf(v);
                }
            }
        }
    }
}

// ================= edge MFMA GEMM (bf16) — unchanged (passing since round 3) =================
__global__ __launch_bounds__(256) void edge_mfma_kernel(
    const u16* __restrict__ h_bf, const float* __restrict__ x,
    const int* __restrict__ edges, const int* __restrict__ etype,
    const float* __restrict__ edge_table,
    const u16* __restrict__ Bpack_l, const float* __restrict__ be_l,
    const float* __restrict__ Wx_l, const float* __restrict__ bx_l,
    const int* __restrict__ pos,
    u16* __restrict__ msg, float* __restrict__ wdiff)
{
    __shared__ u16 s_A[64 * 64];
    __shared__ u16 s_B[64 * 136];    // GEMM uses first 64*128; epilogue uses stride 136
    __shared__ u16 s_tail[64 * 64];
    __shared__ float s_wx[128], s_be[128];
    __shared__ int s_src[64], s_dst[64], s_pos[64], s_et[64];
    __shared__ float s_diff[64][3], s_d2[64];

    int tx = threadIdx.x;
    int e0 = blockIdx.x * 64;
    int l = tx & 63, w = tx >> 6;

    if (tx < 64) {
        int s = edges[e0 + tx], d = edges[NE + e0 + tx];
        s_src[tx] = s; s_dst[tx] = d;
        s_pos[tx] = pos[e0 + tx]; s_et[tx] = etype[e0 + tx];
        float dx = x[s*3+0]-x[d*3+0], dy = x[s*3+1]-x[d*3+1], dz = x[s*3+2]-x[d*3+2];
        s_diff[tx][0] = dx; s_diff[tx][1] = dy; s_diff[tx][2] = dz;
        s_d2[tx] = dx*dx + dy*dy + dz*dz;
    }
    if (tx < 128) s_wx[tx] = Wx_l[tx];
    else          s_be[tx - 128] = be_l[tx - 128];
    __syncthreads();

    {
        int e = tx & 63, kq = tx >> 6;
        float d2 = s_d2[e]; int et = s_et[e];
        for (int k = kq * 16; k < kq * 16 + 16; ++k) {
            float v = (k == 0) ? d2 : ((k <= 32) ? edge_table[et * 32 + (k - 1)] : 0.f);
            int slot = (k >> 3) ^ (e & 7);
            s_tail[e * 64 + slot * 8 + (k & 7)] = f2bf(v);
        }
    }

    float4v acc[2][4];
    #pragma unroll
    for (int mi = 0; mi < 2; ++mi)
        #pragma unroll
        for (int ni = 0; ni < 4; ++ni)
            acc[mi][ni] = (float4v){0.f, 0.f, 0.f, 0.f};

    int mt_base = (w & 1) * 2;
    int nt_base = (w >> 1) * 4;

    for (int t = 0; t < 5; ++t) {
        __syncthreads();
        if (t < 4) {
            #pragma unroll
            for (int it = 0; it < 2; ++it) {
                int flat = it * 256 + tx;
                int e = flat >> 3, s = flat & 7;
                int c = s ^ (e & 7);
                int row = (t < 2) ? s_src[e] : s_dst[e];
                uint4 v = *(const uint4*)(h_bf + (size_t)row * 128 + (t & 1) * 64 + c * 8);
                *(uint4*)(&s_A[e * 64 + s * 8]) = v;
            }
        }
        #pragma unroll
        for (int it = 0; it < 4; ++it) {
            int flat = it * 256 + tx;
            ((uint4*)s_B)[flat] = ((const uint4*)(Bpack_l + (size_t)t * 8192))[flat];
        }
        __syncthreads();

        const u16* At = (t == 4) ? s_tail : s_A;
        #pragma unroll
        for (int s = 0; s < 2; ++s) {
            short8 af[2], bfv[4];
            #pragma unroll
            for (int mi = 0; mi < 2; ++mi) {
                int e = (mt_base + mi) * 16 + (l & 15);
                int c = s * 4 + (l >> 4);
                int slot = c ^ (e & 7);
                af[mi] = *(const short8*)(At + e * 64 + slot * 8);
            }
            #pragma unroll
            for (int ni = 0; ni < 4; ++ni)
                bfv[ni] = *(const short8*)(s_B + ((s * 8 + nt_base + ni) * 64 + l) * 8);
            #pragma unroll
            for (int mi = 0; mi < 2; ++mi)
                #pragma unroll
                for (int ni = 0; ni < 4; ++ni)
                    acc[mi][ni] = __builtin_amdgcn_mfma_f32_16x16x32_bf16(
                        af[mi], bfv[ni], acc[mi][ni], 0, 0, 0);
        }
    }
    __syncthreads();

    // epilogue: bias + silu -> padded out tile (stride 136)
    #pragma unroll
    for (int mi = 0; mi < 2; ++mi) {
        int ebase = (mt_base + mi) * 16 + (l >> 4) * 4;
        #pragma unroll
        for (int ni = 0; ni < 4; ++ni) {
            int f = (nt_base + ni) * 16 + (l & 15);
            float bev = s_be[f];
            #pragma unroll
            for (int r = 0; r < 4; ++r) {
                float v = acc[mi][ni][r] + bev;
                s_B[(ebase + r) * 136 + f] = f2bf(silu(v));
            }
        }
    }
    __syncthreads();

    {
        int tf = tx & 15, te = tx >> 4;
        float wsum[4];
        #pragma unroll
        for (int i = 0; i < 4; ++i) {
            int e = te * 4 + i;
            const u16* rp = s_B + e * 136 + tf * 8;
            float p = 0.f;
            #pragma unroll
            for (int j = 0; j < 8; ++j) p += bf2f(rp[j]) * s_wx[tf * 8 + j];
            wsum[i] = p;
        }
        #pragma unroll
        for (int off = 1; off < 16; off <<= 1) {
            #pragma unroll
            for (int i = 0; i < 4; ++i) wsum[i] += __shfl_xor(wsum[i], off);
        }
        float bxv = bx_l[0];
        if (tf < 3) {
            #pragma unroll
            for (int i = 0; i < 4; ++i) {
                int e = te * 4 + i;
                wdiff[s_pos[e] * 3 + tf] = s_diff[e][tf] * (wsum[i] + bxv);
            }
        }
    }
    #pragma unroll
    for (int it = 0; it < 4; ++it) {
        int flat = it * 256 + tx;
        int e = flat >> 4, c = flat & 15;
        *((uint4*)(msg + (size_t)s_pos[e] * 128) + c) = *(const uint4*)(s_B + e * 136 + c * 8);
    }
}

// ================= node update: CSR agg + MFMA Wh GEMM, 64 nodes/block =================
__global__ __launch_bounds__(256) void node_update_mfma_kernel(
    float* __restrict__ h, u16* __restrict__ h_bf, float* __restrict__ x,
    const u16* __restrict__ msg, const float* __restrict__ wdiff,
    const int* __restrict__ row_start,
    const u16* __restrict__ Whp_l, const float* __restrict__ bh_l)
{
    __shared__ u16 s_A[64 * 256];   // [node][256k] xor-swizzled: h | agg_m
    __shared__ u16 s_B[64 * 128];
    __shared__ int s_rs[65];

    int tx = threadIdx.x;
    int n0 = blockIdx.x * 64;
    int l = tx & 63, w = tx >> 6;
    int mt_base = (w & 1) * 2, nt_base = (w >> 1) * 4;

    if (tx < 65) {
        int n = n0 + tx;
        s_rs[tx] = row_start[n > NN ? NN : n];
    }
    // stage h_bf (chunks 0..15)
    #pragma unroll
    for (int it = 0; it < 4; ++it) {
        int flat = it * 256 + tx;
        int n = flat >> 4, c = flat & 15;
        int slot = c ^ (n & 7);
        int gn = n0 + n;
        uint4 v = make_uint4(0,0,0,0);
        if (gn < NN) v = *(const uint4*)(h_bf + (size_t)gn * 128 + c * 8);
        *(uint4*)&s_A[n * 256 + slot * 8] = v;
    }
    __syncthreads();
    // aggregation: thread -> node tx>>2, feats (tx&3)*32..+31 (chunks 16..31)
    {
        int i = tx >> 2, p = tx & 3;
        int rs = s_rs[i], re = s_rs[i + 1];
        float ag[32];
        #pragma unroll
        for (int q = 0; q < 32; ++q) ag[q] = 0.f;
        for (int j = rs; j < re; ++j) {
            const uint4* row = (const uint4*)(msg + (size_t)j * 128 + p * 32);
            #pragma unroll
            for (int q = 0; q < 4; ++q) {
                uint4 v = row[q];
                ag[q*8+0] += bf2f((u16)(v.x & 0xffffu));
                ag[q*8+1] += bf2f((u16)(v.x >> 16));
                ag[q*8+2] += bf2f((u16)(v.y & 0xffffu));
                ag[q*8+3] += bf2f((u16)(v.y >> 16));
                ag[q*8+4] += bf2f((u16)(v.z & 0xffffu));
                ag[q*8+5] += bf2f((u16)(v.z >> 16));
                ag[q*8+6] += bf2f((u16)(v.w & 0xffffu));
                ag[q*8+7] += bf2f((u16)(v.w >> 16));
            }
        }
        #pragma unroll
        for (int q = 0; q < 4; ++q) {
            int c2 = 16 + p * 4 + q;
            int slot = c2 ^ (i & 7);
            *(uint4*)&s_A[i * 256 + slot * 8] = pack8(&ag[q * 8]);
        }
    }
    // x update
    if (tx < 192) {
        int i = tx / 3, c = tx % 3;
        int gn = n0 + i;
        if (gn < NN) {
            int rs = s_rs[i], re = s_rs[i + 1];
            float sxx = 0.f;
            for (int j = rs; j < re; ++j) sxx += wdiff[j * 3 + c];
            x[gn * 3 + c] += sxx / ((float)(re - rs) + 1.f);
        }
    }

    float4v acc[2][4];
    #pragma unroll
    for (int mi = 0; mi < 2; ++mi)
        #pragma unroll
        for (int ni = 0; ni < 4; ++ni) acc[mi][ni] = (float4v){0.f,0.f,0.f,0.f};

    for (int t = 0; t < 4; ++t) {
        __syncthreads();
        #pragma unroll
        for (int it = 0; it < 4; ++it) {     // 1024 uint4 = full N128 tile
            int flat = it * 256 + tx;
            ((uint4*)s_B)[flat] = ((const uint4*)(Whp_l + (size_t)t * 8192))[flat];
        }
        __syncthreads();
        #pragma unroll
        for (int s = 0; s < 2; ++s) {
            short8 af[2], bfv[4];
            #pragma unroll
            for (int mi = 0; mi < 2; ++mi) {
                int m = (mt_base + mi) * 16 + (l & 15);
                int c = t * 8 + s * 4 + (l >> 4);
                int slot = c ^ (l & 7);
                af[mi] = *(const short8*)(s_A + m * 256 + slot * 8);
            }
            #pragma unroll
            for (int ni = 0; ni < 4; ++ni)
                bfv[ni] = *(const short8*)(s_B + ((s * 8 + nt_base + ni) * 64 + l) * 8);
            #pragma unroll
            for (int mi = 0; mi < 2; ++mi)
                #pragma unroll
                for (int ni = 0; ni < 4; ++ni)
                    acc[mi][ni] = __builtin_amdgcn_mfma_f32_16x16x32_bf16(
                        af[mi], bfv[ni], acc[mi][ni], 0, 0, 0);
        }
    }
    // epilogue: h += silu(acc + bh)
    #pragma unroll
    for (int mi = 0; mi < 2; ++mi) {
        #pragma unroll
        for (int ni = 0; ni < 4; ++ni) {
            int f = (nt_base + ni) * 16 + (l & 15);
            float bv = bh_l[f];
            #pragma unroll
            for (int r = 0; r < 4; ++r) {
                int m = (mt_base + mi) * 16 + (l >> 4) * 4 + r;
                int gn = n0 + m;
                if (gn < NN) {
                    float v = acc[mi][ni][r] + bv;
                    float hn = h[(size_t)gn * HID + f] + silu(v);
                    h[(size_t)gn * HID + f] = hn;
                    h_bf[(size_t)gn * HID + f] = f2bf(hn);
                }
            }
        }
    }
}

// ================= final: MFMA h2i, 64 nodes/block =================
__global__ __launch_bounds__(256) void final_mfma_kernel(
    const u16* __restrict__ h_bf, const float* __restrict__ x,
    const int* __restrict__ gmask,
    const u16* __restrict__ h2ip, const float* __restrict__ b,
    float* __restrict__ out)
{
    __shared__ u16 s_A[64 * 128];
    __shared__ u16 s_B[4096];       // K64 x N64 tile = 4096 u16 = 512 uint4

    int tx = threadIdx.x;
    int n0 = blockIdx.x * 64;
    int l = tx & 63, w = tx >> 6;
    int mt_base = (w & 1) * 2, nt_base = (w >> 1) * 2;

    #pragma unroll
    for (int it = 0; it < 4; ++it) {
        int flat = it * 256 + tx;
        int n = flat >> 4, c = flat & 15;
        int slot = c ^ (n & 7);
        int gn = n0 + n;
        uint4 v = make_uint4(0,0,0,0);
        if (gn < NN) v = *(const uint4*)(h_bf + (size_t)gn * 128 + c * 8);
        *(uint4*)&s_A[n * 128 + slot * 8] = v;
    }

    float4v acc[2][2];
    #pragma unroll
    for (int mi = 0; mi < 2; ++mi)
        #pragma unroll
        for (int ni = 0; ni < 2; ++ni) acc[mi][ni] = (float4v){0.f,0.f,0.f,0.f};

    for (int t = 0; t < 2; ++t) {
        __syncthreads();
        #pragma unroll
        for (int it = 0; it < 2; ++it) {     // FIX: 512 uint4 = full K64xN64 tile
            int flat = it * 256 + tx;
            ((uint4*)s_B)[flat] = ((const uint4*)(h2ip + (size_t)t * 4096))[flat];
        }
        __syncthreads();
        #pragma unroll
        for (int s = 0; s < 2; ++s) {
            short8 af[2], bfv[2];
            #pragma unroll
            for (int mi = 0; mi < 2; ++mi) {
                int m = (mt_base + mi) * 16 + (l & 15);
                int c = t * 8 + s * 4 + (l >> 4);
                int slot = c ^ (l & 7);
                af[mi] = *(const short8*)(s_A + m * 128 + slot * 8);
            }
            #pragma unroll
            for (int ni = 0; ni < 2; ++ni)
                bfv[ni] = *(const short8*)(s_B + ((s * 4 + nt_base + ni) * 64 + l) * 8);
            #pragma unroll
            for (int mi = 0; mi < 2; ++mi)
                #pragma unroll
                for (int ni = 0; ni < 2; ++ni)
                    acc[mi][ni] = __builtin_amdgcn_mfma_f32_16x16x32_bf16(
                        af[mi], bfv[ni], acc[mi][ni], 0, 0, 0);
        }
    }
    #pragma unroll
    for (int mi = 0; mi < 2; ++mi) {
        #pragma unroll
        for (int ni = 0; ni < 2; ++ni) {
            int f = (nt_base + ni) * 16 + (l & 15);
            float bv = b[f];
            #pragma unroll
            for (int r = 0; r < 4; ++r) {
                int m = (mt_base + mi) * 16 + (l >> 4) * 4 + r;
                int gn = n0 + m;
                if (gn < NN)
                    out[(size_t)gn * IN_DIM + f] = gmask[gn] ? (acc[mi][ni][r] + bv) : 0.f;
            }
        }
    }
    if (tx < 192) {
        int i = tx / 3, c = tx % 3;
        int gn = n0 + i;
        if (gn < NN)
            out[(size_t)NN * IN_DIM + gn * 3 + c] = gmask[gn] ? x[gn * 3 + c] : 0.f;
    }
}

// ================= fallback path (atomic, scalar; used only if ws too small) =================
__global__ __launch_bounds__(256) void init_fb_kernel(
    const float* __restrict__ X_t, const int* __restrict__ edges,
    float* __restrict__ x, float* __restrict__ cnt)
{
    int gid = blockIdx.x * blockDim.x + threadIdx.x;
    int stride = gridDim.x * blockDim.x;
    for (int i = gid; i < NN * 3; i += stride) x[i] = X_t[i];
    for (int e = gid; e < NE; e += stride)
        atomicAdd(&cnt[edges[NE + e]], 1.0f);
}

__global__ __launch_bounds__(128) void node_mlp_kernel(
    const float* __restrict__ H_t, const float* __restrict__ cond,
    const float* __restrict__ t_in,
    const float* __restrict__ W0, const float* __restrict__ b0,
    const float* __restrict__ W1, const float* __restrict__ b1,
    const float* __restrict__ W2, const float* __restrict__ b2,
    float* __restrict__ h)
{
    __shared__ float s_feat[D0][20];
    __shared__ float s_h0[HID][20];
    __shared__ float s_h1[HID][20];
    int n0 = blockIdx.x * 16;
    int tx = threadIdx.x;

    for (int idx = tx; idx < 16 * IN_DIM; idx += 128) {
        int i = idx >> 6, k = idx & 63;
        s_feat[k][i] = H_t[(n0 + i) * IN_DIM + k];
    }
    for (int idx = tx; idx < 16 * HID; idx += 128) {
        int i = idx >> 7, k = idx & 127;
        s_feat[IN_DIM + k][i] = cond[(n0 + i) * HID + k];
    }
    const float cfr = -logf(10000.f) / 63.f;
    for (int idx = tx; idx < 16 * HID; idx += 128) {
        int i = idx >> 7, k = idx & 127;
        float tv = t_in[n0 + i];
        int jj = k & 63;
        float ang = tv * __expf(cfr * (float)jj);
        s_feat[IN_DIM + HID + k][i] = (k < 64) ? __sinf(ang) : __cosf(ang);
    }
    __syncthreads();

    float acc[16];
    {
        float bv = b0[tx];
        #pragma unroll
        for (int i = 0; i < 16; ++i) acc[i] = bv;
        for (int k = 0; k < D0; ++k) {
            float w = W0[k * HID + tx];
            float4 f0 = *(const float4*)&s_feat[k][0];
            float4 f1 = *(const float4*)&s_feat[k][4];
            float4 f2 = *(const float4*)&s_feat[k][8];
            float4 f3 = *(const float4*)&s_feat[k][12];
            acc[0] += f0.x*w; acc[1] += f0.y*w; acc[2] += f0.z*w; acc[3] += f0.w*w;
            acc[4] += f1.x*w; acc[5] += f1.y*w; acc[6] += f1.z*w; acc[7] += f1.w*w;
            acc[8] += f2.x*w; acc[9] += f2.y*w; acc[10]+= f2.z*w; acc[11]+= f2.w*w;
            acc[12]+= f3.x*w; acc[13]+= f3.y*w; acc[14]+= f3.z*w; acc[15]+= f3.w*w;
        }
        #pragma unroll
        for (int i = 0; i < 16; ++i) s_h0[tx][i] = fmaxf(acc[i], 0.f);
    }
    __syncthreads();
    {
        float bv = b1[tx];
        #pragma unroll
        for (int i = 0; i < 16; ++i) acc[i] = bv;
        for (int k = 0; k < HID; ++k) {
            float w = W1[k * HID + tx];
            float4 f0 = *(const float4*)&s_h0[k][0];
            float4 f1 = *(const float4*)&s_h0[k][4];
            float4 f2 = *(const float4*)&s_h0[k][8];
            float4 f3 = *(const float4*)&s_h0[k][12];
            acc[0] += f0.x*w; acc[1] += f0.y*w; acc[2] += f0.z*w; acc[3] += f0.w*w;
            acc[4] += f1.x*w; acc[5] += f1.y*w; acc[6] += f1.z*w; acc[7] += f1.w*w;
            acc[8] += f2.x*w; acc[9] += f2.y*w; acc[10]+= f2.z*w; acc[11]+= f2.w*w;
            acc[12]+= f3.x*w; acc[13]+= f3.y*w; acc[14]+= f3.z*w; acc[15]+= f3.w*w;
        }
        #pragma unroll
        for (int i = 0; i < 16; ++i) s_h1[tx][i] = fmaxf(acc[i], 0.f);
    }
    __syncthreads();
    {
        float bv = b2[tx];
        #pragma unroll
        for (int i = 0; i < 16; ++i) acc[i] = bv;
        for (int k = 0; k < HID; ++k) {
            float w = W2[k * HID + tx];
            float4 f0 = *(const float4*)&s_h1[k][0];
            float4 f1 = *(const float4*)&s_h1[k][4];
            float4 f2 = *(const float4*)&s_h1[k][8];
            float4 f3 = *(const float4*)&s_h1[k][12];
            acc[0] += f0.x*w; acc[1] += f0.y*w; acc[2] += f0.z*w; acc[3] += f0.w*w;
            acc[4] += f1.x*w; acc[5] += f1.y*w; acc[6] += f1.z*w; acc[7] += f1.w*w;
            acc[8] += f2.x*w; acc[9] += f2.y*w; acc[10]+= f2.z*w; acc[11]+= f2.w*w;
            acc[12]+= f3.x*w; acc[13]+= f3.y*w; acc[14]+= f3.z*w; acc[15]+= f3.w*w;
        }
        #pragma unroll
        for (int i = 0; i < 16; ++i) h[(n0 + i) * HID + tx] = acc[i];
    }
}

__global__ __launch_bounds__(256) void edge_gemm_fb_kernel(
    const float* __restrict__ h, const float* __restrict__ x,
    const int* __restrict__ edges, const int* __restrict__ etype,
    const float* __restrict__ edge_table,
    const float* __restrict__ We_l, const float* __restrict__ be_l,
    const float* __restrict__ Wx_l, const float* __restrict__ bx_l,
    float* __restrict__ agg_m, float* __restrict__ agg_x)
{
    __shared__ int s_src[TILE_E], s_dst[TILE_E];
    __shared__ float s_diff[TILE_E][3];
    __shared__ float s_tail[TILE_E][36];
    __shared__ float s_Af[TILE_E][36];
    __shared__ float s_Bf[33][HID];
    __shared__ float s_wx[HID];

    int e0 = blockIdx.x * TILE_E;
    int tx = threadIdx.x;
    int tf = tx & 15;
    int te = tx >> 4;

    if (tx < TILE_E) {
        int s = edges[e0 + tx];
        int d = edges[NE + e0 + tx];
        s_src[tx] = s; s_dst[tx] = d;
        float dx = x[s * 3 + 0] - x[d * 3 + 0];
        float dy = x[s * 3 + 1] - x[d * 3 + 1];
        float dz = x[s * 3 + 2] - x[d * 3 + 2];
        s_diff[tx][0] = dx; s_diff[tx][1] = dy; s_diff[tx][2] = dz;
        s_tail[tx][0] = dx * dx + dy * dy + dz * dz;
        int et = etype[e0 + tx];
        #pragma unroll
        for (int j = 0; j < 32; ++j) s_tail[tx][1 + j] = edge_table[et * 32 + j];
    }
    if (tx < HID) s_wx[tx] = Wx_l[tx];
    __syncthreads();

    float acc[4][8];
    #pragma unroll
    for (int i = 0; i < 4; ++i)
        #pragma unroll
        for (int j = 0; j < 8; ++j) acc[i][j] = 0.f;

    for (int t = 0; t < 9; ++t) {
        int k0 = t * 32;
        int klen = (t == 8) ? 33 : 32;
        __syncthreads();
        if (t < 8) {
            const bool use_src = (t < 4);
            int kbase = (t & 3) * 32;
            for (int q4 = tx; q4 < TILE_E * 8; q4 += 256) {
                int e = q4 >> 3, q = q4 & 7;
                int row = use_src ? s_src[e] : s_dst[e];
                float4 v = *(const float4*)&h[row * HID + kbase + q * 4];
                *(float4*)&s_Af[e][q * 4] = v;
            }
        }
        for (int q4 = tx; q4 < klen * 32; q4 += 256) {
            int kk = q4 >> 5, c4 = q4 & 31;
            float4 v = *(const float4*)&We_l[(k0 + kk) * HID + c4 * 4];
            *(float4*)&s_Bf[kk][c4 * 4] = v;
        }
        __syncthreads();
        const float (*Asrc)[36] = (t == 8) ? (const float (*)[36])s_tail
                                           : (const float (*)[36])s_Af;
        for (int kk = 0; kk < klen; ++kk) {
            float a0 = Asrc[te * 4 + 0][kk];
            float a1 = Asrc[te * 4 + 1][kk];
            float a2 = Asrc[te * 4 + 2][kk];
            float a3 = Asrc[te * 4 + 3][kk];
            float4 bv0 = *(const float4*)&s_Bf[kk][tf * 8];
            float4 bv1 = *(const float4*)&s_Bf[kk][tf * 8 + 4];
            float b[8] = {bv0.x, bv0.y, bv0.z, bv0.w, bv1.x, bv1.y, bv1.z, bv1.w};
            #pragma unroll
            for (int j = 0; j < 8; ++j) {
                acc[0][j] += a0 * b[j];
                acc[1][j] += a1 * b[j];
                acc[2][j] += a2 * b[j];
                acc[3][j] += a3 * b[j];
            }
        }
    }

    float wsum[4];
    #pragma unroll
    for (int i = 0; i < 4; ++i) {
        float p = 0.f;
        #pragma unroll
        for (int j = 0; j < 8; ++j) {
            int f = tf * 8 + j;
            float v = acc[i][j] + be_l[f];
            float m = silu(v);
            acc[i][j] = m;
            p += m * s_wx[f];
        }
        wsum[i] = p;
    }
    #pragma unroll
    for (int off = 1; off < 16; off <<= 1) {
        #pragma unroll
        for (int i = 0; i < 4; ++i) wsum[i] += __shfl_xor(wsum[i], off);
    }
    float bxv = bx_l[0];
    if (tf < 3) {
        #pragma unroll
        for (int i = 0; i < 4; ++i) {
            int e = te * 4 + i;
            float w2 = wsum[i] + bxv;
            atomicAdd(&agg_x[s_dst[e] * 3 + tf], s_diff[e][tf] * w2);
        }
    }
    #pragma unroll
    for (int i = 0; i < 4; ++i) {
        int d = s_dst[te * 4 + i];
        #pragma unroll
        for (int j = 0; j < 8; ++j)
            atomicAdd(&agg_m[d * HID + tf * 8 + j], acc[i][j]);
    }
}

__global__ __launch_bounds__(128) void node_update_fb_kernel(
    float* __restrict__ h, float* __restrict__ x,
    const float* __restrict__ agg_m, const float* __restrict__ agg_x,
    const float* __restrict__ cnt,
    const float* __restrict__ Wh_l, const float* __restrict__ bh_l)
{
    __shared__ float s_in[256][20];
    int n0 = blockIdx.x * 16;
    int tx = threadIdx.x;
    for (int idx = tx; idx < 16 * HID; idx += 128) {
        int i = idx >> 7, k = idx & 127;
        s_in[k][i] = h[(n0 + i) * HID + k];
    }
    for (int idx = tx; idx < 16 * HID; idx += 128) {
        int i = idx >> 7, k = idx & 127;
        s_in[HID + k][i] = agg_m[(n0 + i) * HID + k];
    }
    __syncthreads();
    float acc[16];
    float bv = bh_l[tx];
    #pragma unroll
    for (int i = 0; i < 16; ++i) acc[i] = bv;
    for (int k = 0; k < 256; ++k) {
        float w = Wh_l[k * HID + tx];
        float4 f0 = *(const float4*)&s_in[k][0];
        float4 f1 = *(const float4*)&s_in[k][4];
        float4 f2 = *(const float4*)&s_in[k][8];
        float4 f3 = *(const float4*)&s_in[k][12];
        acc[0] += f0.x*w; acc[1] += f0.y*w; acc[2] += f0.z*w; acc[3] += f0.w*w;
        acc[4] += f1.x*w; acc[5] += f1.y*w; acc[6] += f1.z*w; acc[7] += f1.w*w;
        acc[8] += f2.x*w; acc[9] += f2.y*w; acc[10]+= f2.z*w; acc[11]+= f2.w*w;
        acc[12]+= f3.x*w; acc[13]+= f3.y*w; acc[14]+= f3.z*w; acc[15]+= f3.w*w;
    }
    #pragma unroll
    for (int i = 0; i < 16; ++i) {
        float v = acc[i];
        h[(n0 + i) * HID + tx] = s_in[tx][i] + silu(v);
    }
    if (tx < 48) {
        int i = tx / 3, c = tx % 3;
        int n = n0 + i;
        x[n * 3 + c] += agg_x[n * 3 + c] / (cnt[n] + 1.f);
    }
}

__global__ __launch_bounds__(64) void final_fb_kernel(
    const float* __restrict__ h, const float* __restrict__ x,
    const int* __restrict__ gmask,
    const float* __restrict__ W, const float* __restrict__ b,
    float* __restrict__ out)
{
    __shared__ float s_h[8][HID];
    int n0 = blockIdx.x * 8;
    int tx = threadIdx.x;
    for (int idx = tx; idx < 8 * HID; idx += 64) {
        int i = idx >> 7, k = idx & 127;
        s_h[i][k] = h[(n0 + i) * HID + k];
    }
    __syncthreads();
    float acc[8];
    float bv = b[tx];
    #pragma unroll
    for (int i = 0; i < 8; ++i) acc[i] = bv;
    for (int k = 0; k < HID; ++k) {
        float w = W[k * IN_DIM + tx];
        #pragma unroll
        for (int i = 0; i < 8; ++i) acc[i] += s_h[i][k] * w;
    }
    #pragma unroll
    for (int i = 0; i < 8; ++i) {
        int n = n0 + i;
        out[n * IN_DIM + tx] = gmask[n] ? acc[i] : 0.f;
    }
    if (tx < 24) {
        int i = tx / 3, c = tx % 3;
        int n = n0 + i;
        out[NN * IN_DIM + n * 3 + c] = gmask[n] ? x[n * 3 + c] : 0.f;
    }
}

extern "C" void kernel_launch(void* const* d_in, const int* in_sizes, int n_in,
                              void* d_out, int out_size, void* d_ws, size_t ws_size,
                              hipStream_t stream) {
    const float* H_t   = (const float*)d_in[0];
    const float* X_t   = (const float*)d_in[1];
    const float* cond  = (const float*)d_in[2];
    const float* t_in  = (const float*)d_in[3];
    const int*   edges = (const int*)d_in[4];
    const int*   etype = (const int*)d_in[5];
    const int*   gmask = (const int*)d_in[6];
    const float* W0 = (const float*)d_in[8];
    const float* b0 = (const float*)d_in[9];
    const float* W1 = (const float*)d_in[10];
    const float* b1 = (const float*)d_in[11];
    const float* W2 = (const float*)d_in[12];
    const float* b2 = (const float*)d_in[13];
    const float* edge_table = (const float*)d_in[14];
    const float* We = (const float*)d_in[15];
    const float* be = (const float*)d_in[16];
    const float* Wx = (const float*)d_in[17];
    const float* bx = (const float*)d_in[18];
    const float* Wh = (const float*)d_in[19];
    const float* bh = (const float*)d_in[20];
    const float* h2i_W = (const float*)d_in[21];
    const float* h2i_b = (const float*)d_in[22];

    char* p = (char*)d_ws;
    float* h = (float*)p;           p += (size_t)NN * HID * 4;
    u16* h_bf = (u16*)p;            p += (size_t)NN * HID * 2;
    float* x = (float*)p;           p += (size_t)NN * 3 * 4;
    float* wdiff = (float*)p;       p += (size_t)NE * 3 * 4;
    u16* msg = (u16*)p;             p += (size_t)NE * HID * 2;
    u16* Bpack = (u16*)p;           p += (size_t)PACK_TOT * 2;
    int* row_start = (int*)p;       p += (size_t)(NN + 4) * 4;
    int* deg = (int*)p;             p += (size_t)NN * 4;
    int* head = (int*)p;            p += (size_t)NN * 4;
    int* pos = (int*)p;             p += (size_t)NE * 4;
    size_t need = (size_t)(p - (char*)d_ws);

    if (ws_size >= need) {
        hipMemsetAsync(deg, 0, NN * sizeof(int), stream);
        hist_kernel<<<256, 256, 0, stream>>>(X_t, edges, x, deg);
        scan_kernel<<<1, 256, 0, stream>>>(deg, row_start, head);
        scatter_kernel<<<256, 256, 0, stream>>>(edges, head, pos);
        pack_all_kernel<<<(PACK_TOT + 255) / 256, 256, 0, stream>>>(
            We, W0, W1, W2, Wh, h2i_W, Bpack);
        node_mlp_mfma_kernel<<<NB64, 256, 0, stream>>>(
            H_t, cond, t_in,
            Bpack + OFF_W0, b0, Bpack + OFF_W1, b1, Bpack + OFF_W2, b2,
            h, h_bf);
        for (int l = 0; l < 3; ++l) {
            edge_mfma_kernel<<<NE / 64, 256, 0, stream>>>(
                h_bf, x, edges, etype, edge_table,
                Bpack + OFF_WE + (size_t)l * 40960, be + l * HID,
                Wx + l * HID, bx + l, pos, msg, wdiff);
            node_update_mfma_kernel<<<NB64, 256, 0, stream>>>(
                h, h_bf, x, msg, wdiff, row_start,
                Bpack + OFF_WH + (size_t)l * 32768, bh + l * HID);
        }
        final_mfma_kernel<<<NB64, 256, 0, stream>>>(
            h_bf, x, gmask, Bpack + OFF_H2I, h2i_b, (float*)d_out);
    } else {
        // fallback: scalar atomic path (~21 MB)
        float* ws    = (float*)d_ws;
        float* fh    = ws;
        float* fx    = fh + NN * HID;
        float* cnt   = fx + NN * 3;
        float* agg_m = cnt + NN;
        float* agg_x = agg_m + NN * HID;

        hipMemsetAsync(cnt, 0, NN * sizeof(float), stream);
        init_fb_kernel<<<256, 256, 0, stream>>>(X_t, edges, fx, cnt);
        node_mlp_kernel<<<NN / 16, 128, 0, stream>>>(H_t, cond, t_in,
                                                     W0, b0, W1, b1, W2, b2, fh);
        for (int l = 0; l < 3; ++l) {
            hipMemsetAsync(agg_m, 0, (size_t)NN * 131 * sizeof(float), stream);
            edge_gemm_fb_kernel<<<NE / TILE_E, 256, 0, stream>>>(
                fh, fx, edges, etype, edge_table,
                We + (size_t)l * DE * HID, be + l * HID,
                Wx + l * HID, bx + l, agg_m, agg_x);
            node_update_fb_kernel<<<NN / 16, 128, 0, stream>>>(
                fh, fx, agg_m, agg_x, cnt,
                Wh + (size_t)l * 256 * HID, bh + l * HID);
        }
        final_fb_kernel<<<NN / 8, 64, 0, stream>>>(fh, fx, gmask, h2i_W, h2i_b, (float*)d_out);
    }
}

// Round 7
// 465.819 us; speedup vs baseline: 7.2352x; 1.0406x over previous
//
#include <hip/hip_runtime.h>
#include <math.h>

#define NN 20000
#define NE 256000
#define IN_DIM 64
#define HID 128
#define DE 289     // 2*HID + 1 + 32
#define D0 320     // IN_DIM + 2*HID
#define TILE_E 64
#define NB64 313   // ceil(NN/64)
#define ETE 128    // edges per block (MFMA edge kernel)
#define NUB 32     // nodes per block (node update)

typedef unsigned short u16;
typedef unsigned int u32;
typedef __attribute__((ext_vector_type(8))) short short8;
typedef __attribute__((ext_vector_type(4))) float float4v;

// Bpack layout offsets (u16 elements)
#define OFF_WE   0          // 3 x 40960 (K=289 pad 320, N=128) — only K-tiles 0..3 used now
#define OFF_W0   122880     // 40960 (K=320, N=128)
#define OFF_W1   163840     // 16384 (K=128, N=128)
#define OFF_W2   180224     // 16384
#define OFF_WH   196608     // 3 x 32768 (K=256, N=128)
#define OFF_H2I  294912     // 8192 (K=128, N=64)
#define PACK_TOT 303104

static __device__ __forceinline__ u16 f2bf(float f) {
    unsigned int u = __float_as_uint(f);
    u += 0x7fffu + ((u >> 16) & 1u);
    return (u16)(u >> 16);
}
static __device__ __forceinline__ float bf2f(u16 s) {
    return __uint_as_float(((unsigned int)s) << 16);
}
static __device__ __forceinline__ uint4 pack8(const float* v) {
    uint4 r;
    r.x = (u32)f2bf(v[0]) | ((u32)f2bf(v[1]) << 16);
    r.y = (u32)f2bf(v[2]) | ((u32)f2bf(v[3]) << 16);
    r.z = (u32)f2bf(v[4]) | ((u32)f2bf(v[5]) << 16);
    r.w = (u32)f2bf(v[6]) | ((u32)f2bf(v[7]) << 16);
    return r;
}
static __device__ __forceinline__ float silu(float v) {
    return v * (1.f / (1.f + __expf(-v)));
}

// ================= CSR build =================
__global__ __launch_bounds__(256) void hist_kernel(
    const float* __restrict__ X_t, const int* __restrict__ edges,
    float* __restrict__ x, int* __restrict__ deg)
{
    int gid = blockIdx.x * blockDim.x + threadIdx.x;
    int stride = gridDim.x * blockDim.x;
    for (int i = gid; i < NN * 3; i += stride) x[i] = X_t[i];
    for (int e = gid; e < NE; e += stride)
        atomicAdd(&deg[edges[NE + e]], 1);
}

__global__ __launch_bounds__(256) void scan_kernel(
    const int* __restrict__ deg, int* __restrict__ row_start, int* __restrict__ head)
{
    __shared__ int s[256];
    int tx = threadIdx.x;
    const int per = (NN + 255) / 256;
    int st = tx * per, en = st + per;
    if (st > NN) st = NN;
    if (en > NN) en = NN;
    int sum = 0;
    for (int i = st; i < en; ++i) sum += deg[i];
    s[tx] = sum;
    __syncthreads();
    for (int off = 1; off < 256; off <<= 1) {
        int t = (tx >= off) ? s[tx - off] : 0;
        __syncthreads();
        s[tx] += t;
        __syncthreads();
    }
    int run = (tx == 0) ? 0 : s[tx - 1];
    for (int i = st; i < en; ++i) {
        row_start[i] = run; head[i] = run; run += deg[i];
    }
    if (tx == 255) row_start[NN] = run;
}

__global__ __launch_bounds__(256) void scatter_kernel(
    const int* __restrict__ edges, int* __restrict__ head, int* __restrict__ pos)
{
    int gid = blockIdx.x * blockDim.x + threadIdx.x;
    int stride = gridDim.x * blockDim.x;
    for (int e = gid; e < NE; e += stride)
        pos[e] = atomicAdd(&head[edges[NE + e]], 1);
}

// ================= weight frag-order packing =================
__global__ __launch_bounds__(256) void pack_all_kernel(
    const float* __restrict__ We, const float* __restrict__ W0,
    const float* __restrict__ W1, const float* __restrict__ W2,
    const float* __restrict__ Wh, const float* __restrict__ h2i,
    u16* __restrict__ Bp)
{
    int idx = blockIdx.x * 256 + threadIdx.x;
    if (idx >= PACK_TOT) return;
    const float* src; int N = 128, Ksrc; int r;
    if (idx < OFF_W0) {
        int layer = idx / 40960; r = idx - layer * 40960;
        src = We + (size_t)layer * DE * HID; Ksrc = DE;
    } else if (idx < OFF_W1) { r = idx - OFF_W0; src = W0; Ksrc = 320; }
    else if (idx < OFF_W2)   { r = idx - OFF_W1; src = W1; Ksrc = 128; }
    else if (idx < OFF_WH)   { r = idx - OFF_W2; src = W2; Ksrc = 128; }
    else if (idx < OFF_H2I) {
        int t = idx - OFF_WH; int layer = t / 32768; r = t - layer * 32768;
        src = Wh + (size_t)layer * 256 * HID; Ksrc = 256;
    } else { r = idx - OFF_H2I; src = h2i; Ksrc = 128; N = 64; }
    int ntc = N / 16;
    int j = r & 7, lane = (r >> 3) & 63;
    int rem = r >> 9;
    int nt = rem % ntc, ks = rem / ntc;
    int k = ks * 32 + ((lane >> 4) << 3) + j;
    int c = nt * 16 + (lane & 15);
    Bp[idx] = f2bf((k < Ksrc) ? src[(size_t)k * N + c] : 0.f);
}

// ================= edge tail precompute (f32) =================
// tv[l][t][f] = be[l][f] + sum_k edge_table[t][k] * We[l][257+k][f]
// wed2[l][f]  = We[l][256][f]
__global__ __launch_bounds__(256) void precomp_tv_kernel(
    const float* __restrict__ edge_table, const float* __restrict__ We,
    const float* __restrict__ be, float* __restrict__ tv, float* __restrict__ wed2)
{
    int idx = blockIdx.x * 256 + threadIdx.x;
    if (idx < 768) {
        int f = idx & 127, t = (idx >> 7) & 1, l = idx >> 8;
        float acc = be[l * 128 + f];
        const float* W = We + (size_t)l * DE * HID;
        #pragma unroll
        for (int k = 0; k < 32; ++k)
            acc += edge_table[t * 32 + k] * W[(size_t)(257 + k) * HID + f];
        tv[l * 256 + t * 128 + f] = acc;
    } else if (idx < 1152) {
        int r = idx - 768;
        int f = r & 127, l = r >> 7;
        wed2[l * 128 + f] = We[(size_t)l * DE * HID + (size_t)256 * HID + f];
    }
}

// ================= node MLP: MFMA, 64 nodes/block =================
__global__ __launch_bounds__(256) void node_mlp_mfma_kernel(
    const float* __restrict__ H_t, const float* __restrict__ cond,
    const float* __restrict__ t_in,
    const u16* __restrict__ W0p, const float* __restrict__ b0,
    const u16* __restrict__ W1p, const float* __restrict__ b1,
    const u16* __restrict__ W2p, const float* __restrict__ b2,
    float* __restrict__ h, u16* __restrict__ h_bf)
{
    __shared__ u16 s_A[64 * 64];
    __shared__ u16 s_B[64 * 128];
    __shared__ u16 s_h[64 * 128];
    __shared__ float s_t[64];

    int tx = threadIdx.x;
    int n0 = blockIdx.x * 64;
    int l = tx & 63, w = tx >> 6;
    int mt_base = (w & 1) * 2, nt_base = (w >> 1) * 4;
    const float cfr = -logf(10000.f) / 63.f;

    if (tx < 64) s_t[tx] = (n0 + tx < NN) ? t_in[n0 + tx] : 0.f;

    float4v acc[2][4];
    #pragma unroll
    for (int mi = 0; mi < 2; ++mi)
        #pragma unroll
        for (int ni = 0; ni < 4; ++ni) acc[mi][ni] = (float4v){0.f,0.f,0.f,0.f};

    for (int t = 0; t < 5; ++t) {
        __syncthreads();
        #pragma unroll
        for (int it = 0; it < 2; ++it) {
            int flat = it * 256 + tx;
            int n = flat >> 3, sl = flat & 7;
            int c = sl ^ (n & 7);
            int k0 = t * 64 + c * 8;
            float tv8[8];
            int gn = n0 + n;
            if (gn < NN) {
                if (k0 < 192) {
                    const float* src = (k0 < 64) ? &H_t[(size_t)gn * IN_DIM + k0]
                                                 : &cond[(size_t)gn * HID + (k0 - 64)];
                    float4 a = *(const float4*)src;
                    float4 b = *(const float4*)(src + 4);
                    tv8[0]=a.x; tv8[1]=a.y; tv8[2]=a.z; tv8[3]=a.w;
                    tv8[4]=b.x; tv8[5]=b.y; tv8[6]=b.z; tv8[7]=b.w;
                } else {
                    float tv = s_t[n];
                    int jj = (k0 - 192) & 63;
                    bool is_sin = (k0 < 256);
                    #pragma unroll
                    for (int jx = 0; jx < 8; ++jx) {
                        float ang = tv * __expf(cfr * (float)(jj + jx));
                        tv8[jx] = is_sin ? __sinf(ang) : __cosf(ang);
                    }
                }
            } else {
                #pragma unroll
                for (int jx = 0; jx < 8; ++jx) tv8[jx] = 0.f;
            }
            *(uint4*)&s_A[n * 64 + sl * 8] = pack8(tv8);
        }
        #pragma unroll
        for (int it = 0; it < 4; ++it) {
            int flat = it * 256 + tx;
            ((uint4*)s_B)[flat] = ((const uint4*)(W0p + (size_t)t * 8192))[flat];
        }
        __syncthreads();
        #pragma unroll
        for (int s = 0; s < 2; ++s) {
            short8 af[2], bfv[4];
            #pragma unroll
            for (int mi = 0; mi < 2; ++mi) {
                int m = (mt_base + mi) * 16 + (l & 15);
                int c = s * 4 + (l >> 4);
                int slot = c ^ (l & 7);
                af[mi] = *(const short8*)(s_A + m * 64 + slot * 8);
            }
            #pragma unroll
            for (int ni = 0; ni < 4; ++ni)
                bfv[ni] = *(const short8*)(s_B + ((s * 8 + nt_base + ni) * 64 + l) * 8);
            #pragma unroll
            for (int mi = 0; mi < 2; ++mi)
                #pragma unroll
                for (int ni = 0; ni < 4; ++ni)
                    acc[mi][ni] = __builtin_amdgcn_mfma_f32_16x16x32_bf16(
                        af[mi], bfv[ni], acc[mi][ni], 0, 0, 0);
        }
    }
    #pragma unroll
    for (int mi = 0; mi < 2; ++mi) {
        #pragma unroll
        for (int ni = 0; ni < 4; ++ni) {
            int f = (nt_base + ni) * 16 + (l & 15);
            float bv = b0[f];
            #pragma unroll
            for (int r = 0; r < 4; ++r) {
                int m = (mt_base + mi) * 16 + (l >> 4) * 4 + r;
                float v = fmaxf(acc[mi][ni][r] + bv, 0.f);
                int slot = (f >> 3) ^ (m & 7);
                s_h[m * 128 + slot * 8 + (f & 7)] = f2bf(v);
            }
            acc[mi][ni] = (float4v){0.f,0.f,0.f,0.f};
        }
    }
    for (int t = 0; t < 2; ++t) {
        __syncthreads();
        #pragma unroll
        for (int it = 0; it < 4; ++it) {
            int flat = it * 256 + tx;
            ((uint4*)s_B)[flat] = ((const uint4*)(W1p + (size_t)t * 8192))[flat];
        }
        __syncthreads();
        #pragma unroll
        for (int s = 0; s < 2; ++s) {
            short8 af[2], bfv[4];
            #pragma unroll
            for (int mi = 0; mi < 2; ++mi) {
                int m = (mt_base + mi) * 16 + (l & 15);
                int c = t * 8 + s * 4 + (l >> 4);
                int slot = c ^ (l & 7);
                af[mi] = *(const short8*)(s_h + m * 128 + slot * 8);
            }
            #pragma unroll
            for (int ni = 0; ni < 4; ++ni)
                bfv[ni] = *(const short8*)(s_B + ((s * 8 + nt_base + ni) * 64 + l) * 8);
            #pragma unroll
            for (int mi = 0; mi < 2; ++mi)
                #pragma unroll
                for (int ni = 0; ni < 4; ++ni)
                    acc[mi][ni] = __builtin_amdgcn_mfma_f32_16x16x32_bf16(
                        af[mi], bfv[ni], acc[mi][ni], 0, 0, 0);
        }
    }
    __syncthreads();
    #pragma unroll
    for (int mi = 0; mi < 2; ++mi) {
        #pragma unroll
        for (int ni = 0; ni < 4; ++ni) {
            int f = (nt_base + ni) * 16 + (l & 15);
            float bv = b1[f];
            #pragma unroll
            for (int r = 0; r < 4; ++r) {
                int m = (mt_base + mi) * 16 + (l >> 4) * 4 + r;
                float v = fmaxf(acc[mi][ni][r] + bv, 0.f);
                int slot = (f >> 3) ^ (m & 7);
                s_h[m * 128 + slot * 8 + (f & 7)] = f2bf(v);
            }
            acc[mi][ni] = (float4v){0.f,0.f,0.f,0.f};
        }
    }
    for (int t = 0; t < 2; ++t) {
        __syncthreads();
        #pragma unroll
        for (int it = 0; it < 4; ++it) {
            int flat = it * 256 + tx;
            ((uint4*)s_B)[flat] = ((const uint4*)(W2p + (size_t)t * 8192))[flat];
        }
        __syncthreads();
        #pragma unroll
        for (int s = 0; s < 2; ++s) {
            short8 af[2], bfv[4];
            #pragma unroll
            for (int mi = 0; mi < 2; ++mi) {
                int m = (mt_base + mi) * 16 + (l & 15);
                int c = t * 8 + s * 4 + (l >> 4);
                int slot = c ^ (l & 7);
                af[mi] = *(const short8*)(s_h + m * 128 + slot * 8);
            }
            #pragma unroll
            for (int ni = 0; ni < 4; ++ni)
                bfv[ni] = *(const short8*)(s_B + ((s * 8 + nt_base + ni) * 64 + l) * 8);
            #pragma unroll
            for (int mi = 0; mi < 2; ++mi)
                #pragma unroll
                for (int ni = 0; ni < 4; ++ni)
                    acc[mi][ni] = __builtin_amdgcn_mfma_f32_16x16x32_bf16(
                        af[mi], bfv[ni], acc[mi][ni], 0, 0, 0);
        }
    }
    #pragma unroll
    for (int mi = 0; mi < 2; ++mi) {
        #pragma unroll
        for (int ni = 0; ni < 4; ++ni) {
            int f = (nt_base + ni) * 16 + (l & 15);
            float bv = b2[f];
            #pragma unroll
            for (int r = 0; r < 4; ++r) {
                int m = (mt_base + mi) * 16 + (l >> 4) * 4 + r;
                int gn = n0 + m;
                if (gn < NN) {
                    float v = acc[mi][ni][r] + bv;
                    h[(size_t)gn * HID + f] = v;
                    h_bf[(size_t)gn * HID + f] = f2bf(v);
                }
            }
        }
    }
}

// ================= edge MFMA GEMM: 128 edges/block, K=256, tail folded into epilogue =================
__global__ __launch_bounds__(256) void edge_mfma_kernel(
    const u16* __restrict__ h_bf, const float* __restrict__ x,
    const int* __restrict__ edges, const int* __restrict__ etype,
    const u16* __restrict__ Bpack_l,
    const float* __restrict__ tv_l,    // 2 x 128, includes be
    const float* __restrict__ wed2_l,  // 128
    const float* __restrict__ Wx_l, const float* __restrict__ bx_l,
    const int* __restrict__ pos,
    u16* __restrict__ msg, float* __restrict__ wdiff)
{
    __shared__ u16 s_AB[ETE * 132];    // GEMM: A=[0,8192) B=[8192,16384); epilogue: out stride 132
    __shared__ float s_tv[2][128];
    __shared__ float s_wx[128], s_wed2[128];
    __shared__ int s_src[ETE], s_dst[ETE], s_pos[ETE], s_et[ETE];
    __shared__ float s_diff[ETE][3], s_d2[ETE];

    u16* s_A = s_AB;
    u16* s_B = s_AB + 8192;

    int tx = threadIdx.x;
    int e0 = blockIdx.x * ETE;
    int l = tx & 63, w = tx >> 6;
    int mt_base = (w & 1) * 4;
    int nt_base = (w >> 1) * 4;

    if (tx < ETE) {
        int s = edges[e0 + tx], d = edges[NE + e0 + tx];
        s_src[tx] = s; s_dst[tx] = d;
        s_pos[tx] = pos[e0 + tx]; s_et[tx] = etype[e0 + tx];
        float dx = x[s*3+0]-x[d*3+0], dy = x[s*3+1]-x[d*3+1], dz = x[s*3+2]-x[d*3+2];
        s_diff[tx][0] = dx; s_diff[tx][1] = dy; s_diff[tx][2] = dz;
        s_d2[tx] = dx*dx + dy*dy + dz*dz;
    }
    ((float*)s_tv)[tx] = tv_l[tx];                  // 256 floats
    if (tx < 128) s_wx[tx] = Wx_l[tx];
    else          s_wed2[tx - 128] = wed2_l[tx - 128];
    __syncthreads();

    float4v acc[4][4];
    #pragma unroll
    for (int mi = 0; mi < 4; ++mi)
        #pragma unroll
        for (int ni = 0; ni < 4; ++ni)
            acc[mi][ni] = (float4v){0.f, 0.f, 0.f, 0.f};

    for (int t = 0; t < 4; ++t) {
        __syncthreads();
        // A: gather 128 rows x 128B (src for t<2, dst for t>=2), xor-swizzled chunks
        #pragma unroll
        for (int it = 0; it < 4; ++it) {
            int flat = it * 256 + tx;
            int e = flat >> 3, sl = flat & 7;
            int c = sl ^ (e & 7);
            int row = (t < 2) ? s_src[e] : s_dst[e];
            uint4 v = *(const uint4*)(h_bf + (size_t)row * 128 + (t & 1) * 64 + c * 8);
            *(uint4*)(s_A + e * 64 + sl * 8) = v;
        }
        // B: contiguous frag-order copy (K-tiles 0..3 of Bpack)
        #pragma unroll
        for (int it = 0; it < 4; ++it) {
            int flat = it * 256 + tx;
            ((uint4*)s_B)[flat] = ((const uint4*)(Bpack_l + (size_t)t * 8192))[flat];
        }
        __syncthreads();

        #pragma unroll
        for (int s = 0; s < 2; ++s) {
            short8 af[4], bfv[4];
            #pragma unroll
            for (int mi = 0; mi < 4; ++mi) {
                int m = (mt_base + mi) * 16 + (l & 15);
                int c = s * 4 + (l >> 4);
                int slot = c ^ (l & 7);
                af[mi] = *(const short8*)(s_A + m * 64 + slot * 8);
            }
            #pragma unroll
            for (int ni = 0; ni < 4; ++ni)
                bfv[ni] = *(const short8*)(s_B + ((s * 8 + nt_base + ni) * 64 + l) * 8);
            #pragma unroll
            for (int mi = 0; mi < 4; ++mi)
                #pragma unroll
                for (int ni = 0; ni < 4; ++ni)
                    acc[mi][ni] = __builtin_amdgcn_mfma_f32_16x16x32_bf16(
                        af[mi], bfv[ni], acc[mi][ni], 0, 0, 0);
        }
    }
    __syncthreads();

    // epilogue: v = acc + tv[et][f] + d2*wed2[f]; silu -> out tile stride 132
    #pragma unroll
    for (int mi = 0; mi < 4; ++mi) {
        int ebase = (mt_base + mi) * 16 + (l >> 4) * 4;
        #pragma unroll
        for (int ni = 0; ni < 4; ++ni) {
            int f = (nt_base + ni) * 16 + (l & 15);
            float wd = s_wed2[f];
            #pragma unroll
            for (int r = 0; r < 4; ++r) {
                int e = ebase + r;
                float v = acc[mi][ni][r] + s_tv[s_et[e]][f] + s_d2[e] * wd;
                s_AB[e * 132 + f] = f2bf(silu(v));
            }
        }
    }
    __syncthreads();

    // wsum = msg @ Wx (16 lanes per edge-group of 8 edges)
    {
        int tf = tx & 15, te = tx >> 4;
        float wsum[8];
        #pragma unroll
        for (int i = 0; i < 8; ++i) {
            int e = te * 8 + i;
            const u16* rp = s_AB + e * 132 + tf * 8;
            float p = 0.f;
            #pragma unroll
            for (int j = 0; j < 8; ++j) p += bf2f(rp[j]) * s_wx[tf * 8 + j];
            wsum[i] = p;
        }
        #pragma unroll
        for (int off = 1; off < 16; off <<= 1) {
            #pragma unroll
            for (int i = 0; i < 8; ++i) wsum[i] += __shfl_xor(wsum[i], off);
        }
        float bxv = bx_l[0];
        if (tf < 3) {
            #pragma unroll
            for (int i = 0; i < 8; ++i) {
                int e = te * 8 + i;
                wdiff[s_pos[e] * 3 + tf] = s_diff[e][tf] * (wsum[i] + bxv);
            }
        }
    }
    // msg stores: 128 rows x 16 uint4
    #pragma unroll
    for (int it = 0; it < 8; ++it) {
        int flat = it * 256 + tx;
        int e = flat >> 4, c = flat & 15;
        *((uint4*)(msg + (size_t)s_pos[e] * 128) + c) = *(const uint4*)(s_AB + e * 132 + c * 8);
    }
}

// ================= node update: CSR agg + MFMA Wh GEMM, 32 nodes/block =================
__global__ __launch_bounds__(256) void node_update_mfma_kernel(
    float* __restrict__ h, u16* __restrict__ h_bf, float* __restrict__ x,
    const u16* __restrict__ msg, const float* __restrict__ wdiff,
    const int* __restrict__ row_start,
    const u16* __restrict__ Whp_l, const float* __restrict__ bh_l)
{
    __shared__ u16 s_A[NUB * 256];   // [node][256k] xor-swizzled: h | agg_m
    __shared__ u16 s_B[64 * 128];
    __shared__ int s_rs[NUB + 1];

    int tx = threadIdx.x;
    int n0 = blockIdx.x * NUB;
    int l = tx & 63, w = tx >> 6;
    int mt = w & 1, nt_base = (w >> 1) * 4;

    if (tx < NUB + 1) s_rs[tx] = row_start[n0 + tx];
    // stage h_bf (chunks 0..15): 32 nodes x 16 uint4 = 512
    #pragma unroll
    for (int it = 0; it < 2; ++it) {
        int flat = it * 256 + tx;
        int n = flat >> 4, c = flat & 15;
        int slot = c ^ (n & 7);
        uint4 v = *(const uint4*)(h_bf + (size_t)(n0 + n) * 128 + c * 8);
        *(uint4*)&s_A[n * 256 + slot * 8] = v;
    }
    __syncthreads();
    // aggregation: thread -> node tx>>3, feats (tx&7)*16..+15 (chunks 16..31)
    {
        int i = tx >> 3, p = tx & 7;
        int rs = s_rs[i], re = s_rs[i + 1];
        float ag[16];
        #pragma unroll
        for (int q = 0; q < 16; ++q) ag[q] = 0.f;
        for (int j = rs; j < re; ++j) {
            const uint4* row = (const uint4*)(msg + (size_t)j * 128 + p * 16);
            #pragma unroll
            for (int q = 0; q < 2; ++q) {
                uint4 v = row[q];
                ag[q*8+0] += bf2f((u16)(v.x & 0xffffu));
                ag[q*8+1] += bf2f((u16)(v.x >> 16));
                ag[q*8+2] += bf2f((u16)(v.y & 0xffffu));
                ag[q*8+3] += bf2f((u16)(v.y >> 16));
                ag[q*8+4] += bf2f((u16)(v.z & 0xffffu));
                ag[q*8+5] += bf2f((u16)(v.z >> 16));
                ag[q*8+6] += bf2f((u16)(v.w & 0xffffu));
                ag[q*8+7] += bf2f((u16)(v.w >> 16));
            }
        }
        #pragma unroll
        for (int q = 0; q < 2; ++q) {
            int c2 = 16 + p * 2 + q;
            int slot = c2 ^ (i & 7);
            *(uint4*)&s_A[i * 256 + slot * 8] = pack8(&ag[q * 8]);
        }
    }
    // x update: 32 nodes x 3
    if (tx < NUB * 3) {
        int i = tx / 3, c = tx % 3;
        int gn = n0 + i;
        int rs = s_rs[i], re = s_rs[i + 1];
        float sxx = 0.f;
        for (int j = rs; j < re; ++j) sxx += wdiff[j * 3 + c];
        x[gn * 3 + c] += sxx / ((float)(re - rs) + 1.f);
    }

    float4v acc[4];
    #pragma unroll
    for (int ni = 0; ni < 4; ++ni) acc[ni] = (float4v){0.f,0.f,0.f,0.f};

    for (int t = 0; t < 4; ++t) {
        __syncthreads();
        #pragma unroll
        for (int it = 0; it < 4; ++it) {
            int flat = it * 256 + tx;
            ((uint4*)s_B)[flat] = ((const uint4*)(Whp_l + (size_t)t * 8192))[flat];
        }
        __syncthreads();
        #pragma unroll
        for (int s = 0; s < 2; ++s) {
            short8 af, bfv[4];
            {
                int m = mt * 16 + (l & 15);
                int c = t * 8 + s * 4 + (l >> 4);
                int slot = c ^ (l & 7);
                af = *(const short8*)(s_A + m * 256 + slot * 8);
            }
            #pragma unroll
            for (int ni = 0; ni < 4; ++ni)
                bfv[ni] = *(const short8*)(s_B + ((s * 8 + nt_base + ni) * 64 + l) * 8);
            #pragma unroll
            for (int ni = 0; ni < 4; ++ni)
                acc[ni] = __builtin_amdgcn_mfma_f32_16x16x32_bf16(
                    af, bfv[ni], acc[ni], 0, 0, 0);
        }
    }
    // epilogue: h += silu(acc + bh)
    #pragma unroll
    for (int ni = 0; ni < 4; ++ni) {
        int f = (nt_base + ni) * 16 + (l & 15);
        float bv = bh_l[f];
        #pragma unroll
        for (int r = 0; r < 4; ++r) {
            int m = mt * 16 + (l >> 4) * 4 + r;
            int gn = n0 + m;
            float v = acc[ni][r] + bv;
            float hn = h[(size_t)gn * HID + f] + silu(v);
            h[(size_t)gn * HID + f] = hn;
            h_bf[(size_t)gn * HID + f] = f2bf(hn);
        }
    }
}

// ================= final: MFMA h2i, 64 nodes/block =================
__global__ __launch_bounds__(256) void final_mfma_kernel(
    const u16* __restrict__ h_bf, const float* __restrict__ x,
    const int* __restrict__ gmask,
    const u16* __restrict__ h2ip, const float* __restrict__ b,
    float* __restrict__ out)
{
    __shared__ u16 s_A[64 * 128];
    __shared__ u16 s_B[4096];       // K64 x N64 tile = 512 uint4

    int tx = threadIdx.x;
    int n0 = blockIdx.x * 64;
    int l = tx & 63, w = tx >> 6;
    int mt_base = (w & 1) * 2, nt_base = (w >> 1) * 2;

    #pragma unroll
    for (int it = 0; it < 4; ++it) {
        int flat = it * 256 + tx;
        int n = flat >> 4, c = flat & 15;
        int slot = c ^ (n & 7);
        int gn = n0 + n;
        uint4 v = make_uint4(0,0,0,0);
        if (gn < NN) v = *(const uint4*)(h_bf + (size_t)gn * 128 + c * 8);
        *(uint4*)&s_A[n * 128 + slot * 8] = v;
    }

    float4v acc[2][2];
    #pragma unroll
    for (int mi = 0; mi < 2; ++mi)
        #pragma unroll
        for (int ni = 0; ni < 2; ++ni) acc[mi][ni] = (float4v){0.f,0.f,0.f,0.f};

    for (int t = 0; t < 2; ++t) {
        __syncthreads();
        #pragma unroll
        for (int it = 0; it < 2; ++it) {
            int flat = it * 256 + tx;
            ((uint4*)s_B)[flat] = ((const uint4*)(h2ip + (size_t)t * 4096))[flat];
        }
        __syncthreads();
        #pragma unroll
        for (int s = 0; s < 2; ++s) {
            short8 af[2], bfv[2];
            #pragma unroll
            for (int mi = 0; mi < 2; ++mi) {
                int m = (mt_base + mi) * 16 + (l & 15);
                int c = t * 8 + s * 4 + (l >> 4);
                int slot = c ^ (l & 7);
                af[mi] = *(const short8*)(s_A + m * 128 + slot * 8);
            }
            #pragma unroll
            for (int ni = 0; ni < 2; ++ni)
                bfv[ni] = *(const short8*)(s_B + ((s * 4 + nt_base + ni) * 64 + l) * 8);
            #pragma unroll
            for (int mi = 0; mi < 2; ++mi)
                #pragma unroll
                for (int ni = 0; ni < 2; ++ni)
                    acc[mi][ni] = __builtin_amdgcn_mfma_f32_16x16x32_bf16(
                        af[mi], bfv[ni], acc[mi][ni], 0, 0, 0);
        }
    }
    #pragma unroll
    for (int mi = 0; mi < 2; ++mi) {
        #pragma unroll
        for (int ni = 0; ni < 2; ++ni) {
            int f = (nt_base + ni) * 16 + (l & 15);
            float bv = b[f];
            #pragma unroll
            for (int r = 0; r < 4; ++r) {
                int m = (mt_base + mi) * 16 + (l >> 4) * 4 + r;
                int gn = n0 + m;
                if (gn < NN)
                    out[(size_t)gn * IN_DIM + f] = gmask[gn] ? (acc[mi][ni][r] + bv) : 0.f;
            }
        }
    }
    if (tx < 192) {
        int i = tx / 3, c = tx % 3;
        int gn = n0 + i;
        if (gn < NN)
            out[(size_t)NN * IN_DIM + gn * 3 + c] = gmask[gn] ? x[gn * 3 + c] : 0.f;
    }
}

// ================= fallback path (atomic, scalar; used only if ws too small) =================
__global__ __launch_bounds__(256) void init_fb_kernel(
    const float* __restrict__ X_t, const int* __restrict__ edges,
    float* __restrict__ x, float* __restrict__ cnt)
{
    int gid = blockIdx.x * blockDim.x + threadIdx.x;
    int stride = gridDim.x * blockDim.x;
    for (int i = gid; i < NN * 3; i += stride) x[i] = X_t[i];
    for (int e = gid; e < NE; e += stride)
        atomicAdd(&cnt[edges[NE + e]], 1.0f);
}

__global__ __launch_bounds__(128) void node_mlp_kernel(
    const float* __restrict__ H_t, const float* __restrict__ cond,
    const float* __restrict__ t_in,
    const float* __restrict__ W0, const float* __restrict__ b0,
    const float* __restrict__ W1, const float* __restrict__ b1,
    const float* __restrict__ W2, const float* __restrict__ b2,
    float* __restrict__ h)
{
    __shared__ float s_feat[D0][20];
    __shared__ float s_h0[HID][20];
    __shared__ float s_h1[HID][20];
    int n0 = blockIdx.x * 16;
    int tx = threadIdx.x;

    for (int idx = tx; idx < 16 * IN_DIM; idx += 128) {
        int i = idx >> 6, k = idx & 63;
        s_feat[k][i] = H_t[(n0 + i) * IN_DIM + k];
    }
    for (int idx = tx; idx < 16 * HID; idx += 128) {
        int i = idx >> 7, k = idx & 127;
        s_feat[IN_DIM + k][i] = cond[(n0 + i) * HID + k];
    }
    const float cfr = -logf(10000.f) / 63.f;
    for (int idx = tx; idx < 16 * HID; idx += 128) {
        int i = idx >> 7, k = idx & 127;
        float tv = t_in[n0 + i];
        int jj = k & 63;
        float ang = tv * __expf(cfr * (float)jj);
        s_feat[IN_DIM + HID + k][i] = (k < 64) ? __sinf(ang) : __cosf(ang);
    }
    __syncthreads();

    float acc[16];
    {
        float bv = b0[tx];
        #pragma unroll
        for (int i = 0; i < 16; ++i) acc[i] = bv;
        for (int k = 0; k < D0; ++k) {
            float w = W0[k * HID + tx];
            float4 f0 = *(const float4*)&s_feat[k][0];
            float4 f1 = *(const float4*)&s_feat[k][4];
            float4 f2 = *(const float4*)&s_feat[k][8];
            float4 f3 = *(const float4*)&s_feat[k][12];
            acc[0] += f0.x*w; acc[1] += f0.y*w; acc[2] += f0.z*w; acc[3] += f0.w*w;
            acc[4] += f1.x*w; acc[5] += f1.y*w; acc[6] += f1.z*w; acc[7] += f1.w*w;
            acc[8] += f2.x*w; acc[9] += f2.y*w; acc[10]+= f2.z*w; acc[11]+= f2.w*w;
            acc[12]+= f3.x*w; acc[13]+= f3.y*w; acc[14]+= f3.z*w; acc[15]+= f3.w*w;
        }
        #pragma unroll
        for (int i = 0; i < 16; ++i) s_h0[tx][i] = fmaxf(acc[i], 0.f);
    }
    __syncthreads();
    {
        float bv = b1[tx];
        #pragma unroll
        for (int i = 0; i < 16; ++i) acc[i] = bv;
        for (int k = 0; k < HID; ++k) {
            float w = W1[k * HID + tx];
            float4 f0 = *(const float4*)&s_h0[k][0];
            float4 f1 = *(const float4*)&s_h0[k][4];
            float4 f2 = *(const float4*)&s_h0[k][8];
            float4 f3 = *(const float4*)&s_h0[k][12];
            acc[0] += f0.x*w; acc[1] += f0.y*w; acc[2] += f0.z*w; acc[3] += f0.w*w;
            acc[4] += f1.x*w; acc[5] += f1.y*w; acc[6] += f1.z*w; acc[7] += f1.w*w;
            acc[8] += f2.x*w; acc[9] += f2.y*w; acc[10]+= f2.z*w; acc[11]+= f2.w*w;
            acc[12]+= f3.x*w; acc[13]+= f3.y*w; acc[14]+= f3.z*w; acc[15]+= f3.w*w;
        }
        #pragma unroll
        for (int i = 0; i < 16; ++i) s_h1[tx][i] = fmaxf(acc[i], 0.f);
    }
    __syncthreads();
    {
        float bv = b2[tx];
        #pragma unroll
        for (int i = 0; i < 16; ++i) acc[i] = bv;
        for (int k = 0; k < HID; ++k) {
            float w = W2[k * HID + tx];
            float4 f0 = *(const float4*)&s_h1[k][0];
            float4 f1 = *(const float4*)&s_h1[k][4];
            float4 f2 = *(const float4*)&s_h1[k][8];
            float4 f3 = *(const float4*)&s_h1[k][12];
            acc[0] += f0.x*w; acc[1] += f0.y*w; acc[2] += f0.z*w; acc[3] += f0.w*w;
            acc[4] += f1.x*w; acc[5] += f1.y*w; acc[6] += f1.z*w; acc[7] += f1.w*w;
            acc[8] += f2.x*w; acc[9] += f2.y*w; acc[10]+= f2.z*w; acc[11]+= f2.w*w;
            acc[12]+= f3.x*w; acc[13]+= f3.y*w; acc[14]+= f3.z*w; acc[15]+= f3.w*w;
        }
        #pragma unroll
        for (int i = 0; i < 16; ++i) h[(n0 + i) * HID + tx] = acc[i];
    }
}

__global__ __launch_bounds__(256) void edge_gemm_fb_kernel(
    const float* __restrict__ h, const float* __restrict__ x,
    const int* __restrict__ edges, const int* __restrict__ etype,
    const float* __restrict__ edge_table,
    const float* __restrict__ We_l, const float* __restrict__ be_l,
    const float* __restrict__ Wx_l, const float* __restrict__ bx_l,
    float* __restrict__ agg_m, float* __restrict__ agg_x)
{
    __shared__ int s_src[TILE_E], s_dst[TILE_E];
    __shared__ float s_diff[TILE_E][3];
    __shared__ float s_tail[TILE_E][36];
    __shared__ float s_Af[TILE_E][36];
    __shared__ float s_Bf[33][HID];
    __shared__ float s_wx[HID];

    int e0 = blockIdx.x * TILE_E;
    int tx = threadIdx.x;
    int tf = tx & 15;
    int te = tx >> 4;

    if (tx < TILE_E) {
        int s = edges[e0 + tx];
        int d = edges[NE + e0 + tx];
        s_src[tx] = s; s_dst[tx] = d;
        float dx = x[s * 3 + 0] - x[d * 3 + 0];
        float dy = x[s * 3 + 1] - x[d * 3 + 1];
        float dz = x[s * 3 + 2] - x[d * 3 + 2];
        s_diff[tx][0] = dx; s_diff[tx][1] = dy; s_diff[tx][2] = dz;
        s_tail[tx][0] = dx * dx + dy * dy + dz * dz;
        int et = etype[e0 + tx];
        #pragma unroll
        for (int j = 0; j < 32; ++j) s_tail[tx][1 + j] = edge_table[et * 32 + j];
    }
    if (tx < HID) s_wx[tx] = Wx_l[tx];
    __syncthreads();

    float acc[4][8];
    #pragma unroll
    for (int i = 0; i < 4; ++i)
        #pragma unroll
        for (int j = 0; j < 8; ++j) acc[i][j] = 0.f;

    for (int t = 0; t < 9; ++t) {
        int k0 = t * 32;
        int klen = (t == 8) ? 33 : 32;
        __syncthreads();
        if (t < 8) {
            const bool use_src = (t < 4);
            int kbase = (t & 3) * 32;
            for (int q4 = tx; q4 < TILE_E * 8; q4 += 256) {
                int e = q4 >> 3, q = q4 & 7;
                int row = use_src ? s_src[e] : s_dst[e];
                float4 v = *(const float4*)&h[row * HID + kbase + q * 4];
                *(float4*)&s_Af[e][q * 4] = v;
            }
        }
        for (int q4 = tx; q4 < klen * 32; q4 += 256) {
            int kk = q4 >> 5, c4 = q4 & 31;
            float4 v = *(const float4*)&We_l[(k0 + kk) * HID + c4 * 4];
            *(float4*)&s_Bf[kk][c4 * 4] = v;
        }
        __syncthreads();
        const float (*Asrc)[36] = (t == 8) ? (const float (*)[36])s_tail
                                           : (const float (*)[36])s_Af;
        for (int kk = 0; kk < klen; ++kk) {
            float a0 = Asrc[te * 4 + 0][kk];
            float a1 = Asrc[te * 4 + 1][kk];
            float a2 = Asrc[te * 4 + 2][kk];
            float a3 = Asrc[te * 4 + 3][kk];
            float4 bv0 = *(const float4*)&s_Bf[kk][tf * 8];
            float4 bv1 = *(const float4*)&s_Bf[kk][tf * 8 + 4];
            float b[8] = {bv0.x, bv0.y, bv0.z, bv0.w, bv1.x, bv1.y, bv1.z, bv1.w};
            #pragma unroll
            for (int j = 0; j < 8; ++j) {
                acc[0][j] += a0 * b[j];
                acc[1][j] += a1 * b[j];
                acc[2][j] += a2 * b[j];
                acc[3][j] += a3 * b[j];
            }
        }
    }

    float wsum[4];
    #pragma unroll
    for (int i = 0; i < 4; ++i) {
        float p = 0.f;
        #pragma unroll
        for (int j = 0; j < 8; ++j) {
            int f = tf * 8 + j;
            float v = acc[i][j] + be_l[f];
            float m = silu(v);
            acc[i][j] = m;
            p += m * s_wx[f];
        }
        wsum[i] = p;
    }
    #pragma unroll
    for (int off = 1; off < 16; off <<= 1) {
        #pragma unroll
        for (int i = 0; i < 4; ++i) wsum[i] += __shfl_xor(wsum[i], off);
    }
    float bxv = bx_l[0];
    if (tf < 3) {
        #pragma unroll
        for (int i = 0; i < 4; ++i) {
            int e = te * 4 + i;
            float w2 = wsum[i] + bxv;
            atomicAdd(&agg_x[s_dst[e] * 3 + tf], s_diff[e][tf] * w2);
        }
    }
    #pragma unroll
    for (int i = 0; i < 4; ++i) {
        int d = s_dst[te * 4 + i];
        #pragma unroll
        for (int j = 0; j < 8; ++j)
            atomicAdd(&agg_m[d * HID + tf * 8 + j], acc[i][j]);
    }
}

__global__ __launch_bounds__(128) void node_update_fb_kernel(
    float* __restrict__ h, float* __restrict__ x,
    const float* __restrict__ agg_m, const float* __restrict__ agg_x,
    const float* __restrict__ cnt,
    const float* __restrict__ Wh_l, const float* __restrict__ bh_l)
{
    __shared__ float s_in[256][20];
    int n0 = blockIdx.x * 16;
    int tx = threadIdx.x;
    for (int idx = tx; idx < 16 * HID; idx += 128) {
        int i = idx >> 7, k = idx & 127;
        s_in[k][i] = h[(n0 + i) * HID + k];
    }
    for (int idx = tx; idx < 16 * HID; idx += 128) {
        int i = idx >> 7, k = idx & 127;
        s_in[HID + k][i] = agg_m[(n0 + i) * HID + k];
    }
    __syncthreads();
    float acc[16];
    float bv = bh_l[tx];
    #pragma unroll
    for (int i = 0; i < 16; ++i) acc[i] = bv;
    for (int k = 0; k < 256; ++k) {
        float w = Wh_l[k * HID + tx];
        float4 f0 = *(const float4*)&s_in[k][0];
        float4 f1 = *(const float4*)&s_in[k][4];
        float4 f2 = *(const float4*)&s_in[k][8];
        float4 f3 = *(const float4*)&s_in[k][12];
        acc[0] += f0.x*w; acc[1] += f0.y*w; acc[2] += f0.z*w; acc[3] += f0.w*w;
        acc[4] += f1.x*w; acc[5] += f1.y*w; acc[6] += f1.z*w; acc[7] += f1.w*w;
        acc[8] += f2.x*w; acc[9] += f2.y*w; acc[10]+= f2.z*w; acc[11]+= f2.w*w;
        acc[12]+= f3.x*w; acc[13]+= f3.y*w; acc[14]+= f3.z*w; acc[15]+= f3.w*w;
    }
    #pragma unroll
    for (int i = 0; i < 16; ++i) {
        float v = acc[i];
        h[(n0 + i) * HID + tx] = s_in[tx][i] + silu(v);
    }
    if (tx < 48) {
        int i = tx / 3, c = tx % 3;
        int n = n0 + i;
        x[n * 3 + c] += agg_x[n * 3 + c] / (cnt[n] + 1.f);
    }
}

__global__ __launch_bounds__(64) void final_fb_kernel(
    const float* __restrict__ h, const float* __restrict__ x,
    const int* __restrict__ gmask,
    const float* __restrict__ W, const float* __restrict__ b,
    float* __restrict__ out)
{
    __shared__ float s_h[8][HID];
    int n0 = blockIdx.x * 8;
    int tx = threadIdx.x;
    for (int idx = tx; idx < 8 * HID; idx += 64) {
        int i = idx >> 7, k = idx & 127;
        s_h[i][k] = h[(n0 + i) * HID + k];
    }
    __syncthreads();
    float acc[8];
    float bv = b[tx];
    #pragma unroll
    for (int i = 0; i < 8; ++i) acc[i] = bv;
    for (int k = 0; k < HID; ++k) {
        float w = W[k * IN_DIM + tx];
        #pragma unroll
        for (int i = 0; i < 8; ++i) acc[i] += s_h[i][k] * w;
    }
    #pragma unroll
    for (int i = 0; i < 8; ++i) {
        int n = n0 + i;
        out[n * IN_DIM + tx] = gmask[n] ? acc[i] : 0.f;
    }
    if (tx < 24) {
        int i = tx / 3, c = tx % 3;
        int n = n0 + i;
        out[NN * IN_DIM + n * 3 + c] = gmask[n] ? x[n * 3 + c] : 0.f;
    }
}

extern "C" void kernel_launch(void* const* d_in, const int* in_sizes, int n_in,
                              void* d_out, int out_size, void* d_ws, size_t ws_size,
                              hipStream_t stream) {
    const float* H_t   = (const float*)d_in[0];
    const float* X_t   = (const float*)d_in[1];
    const float* cond  = (const float*)d_in[2];
    const float* t_in  = (const float*)d_in[3];
    const int*   edges = (const int*)d_in[4];
    const int*   etype = (const int*)d_in[5];
    const int*   gmask = (const int*)d_in[6];
    const float* W0 = (const float*)d_in[8];
    const float* b0 = (const float*)d_in[9];
    const float* W1 = (const float*)d_in[10];
    const float* b1 = (const float*)d_in[11];
    const float* W2 = (const float*)d_in[12];
    const float* b2 = (const float*)d_in[13];
    const float* edge_table = (const float*)d_in[14];
    const float* We = (const float*)d_in[15];
    const float* be = (const float*)d_in[16];
    const float* Wx = (const float*)d_in[17];
    const float* bx = (const float*)d_in[18];
    const float* Wh = (const float*)d_in[19];
    const float* bh = (const float*)d_in[20];
    const float* h2i_W = (const float*)d_in[21];
    const float* h2i_b = (const float*)d_in[22];

    char* p = (char*)d_ws;
    float* h = (float*)p;           p += (size_t)NN * HID * 4;
    u16* h_bf = (u16*)p;            p += (size_t)NN * HID * 2;
    float* x = (float*)p;           p += (size_t)NN * 3 * 4;
    float* wdiff = (float*)p;       p += (size_t)NE * 3 * 4;
    u16* msg = (u16*)p;             p += (size_t)NE * HID * 2;
    u16* Bpack = (u16*)p;           p += (size_t)PACK_TOT * 2;
    float* tv = (float*)p;          p += (size_t)768 * 4;
    float* wed2 = (float*)p;        p += (size_t)384 * 4;
    int* row_start = (int*)p;       p += (size_t)(NN + 4) * 4;
    int* deg = (int*)p;             p += (size_t)NN * 4;
    int* head = (int*)p;            p += (size_t)NN * 4;
    int* pos = (int*)p;             p += (size_t)NE * 4;
    size_t need = (size_t)(p - (char*)d_ws);

    if (ws_size >= need) {
        hipMemsetAsync(deg, 0, NN * sizeof(int), stream);
        hist_kernel<<<256, 256, 0, stream>>>(X_t, edges, x, deg);
        scan_kernel<<<1, 256, 0, stream>>>(deg, row_start, head);
        scatter_kernel<<<256, 256, 0, stream>>>(edges, head, pos);
        pack_all_kernel<<<(PACK_TOT + 255) / 256, 256, 0, stream>>>(
            We, W0, W1, W2, Wh, h2i_W, Bpack);
        precomp_tv_kernel<<<5, 256, 0, stream>>>(edge_table, We, be, tv, wed2);
        node_mlp_mfma_kernel<<<NB64, 256, 0, stream>>>(
            H_t, cond, t_in,
            Bpack + OFF_W0, b0, Bpack + OFF_W1, b1, Bpack + OFF_W2, b2,
            h, h_bf);
        for (int l = 0; l < 3; ++l) {
            edge_mfma_kernel<<<NE / ETE, 256, 0, stream>>>(
                h_bf, x, edges, etype,
                Bpack + OFF_WE + (size_t)l * 40960,
                tv + (size_t)l * 256, wed2 + (size_t)l * 128,
                Wx + l * HID, bx + l, pos, msg, wdiff);
            node_update_mfma_kernel<<<NN / NUB, 256, 0, stream>>>(
                h, h_bf, x, msg, wdiff, row_start,
                Bpack + OFF_WH + (size_t)l * 32768, bh + l * HID);
        }
        final_mfma_kernel<<<NB64, 256, 0, stream>>>(
            h_bf, x, gmask, Bpack + OFF_H2I, h2i_b, (float*)d_out);
    } else {
        // fallback: scalar atomic path (~21 MB)
        float* ws    = (float*)d_ws;
        float* fh    = ws;
        float* fx    = fh + NN * HID;
        float* cnt   = fx + NN * 3;
        float* agg_m = cnt + NN;
        float* agg_x = agg_m + NN * HID;

        hipMemsetAsync(cnt, 0, NN * sizeof(float), stream);
        init_fb_kernel<<<256, 256, 0, stream>>>(X_t, edges, fx, cnt);
        node_mlp_kernel<<<NN / 16, 128, 0, stream>>>(H_t, cond, t_in,
                                                     W0, b0, W1, b1, W2, b2, fh);
        for (int l = 0; l < 3; ++l) {
            hipMemsetAsync(agg_m, 0, (size_t)NN * 131 * sizeof(float), stream);
            edge_gemm_fb_kernel<<<NE / TILE_E, 256, 0, stream>>>(
                fh, fx, edges, etype, edge_table,
                We + (size_t)l * DE * HID, be + l * HID,
                Wx + l * HID, bx + l, agg_m, agg_x);
            node_update_fb_kernel<<<NN / 16, 128, 0, stream>>>(
                fh, fx, agg_m, agg_x, cnt,
                Wh + (size_t)l * 256 * HID, bh + l * HID);
        }
        final_fb_kernel<<<NN / 8, 64, 0, stream>>>(fh, fx, gmask, h2i_W, h2i_b, (float*)d_out);
    }
}

// Round 8
// 450.923 us; speedup vs baseline: 7.4742x; 1.0330x over previous
//
#include <hip/hip_runtime.h>
#include <math.h>

#define NN 20000
#define NE 256000
#define IN_DIM 64
#define HID 128
#define DE 289     // 2*HID + 1 + 32
#define D0 320     // IN_DIM + 2*HID
#define TILE_E 64
#define NB64 313   // ceil(NN/64)
#define ETE 64     // edges per block (MFMA edge kernel)
#define NUB 16     // nodes per block (node update)

typedef unsigned short u16;
typedef unsigned int u32;
typedef __attribute__((ext_vector_type(8))) short short8;
typedef __attribute__((ext_vector_type(4))) float float4v;

// Bpack layout offsets (u16 elements)
#define OFF_WE   0          // 3 x 40960 (K=289 pad 320, N=128) — only K-tiles 0..3 used
#define OFF_W0   122880     // 40960 (K=320, N=128)
#define OFF_W1   163840     // 16384 (K=128, N=128)
#define OFF_W2   180224     // 16384
#define OFF_WH   196608     // 3 x 32768 (K=256, N=128)
#define OFF_H2I  294912     // 8192 (K=128, N=64)
#define PACK_TOT 303104

static __device__ __forceinline__ u16 f2bf(float f) {
    unsigned int u = __float_as_uint(f);
    u += 0x7fffu + ((u >> 16) & 1u);
    return (u16)(u >> 16);
}
static __device__ __forceinline__ float bf2f(u16 s) {
    return __uint_as_float(((unsigned int)s) << 16);
}
static __device__ __forceinline__ uint4 pack8(const float* v) {
    uint4 r;
    r.x = (u32)f2bf(v[0]) | ((u32)f2bf(v[1]) << 16);
    r.y = (u32)f2bf(v[2]) | ((u32)f2bf(v[3]) << 16);
    r.z = (u32)f2bf(v[4]) | ((u32)f2bf(v[5]) << 16);
    r.w = (u32)f2bf(v[6]) | ((u32)f2bf(v[7]) << 16);
    return r;
}
static __device__ __forceinline__ float silu(float v) {
    return v * (1.f / (1.f + __expf(-v)));
}

// ================= CSR build =================
__global__ __launch_bounds__(256) void hist_kernel(
    const float* __restrict__ X_t, const int* __restrict__ edges,
    float* __restrict__ x, int* __restrict__ deg)
{
    int gid = blockIdx.x * blockDim.x + threadIdx.x;
    int stride = gridDim.x * blockDim.x;
    for (int i = gid; i < NN * 3; i += stride) x[i] = X_t[i];
    for (int e = gid; e < NE; e += stride)
        atomicAdd(&deg[edges[NE + e]], 1);
}

__global__ __launch_bounds__(256) void scan_kernel(
    const int* __restrict__ deg, int* __restrict__ row_start, int* __restrict__ head)
{
    __shared__ int s[256];
    int tx = threadIdx.x;
    const int per = (NN + 255) / 256;
    int st = tx * per, en = st + per;
    if (st > NN) st = NN;
    if (en > NN) en = NN;
    int sum = 0;
    for (int i = st; i < en; ++i) sum += deg[i];
    s[tx] = sum;
    __syncthreads();
    for (int off = 1; off < 256; off <<= 1) {
        int t = (tx >= off) ? s[tx - off] : 0;
        __syncthreads();
        s[tx] += t;
        __syncthreads();
    }
    int run = (tx == 0) ? 0 : s[tx - 1];
    for (int i = st; i < en; ++i) {
        row_start[i] = run; head[i] = run; run += deg[i];
    }
    if (tx == 255) row_start[NN] = run;
}

__global__ __launch_bounds__(256) void scatter_kernel(
    const int* __restrict__ edges, int* __restrict__ head, int* __restrict__ pos)
{
    int gid = blockIdx.x * blockDim.x + threadIdx.x;
    int stride = gridDim.x * blockDim.x;
    for (int e = gid; e < NE; e += stride)
        pos[e] = atomicAdd(&head[edges[NE + e]], 1);
}

// ================= weight frag-order packing =================
__global__ __launch_bounds__(256) void pack_all_kernel(
    const float* __restrict__ We, const float* __restrict__ W0,
    const float* __restrict__ W1, const float* __restrict__ W2,
    const float* __restrict__ Wh, const float* __restrict__ h2i,
    u16* __restrict__ Bp)
{
    int idx = blockIdx.x * 256 + threadIdx.x;
    if (idx >= PACK_TOT) return;
    const float* src; int N = 128, Ksrc; int r;
    if (idx < OFF_W0) {
        int layer = idx / 40960; r = idx - layer * 40960;
        src = We + (size_t)layer * DE * HID; Ksrc = DE;
    } else if (idx < OFF_W1) { r = idx - OFF_W0; src = W0; Ksrc = 320; }
    else if (idx < OFF_W2)   { r = idx - OFF_W1; src = W1; Ksrc = 128; }
    else if (idx < OFF_WH)   { r = idx - OFF_W2; src = W2; Ksrc = 128; }
    else if (idx < OFF_H2I) {
        int t = idx - OFF_WH; int layer = t / 32768; r = t - layer * 32768;
        src = Wh + (size_t)layer * 256 * HID; Ksrc = 256;
    } else { r = idx - OFF_H2I; src = h2i; Ksrc = 128; N = 64; }
    int ntc = N / 16;
    int j = r & 7, lane = (r >> 3) & 63;
    int rem = r >> 9;
    int nt = rem % ntc, ks = rem / ntc;
    int k = ks * 32 + ((lane >> 4) << 3) + j;
    int c = nt * 16 + (lane & 15);
    Bp[idx] = f2bf((k < Ksrc) ? src[(size_t)k * N + c] : 0.f);
}

// ================= edge tail precompute (f32) =================
__global__ __launch_bounds__(256) void precomp_tv_kernel(
    const float* __restrict__ edge_table, const float* __restrict__ We,
    const float* __restrict__ be, float* __restrict__ tv, float* __restrict__ wed2)
{
    int idx = blockIdx.x * 256 + threadIdx.x;
    if (idx < 768) {
        int f = idx & 127, t = (idx >> 7) & 1, l = idx >> 8;
        float acc = be[l * 128 + f];
        const float* W = We + (size_t)l * DE * HID;
        #pragma unroll
        for (int k = 0; k < 32; ++k)
            acc += edge_table[t * 32 + k] * W[(size_t)(257 + k) * HID + f];
        tv[l * 256 + t * 128 + f] = acc;
    } else if (idx < 1152) {
        int r = idx - 768;
        int f = r & 127, l = r >> 7;
        wed2[l * 128 + f] = We[(size_t)l * DE * HID + (size_t)256 * HID + f];
    }
}

// ================= node MLP: MFMA, 64 nodes/block =================
__global__ __launch_bounds__(256) void node_mlp_mfma_kernel(
    const float* __restrict__ H_t, const float* __restrict__ cond,
    const float* __restrict__ t_in,
    const u16* __restrict__ W0p, const float* __restrict__ b0,
    const u16* __restrict__ W1p, const float* __restrict__ b1,
    const u16* __restrict__ W2p, const float* __restrict__ b2,
    float* __restrict__ h, u16* __restrict__ h_bf)
{
    __shared__ u16 s_A[64 * 64];
    __shared__ u16 s_B[64 * 128];
    __shared__ u16 s_h[64 * 128];
    __shared__ float s_t[64];

    int tx = threadIdx.x;
    int n0 = blockIdx.x * 64;
    int l = tx & 63, w = tx >> 6;
    int mt_base = (w & 1) * 2, nt_base = (w >> 1) * 4;
    const float cfr = -logf(10000.f) / 63.f;

    if (tx < 64) s_t[tx] = (n0 + tx < NN) ? t_in[n0 + tx] : 0.f;

    float4v acc[2][4];
    #pragma unroll
    for (int mi = 0; mi < 2; ++mi)
        #pragma unroll
        for (int ni = 0; ni < 4; ++ni) acc[mi][ni] = (float4v){0.f,0.f,0.f,0.f};

    for (int t = 0; t < 5; ++t) {
        __syncthreads();
        #pragma unroll
        for (int it = 0; it < 2; ++it) {
            int flat = it * 256 + tx;
            int n = flat >> 3, sl = flat & 7;
            int c = sl ^ (n & 7);
            int k0 = t * 64 + c * 8;
            float tv8[8];
            int gn = n0 + n;
            if (gn < NN) {
                if (k0 < 192) {
                    const float* src = (k0 < 64) ? &H_t[(size_t)gn * IN_DIM + k0]
                                                 : &cond[(size_t)gn * HID + (k0 - 64)];
                    float4 a = *(const float4*)src;
                    float4 b = *(const float4*)(src + 4);
                    tv8[0]=a.x; tv8[1]=a.y; tv8[2]=a.z; tv8[3]=a.w;
                    tv8[4]=b.x; tv8[5]=b.y; tv8[6]=b.z; tv8[7]=b.w;
                } else {
                    float tv = s_t[n];
                    int jj = (k0 - 192) & 63;
                    bool is_sin = (k0 < 256);
                    #pragma unroll
                    for (int jx = 0; jx < 8; ++jx) {
                        float ang = tv * __expf(cfr * (float)(jj + jx));
                        tv8[jx] = is_sin ? __sinf(ang) : __cosf(ang);
                    }
                }
            } else {
                #pragma unroll
                for (int jx = 0; jx < 8; ++jx) tv8[jx] = 0.f;
            }
            *(uint4*)&s_A[n * 64 + sl * 8] = pack8(tv8);
        }
        #pragma unroll
        for (int it = 0; it < 4; ++it) {
            int flat = it * 256 + tx;
            ((uint4*)s_B)[flat] = ((const uint4*)(W0p + (size_t)t * 8192))[flat];
        }
        __syncthreads();
        #pragma unroll
        for (int s = 0; s < 2; ++s) {
            short8 af[2], bfv[4];
            #pragma unroll
            for (int mi = 0; mi < 2; ++mi) {
                int m = (mt_base + mi) * 16 + (l & 15);
                int c = s * 4 + (l >> 4);
                int slot = c ^ (l & 7);
                af[mi] = *(const short8*)(s_A + m * 64 + slot * 8);
            }
            #pragma unroll
            for (int ni = 0; ni < 4; ++ni)
                bfv[ni] = *(const short8*)(s_B + ((s * 8 + nt_base + ni) * 64 + l) * 8);
            #pragma unroll
            for (int mi = 0; mi < 2; ++mi)
                #pragma unroll
                for (int ni = 0; ni < 4; ++ni)
                    acc[mi][ni] = __builtin_amdgcn_mfma_f32_16x16x32_bf16(
                        af[mi], bfv[ni], acc[mi][ni], 0, 0, 0);
        }
    }
    #pragma unroll
    for (int mi = 0; mi < 2; ++mi) {
        #pragma unroll
        for (int ni = 0; ni < 4; ++ni) {
            int f = (nt_base + ni) * 16 + (l & 15);
            float bv = b0[f];
            #pragma unroll
            for (int r = 0; r < 4; ++r) {
                int m = (mt_base + mi) * 16 + (l >> 4) * 4 + r;
                float v = fmaxf(acc[mi][ni][r] + bv, 0.f);
                int slot = (f >> 3) ^ (m & 7);
                s_h[m * 128 + slot * 8 + (f & 7)] = f2bf(v);
            }
            acc[mi][ni] = (float4v){0.f,0.f,0.f,0.f};
        }
    }
    for (int t = 0; t < 2; ++t) {
        __syncthreads();
        #pragma unroll
        for (int it = 0; it < 4; ++it) {
            int flat = it * 256 + tx;
            ((uint4*)s_B)[flat] = ((const uint4*)(W1p + (size_t)t * 8192))[flat];
        }
        __syncthreads();
        #pragma unroll
        for (int s = 0; s < 2; ++s) {
            short8 af[2], bfv[4];
            #pragma unroll
            for (int mi = 0; mi < 2; ++mi) {
                int m = (mt_base + mi) * 16 + (l & 15);
                int c = t * 8 + s * 4 + (l >> 4);
                int slot = c ^ (l & 7);
                af[mi] = *(const short8*)(s_h + m * 128 + slot * 8);
            }
            #pragma unroll
            for (int ni = 0; ni < 4; ++ni)
                bfv[ni] = *(const short8*)(s_B + ((s * 8 + nt_base + ni) * 64 + l) * 8);
            #pragma unroll
            for (int mi = 0; mi < 2; ++mi)
                #pragma unroll
                for (int ni = 0; ni < 4; ++ni)
                    acc[mi][ni] = __builtin_amdgcn_mfma_f32_16x16x32_bf16(
                        af[mi], bfv[ni], acc[mi][ni], 0, 0, 0);
        }
    }
    __syncthreads();
    #pragma unroll
    for (int mi = 0; mi < 2; ++mi) {
        #pragma unroll
        for (int ni = 0; ni < 4; ++ni) {
            int f = (nt_base + ni) * 16 + (l & 15);
            float bv = b1[f];
            #pragma unroll
            for (int r = 0; r < 4; ++r) {
                int m = (mt_base + mi) * 16 + (l >> 4) * 4 + r;
                float v = fmaxf(acc[mi][ni][r] + bv, 0.f);
                int slot = (f >> 3) ^ (m & 7);
                s_h[m * 128 + slot * 8 + (f & 7)] = f2bf(v);
            }
            acc[mi][ni] = (float4v){0.f,0.f,0.f,0.f};
        }
    }
    for (int t = 0; t < 2; ++t) {
        __syncthreads();
        #pragma unroll
        for (int it = 0; it < 4; ++it) {
            int flat = it * 256 + tx;
            ((uint4*)s_B)[flat] = ((const uint4*)(W2p + (size_t)t * 8192))[flat];
        }
        __syncthreads();
        #pragma unroll
        for (int s = 0; s < 2; ++s) {
            short8 af[2], bfv[4];
            #pragma unroll
            for (int mi = 0; mi < 2; ++mi) {
                int m = (mt_base + mi) * 16 + (l & 15);
                int c = t * 8 + s * 4 + (l >> 4);
                int slot = c ^ (l & 7);
                af[mi] = *(const short8*)(s_h + m * 128 + slot * 8);
            }
            #pragma unroll
            for (int ni = 0; ni < 4; ++ni)
                bfv[ni] = *(const short8*)(s_B + ((s * 8 + nt_base + ni) * 64 + l) * 8);
            #pragma unroll
            for (int mi = 0; mi < 2; ++mi)
                #pragma unroll
                for (int ni = 0; ni < 4; ++ni)
                    acc[mi][ni] = __builtin_amdgcn_mfma_f32_16x16x32_bf16(
                        af[mi], bfv[ni], acc[mi][ni], 0, 0, 0);
        }
    }
    #pragma unroll
    for (int mi = 0; mi < 2; ++mi) {
        #pragma unroll
        for (int ni = 0; ni < 4; ++ni) {
            int f = (nt_base + ni) * 16 + (l & 15);
            float bv = b2[f];
            #pragma unroll
            for (int r = 0; r < 4; ++r) {
                int m = (mt_base + mi) * 16 + (l >> 4) * 4 + r;
                int gn = n0 + m;
                if (gn < NN) {
                    float v = acc[mi][ni][r] + bv;
                    h[(size_t)gn * HID + f] = v;
                    h_bf[(size_t)gn * HID + f] = f2bf(v);
                }
            }
        }
    }
}

// ================= edge MFMA: 64 edges/block, K=256, tail in epilogue, register wsum =================
__global__ __launch_bounds__(256) void edge_mfma_kernel(
    const u16* __restrict__ h_bf, const float* __restrict__ x,
    const int* __restrict__ edges, const int* __restrict__ etype,
    const u16* __restrict__ Bpack_l,
    const float* __restrict__ tv_l,    // 2 x 128 (includes be)
    const float* __restrict__ wed2_l,  // 128
    const float* __restrict__ Wx_l, const float* __restrict__ bx_l,
    const int* __restrict__ pos,
    u16* __restrict__ msg, float* __restrict__ wdiff)
{
    __shared__ u16 s_AB[12288];        // A=[0,4096) B=[4096,12288); epilogue out stride 132 (8448 u16)
    __shared__ float s_tv[2][128];
    __shared__ float s_wx[128], s_wed2[128];
    __shared__ float s_wsum[2][64];
    __shared__ int s_src[64], s_dst[64], s_pos[64], s_et[64];
    __shared__ float s_diff[64][3], s_d2[64];

    u16* s_A = s_AB;
    u16* s_B = s_AB + 4096;

    int tx = threadIdx.x;
    int e0 = blockIdx.x * ETE;
    int l = tx & 63, w = tx >> 6;
    int mt_base = (w & 1) * 2;
    int nt_base = (w >> 1) * 4;

    if (tx < 64) {
        int s = edges[e0 + tx], d = edges[NE + e0 + tx];
        s_src[tx] = s; s_dst[tx] = d;
        s_pos[tx] = pos[e0 + tx]; s_et[tx] = etype[e0 + tx];
        float dx = x[s*3+0]-x[d*3+0], dy = x[s*3+1]-x[d*3+1], dz = x[s*3+2]-x[d*3+2];
        s_diff[tx][0] = dx; s_diff[tx][1] = dy; s_diff[tx][2] = dz;
        s_d2[tx] = dx*dx + dy*dy + dz*dz;
    }
    ((float*)s_tv)[tx] = tv_l[tx];
    if (tx < 128) s_wx[tx] = Wx_l[tx];
    else          s_wed2[tx - 128] = wed2_l[tx - 128];
    __syncthreads();

    float4v acc[2][4];
    #pragma unroll
    for (int mi = 0; mi < 2; ++mi)
        #pragma unroll
        for (int ni = 0; ni < 4; ++ni)
            acc[mi][ni] = (float4v){0.f, 0.f, 0.f, 0.f};

    for (int t = 0; t < 4; ++t) {
        __syncthreads();
        // A: gather 64 rows x 128B halves (src for t<2, dst for t>=2)
        #pragma unroll
        for (int it = 0; it < 2; ++it) {
            int flat = it * 256 + tx;
            int e = flat >> 3, sl = flat & 7;
            int c = sl ^ (e & 7);
            int row = (t < 2) ? s_src[e] : s_dst[e];
            uint4 v = *(const uint4*)(h_bf + (size_t)row * 128 + (t & 1) * 64 + c * 8);
            *(uint4*)(s_A + e * 64 + sl * 8) = v;
        }
        // B: contiguous frag-order copy
        #pragma unroll
        for (int it = 0; it < 4; ++it) {
            int flat = it * 256 + tx;
            ((uint4*)s_B)[flat] = ((const uint4*)(Bpack_l + (size_t)t * 8192))[flat];
        }
        __syncthreads();

        #pragma unroll
        for (int s = 0; s < 2; ++s) {
            short8 af[2], bfv[4];
            #pragma unroll
            for (int mi = 0; mi < 2; ++mi) {
                int m = (mt_base + mi) * 16 + (l & 15);
                int c = s * 4 + (l >> 4);
                int slot = c ^ (l & 7);
                af[mi] = *(const short8*)(s_A + m * 64 + slot * 8);
            }
            #pragma unroll
            for (int ni = 0; ni < 4; ++ni)
                bfv[ni] = *(const short8*)(s_B + ((s * 8 + nt_base + ni) * 64 + l) * 8);
            #pragma unroll
            for (int mi = 0; mi < 2; ++mi)
                #pragma unroll
                for (int ni = 0; ni < 4; ++ni)
                    acc[mi][ni] = __builtin_amdgcn_mfma_f32_16x16x32_bf16(
                        af[mi], bfv[ni], acc[mi][ni], 0, 0, 0);
        }
    }
    __syncthreads();

    // epilogue: v = acc + tv[et][f] + d2*wed2[f]; silu -> out tile (stride 132) + register wsum
    float wx4[4], wd4[4];
    #pragma unroll
    for (int ni = 0; ni < 4; ++ni) {
        int f = (nt_base + ni) * 16 + (l & 15);
        wx4[ni] = s_wx[f];
        wd4[ni] = s_wed2[f];
    }
    float pw[2][4];
    #pragma unroll
    for (int mi = 0; mi < 2; ++mi)
        #pragma unroll
        for (int r = 0; r < 4; ++r) pw[mi][r] = 0.f;

    #pragma unroll
    for (int mi = 0; mi < 2; ++mi) {
        int ebase = (mt_base + mi) * 16 + (l >> 4) * 4;
        #pragma unroll
        for (int ni = 0; ni < 4; ++ni) {
            int f = (nt_base + ni) * 16 + (l & 15);
            #pragma unroll
            for (int r = 0; r < 4; ++r) {
                int e = ebase + r;
                float v = acc[mi][ni][r] + s_tv[s_et[e]][f] + s_d2[e] * wd4[ni];
                float m = silu(v);
                s_AB[e * 132 + f] = f2bf(m);
                pw[mi][r] += m * wx4[ni];
            }
        }
    }
    // reduce pw over the 16-lane column group
    #pragma unroll
    for (int off = 1; off < 16; off <<= 1) {
        #pragma unroll
        for (int mi = 0; mi < 2; ++mi)
            #pragma unroll
            for (int r = 0; r < 4; ++r)
                pw[mi][r] += __shfl_xor(pw[mi][r], off);
    }
    if ((l & 15) == 0) {
        #pragma unroll
        for (int mi = 0; mi < 2; ++mi)
            #pragma unroll
            for (int r = 0; r < 4; ++r) {
                int e = (mt_base + mi) * 16 + (l >> 4) * 4 + r;
                s_wsum[w >> 1][e] = pw[mi][r];
            }
    }
    __syncthreads();

    if (tx < 192) {
        int i = tx / 3, c = tx % 3;
        float full = s_wsum[0][i] + s_wsum[1][i] + bx_l[0];
        wdiff[s_pos[i] * 3 + c] = s_diff[i][c] * full;
    }
    #pragma unroll
    for (int it = 0; it < 4; ++it) {
        int flat = it * 256 + tx;
        int e = flat >> 4, c = flat & 15;
        *((uint4*)(msg + (size_t)s_pos[e] * 128) + c) = *(const uint4*)(s_AB + e * 132 + c * 8);
    }
}

// ================= node update: CSR agg + MFMA Wh GEMM, 16 nodes/block =================
__global__ __launch_bounds__(256) void node_update_mfma_kernel(
    float* __restrict__ h, u16* __restrict__ h_bf, float* __restrict__ x,
    const u16* __restrict__ msg, const float* __restrict__ wdiff,
    const int* __restrict__ row_start,
    const u16* __restrict__ Whp_l, const float* __restrict__ bh_l)
{
    __shared__ u16 s_A[NUB * 256];   // 8 KB: [node][256k] xor-swizzled: h | agg_m
    __shared__ u16 s_B[64 * 128];    // 16 KB
    __shared__ int s_rs[NUB + 1];

    int tx = threadIdx.x;
    int n0 = blockIdx.x * NUB;
    int l = tx & 63, w = tx >> 6;
    int nt_base = w * 2;             // wave covers 2 N-tiles

    if (tx < NUB + 1) s_rs[tx] = row_start[n0 + tx];
    // stage h_bf (chunks 0..15): 16 nodes x 16 uint4 = 256
    {
        int n = tx >> 4, c = tx & 15;
        int slot = c ^ (n & 7);
        uint4 v = *(const uint4*)(h_bf + (size_t)(n0 + n) * 128 + c * 8);
        *(uint4*)&s_A[n * 256 + slot * 8] = v;
    }
    __syncthreads();
    // aggregation: node i = tx>>4, feat-chunk p = tx&15 (8 feats)
    {
        int i = tx >> 4, p = tx & 15;
        int rs = s_rs[i], re = s_rs[i + 1];
        float ag[8];
        #pragma unroll
        for (int q = 0; q < 8; ++q) ag[q] = 0.f;
        for (int j = rs; j < re; ++j) {
            uint4 v = *(const uint4*)(msg + (size_t)j * 128 + p * 8);
            ag[0] += bf2f((u16)(v.x & 0xffffu));
            ag[1] += bf2f((u16)(v.x >> 16));
            ag[2] += bf2f((u16)(v.y & 0xffffu));
            ag[3] += bf2f((u16)(v.y >> 16));
            ag[4] += bf2f((u16)(v.z & 0xffffu));
            ag[5] += bf2f((u16)(v.z >> 16));
            ag[6] += bf2f((u16)(v.w & 0xffffu));
            ag[7] += bf2f((u16)(v.w >> 16));
        }
        int c2 = 16 + p;
        int slot = c2 ^ (i & 7);
        *(uint4*)&s_A[i * 256 + slot * 8] = pack8(ag);
    }
    // x update
    if (tx < NUB * 3) {
        int i = tx / 3, c = tx % 3;
        int gn = n0 + i;
        int rs = s_rs[i], re = s_rs[i + 1];
        float sxx = 0.f;
        for (int j = rs; j < re; ++j) sxx += wdiff[j * 3 + c];
        x[gn * 3 + c] += sxx / ((float)(re - rs) + 1.f);
    }

    float4v acc[2];
    #pragma unroll
    for (int ni = 0; ni < 2; ++ni) acc[ni] = (float4v){0.f,0.f,0.f,0.f};

    for (int t = 0; t < 4; ++t) {
        __syncthreads();
        #pragma unroll
        for (int it = 0; it < 4; ++it) {
            int flat = it * 256 + tx;
            ((uint4*)s_B)[flat] = ((const uint4*)(Whp_l + (size_t)t * 8192))[flat];
        }
        __syncthreads();
        #pragma unroll
        for (int s = 0; s < 2; ++s) {
            short8 af, bfv[2];
            {
                int m = l & 15;
                int c = t * 8 + s * 4 + (l >> 4);
                int slot = c ^ (l & 7);
                af = *(const short8*)(s_A + m * 256 + slot * 8);
            }
            #pragma unroll
            for (int ni = 0; ni < 2; ++ni)
                bfv[ni] = *(const short8*)(s_B + ((s * 8 + nt_base + ni) * 64 + l) * 8);
            #pragma unroll
            for (int ni = 0; ni < 2; ++ni)
                acc[ni] = __builtin_amdgcn_mfma_f32_16x16x32_bf16(
                    af, bfv[ni], acc[ni], 0, 0, 0);
        }
    }
    // epilogue: h += silu(acc + bh)
    #pragma unroll
    for (int ni = 0; ni < 2; ++ni) {
        int f = (nt_base + ni) * 16 + (l & 15);
        float bv = bh_l[f];
        #pragma unroll
        for (int r = 0; r < 4; ++r) {
            int m = (l >> 4) * 4 + r;
            int gn = n0 + m;
            float v = acc[ni][r] + bv;
            float hn = h[(size_t)gn * HID + f] + silu(v);
            h[(size_t)gn * HID + f] = hn;
            h_bf[(size_t)gn * HID + f] = f2bf(hn);
        }
    }
}

// ================= final: MFMA h2i, 64 nodes/block =================
__global__ __launch_bounds__(256) void final_mfma_kernel(
    const u16* __restrict__ h_bf, const float* __restrict__ x,
    const int* __restrict__ gmask,
    const u16* __restrict__ h2ip, const float* __restrict__ b,
    float* __restrict__ out)
{
    __shared__ u16 s_A[64 * 128];
    __shared__ u16 s_B[4096];

    int tx = threadIdx.x;
    int n0 = blockIdx.x * 64;
    int l = tx & 63, w = tx >> 6;
    int mt_base = (w & 1) * 2, nt_base = (w >> 1) * 2;

    #pragma unroll
    for (int it = 0; it < 4; ++it) {
        int flat = it * 256 + tx;
        int n = flat >> 4, c = flat & 15;
        int slot = c ^ (n & 7);
        int gn = n0 + n;
        uint4 v = make_uint4(0,0,0,0);
        if (gn < NN) v = *(const uint4*)(h_bf + (size_t)gn * 128 + c * 8);
        *(uint4*)&s_A[n * 128 + slot * 8] = v;
    }

    float4v acc[2][2];
    #pragma unroll
    for (int mi = 0; mi < 2; ++mi)
        #pragma unroll
        for (int ni = 0; ni < 2; ++ni) acc[mi][ni] = (float4v){0.f,0.f,0.f,0.f};

    for (int t = 0; t < 2; ++t) {
        __syncthreads();
        #pragma unroll
        for (int it = 0; it < 2; ++it) {
            int flat = it * 256 + tx;
            ((uint4*)s_B)[flat] = ((const uint4*)(h2ip + (size_t)t * 4096))[flat];
        }
        __syncthreads();
        #pragma unroll
        for (int s = 0; s < 2; ++s) {
            short8 af[2], bfv[2];
            #pragma unroll
            for (int mi = 0; mi < 2; ++mi) {
                int m = (mt_base + mi) * 16 + (l & 15);
                int c = t * 8 + s * 4 + (l >> 4);
                int slot = c ^ (l & 7);
                af[mi] = *(const short8*)(s_A + m * 128 + slot * 8);
            }
            #pragma unroll
            for (int ni = 0; ni < 2; ++ni)
                bfv[ni] = *(const short8*)(s_B + ((s * 4 + nt_base + ni) * 64 + l) * 8);
            #pragma unroll
            for (int mi = 0; mi < 2; ++mi)
                #pragma unroll
                for (int ni = 0; ni < 2; ++ni)
                    acc[mi][ni] = __builtin_amdgcn_mfma_f32_16x16x32_bf16(
                        af[mi], bfv[ni], acc[mi][ni], 0, 0, 0);
        }
    }
    #pragma unroll
    for (int mi = 0; mi < 2; ++mi) {
        #pragma unroll
        for (int ni = 0; ni < 2; ++ni) {
            int f = (nt_base + ni) * 16 + (l & 15);
            float bv = b[f];
            #pragma unroll
            for (int r = 0; r < 4; ++r) {
                int m = (mt_base + mi) * 16 + (l >> 4) * 4 + r;
                int gn = n0 + m;
                if (gn < NN)
                    out[(size_t)gn * IN_DIM + f] = gmask[gn] ? (acc[mi][ni][r] + bv) : 0.f;
            }
        }
    }
    if (tx < 192) {
        int i = tx / 3, c = tx % 3;
        int gn = n0 + i;
        if (gn < NN)
            out[(size_t)NN * IN_DIM + gn * 3 + c] = gmask[gn] ? x[gn * 3 + c] : 0.f;
    }
}

// ================= fallback path (atomic, scalar; used only if ws too small) =================
__global__ __launch_bounds__(256) void init_fb_kernel(
    const float* __restrict__ X_t, const int* __restrict__ edges,
    float* __restrict__ x, float* __restrict__ cnt)
{
    int gid = blockIdx.x * blockDim.x + threadIdx.x;
    int stride = gridDim.x * blockDim.x;
    for (int i = gid; i < NN * 3; i += stride) x[i] = X_t[i];
    for (int e = gid; e < NE; e += stride)
        atomicAdd(&cnt[edges[NE + e]], 1.0f);
}

__global__ __launch_bounds__(128) void node_mlp_kernel(
    const float* __restrict__ H_t, const float* __restrict__ cond,
    const float* __restrict__ t_in,
    const float* __restrict__ W0, const float* __restrict__ b0,
    const float* __restrict__ W1, const float* __restrict__ b1,
    const float* __restrict__ W2, const float* __restrict__ b2,
    float* __restrict__ h)
{
    __shared__ float s_feat[D0][20];
    __shared__ float s_h0[HID][20];
    __shared__ float s_h1[HID][20];
    int n0 = blockIdx.x * 16;
    int tx = threadIdx.x;

    for (int idx = tx; idx < 16 * IN_DIM; idx += 128) {
        int i = idx >> 6, k = idx & 63;
        s_feat[k][i] = H_t[(n0 + i) * IN_DIM + k];
    }
    for (int idx = tx; idx < 16 * HID; idx += 128) {
        int i = idx >> 7, k = idx & 127;
        s_feat[IN_DIM + k][i] = cond[(n0 + i) * HID + k];
    }
    const float cfr = -logf(10000.f) / 63.f;
    for (int idx = tx; idx < 16 * HID; idx += 128) {
        int i = idx >> 7, k = idx & 127;
        float tv = t_in[n0 + i];
        int jj = k & 63;
        float ang = tv * __expf(cfr * (float)jj);
        s_feat[IN_DIM + HID + k][i] = (k < 64) ? __sinf(ang) : __cosf(ang);
    }
    __syncthreads();

    float acc[16];
    {
        float bv = b0[tx];
        #pragma unroll
        for (int i = 0; i < 16; ++i) acc[i] = bv;
        for (int k = 0; k < D0; ++k) {
            float w = W0[k * HID + tx];
            float4 f0 = *(const float4*)&s_feat[k][0];
            float4 f1 = *(const float4*)&s_feat[k][4];
            float4 f2 = *(const float4*)&s_feat[k][8];
            float4 f3 = *(const float4*)&s_feat[k][12];
            acc[0] += f0.x*w; acc[1] += f0.y*w; acc[2] += f0.z*w; acc[3] += f0.w*w;
            acc[4] += f1.x*w; acc[5] += f1.y*w; acc[6] += f1.z*w; acc[7] += f1.w*w;
            acc[8] += f2.x*w; acc[9] += f2.y*w; acc[10]+= f2.z*w; acc[11]+= f2.w*w;
            acc[12]+= f3.x*w; acc[13]+= f3.y*w; acc[14]+= f3.z*w; acc[15]+= f3.w*w;
        }
        #pragma unroll
        for (int i = 0; i < 16; ++i) s_h0[tx][i] = fmaxf(acc[i], 0.f);
    }
    __syncthreads();
    {
        float bv = b1[tx];
        #pragma unroll
        for (int i = 0; i < 16; ++i) acc[i] = bv;
        for (int k = 0; k < HID; ++k) {
            float w = W1[k * HID + tx];
            float4 f0 = *(const float4*)&s_h0[k][0];
            float4 f1 = *(const float4*)&s_h0[k][4];
            float4 f2 = *(const float4*)&s_h0[k][8];
            float4 f3 = *(const float4*)&s_h0[k][12];
            acc[0] += f0.x*w; acc[1] += f0.y*w; acc[2] += f0.z*w; acc[3] += f0.w*w;
            acc[4] += f1.x*w; acc[5] += f1.y*w; acc[6] += f1.z*w; acc[7] += f1.w*w;
            acc[8] += f2.x*w; acc[9] += f2.y*w; acc[10]+= f2.z*w; acc[11]+= f2.w*w;
            acc[12]+= f3.x*w; acc[13]+= f3.y*w; acc[14]+= f3.z*w; acc[15]+= f3.w*w;
        }
        #pragma unroll
        for (int i = 0; i < 16; ++i) s_h1[tx][i] = fmaxf(acc[i], 0.f);
    }
    __syncthreads();
    {
        float bv = b2[tx];
        #pragma unroll
        for (int i = 0; i < 16; ++i) acc[i] = bv;
        for (int k = 0; k < HID; ++k) {
            float w = W2[k * HID + tx];
            float4 f0 = *(const float4*)&s_h1[k][0];
            float4 f1 = *(const float4*)&s_h1[k][4];
            float4 f2 = *(const float4*)&s_h1[k][8];
            float4 f3 = *(const float4*)&s_h1[k][12];
            acc[0] += f0.x*w; acc[1] += f0.y*w; acc[2] += f0.z*w; acc[3] += f0.w*w;
            acc[4] += f1.x*w; acc[5] += f1.y*w; acc[6] += f1.z*w; acc[7] += f1.w*w;
            acc[8] += f2.x*w; acc[9] += f2.y*w; acc[10]+= f2.z*w; acc[11]+= f2.w*w;
            acc[12]+= f3.x*w; acc[13]+= f3.y*w; acc[14]+= f3.z*w; acc[15]+= f3.w*w;
        }
        #pragma unroll
        for (int i = 0; i < 16; ++i) h[(n0 + i) * HID + tx] = acc[i];
    }
}

__global__ __launch_bounds__(256) void edge_gemm_fb_kernel(
    const float* __restrict__ h, const float* __restrict__ x,
    const int* __restrict__ edges, const int* __restrict__ etype,
    const float* __restrict__ edge_table,
    const float* __restrict__ We_l, const float* __restrict__ be_l,
    const float* __restrict__ Wx_l, const float* __restrict__ bx_l,
    float* __restrict__ agg_m, float* __restrict__ agg_x)
{
    __shared__ int s_src[TILE_E], s_dst[TILE_E];
    __shared__ float s_diff[TILE_E][3];
    __shared__ float s_tail[TILE_E][36];
    __shared__ float s_Af[TILE_E][36];
    __shared__ float s_Bf[33][HID];
    __shared__ float s_wx[HID];

    int e0 = blockIdx.x * TILE_E;
    int tx = threadIdx.x;
    int tf = tx & 15;
    int te = tx >> 4;

    if (tx < TILE_E) {
        int s = edges[e0 + tx];
        int d = edges[NE + e0 + tx];
        s_src[tx] = s; s_dst[tx] = d;
        float dx = x[s * 3 + 0] - x[d * 3 + 0];
        float dy = x[s * 3 + 1] - x[d * 3 + 1];
        float dz = x[s * 3 + 2] - x[d * 3 + 2];
        s_diff[tx][0] = dx; s_diff[tx][1] = dy; s_diff[tx][2] = dz;
        s_tail[tx][0] = dx * dx + dy * dy + dz * dz;
        int et = etype[e0 + tx];
        #pragma unroll
        for (int j = 0; j < 32; ++j) s_tail[tx][1 + j] = edge_table[et * 32 + j];
    }
    if (tx < HID) s_wx[tx] = Wx_l[tx];
    __syncthreads();

    float acc[4][8];
    #pragma unroll
    for (int i = 0; i < 4; ++i)
        #pragma unroll
        for (int j = 0; j < 8; ++j) acc[i][j] = 0.f;

    for (int t = 0; t < 9; ++t) {
        int k0 = t * 32;
        int klen = (t == 8) ? 33 : 32;
        __syncthreads();
        if (t < 8) {
            const bool use_src = (t < 4);
            int kbase = (t & 3) * 32;
            for (int q4 = tx; q4 < TILE_E * 8; q4 += 256) {
                int e = q4 >> 3, q = q4 & 7;
                int row = use_src ? s_src[e] : s_dst[e];
                float4 v = *(const float4*)&h[row * HID + kbase + q * 4];
                *(float4*)&s_Af[e][q * 4] = v;
            }
        }
        for (int q4 = tx; q4 < klen * 32; q4 += 256) {
            int kk = q4 >> 5, c4 = q4 & 31;
            float4 v = *(const float4*)&We_l[(k0 + kk) * HID + c4 * 4];
            *(float4*)&s_Bf[kk][c4 * 4] = v;
        }
        __syncthreads();
        const float (*Asrc)[36] = (t == 8) ? (const float (*)[36])s_tail
                                           : (const float (*)[36])s_Af;
        for (int kk = 0; kk < klen; ++kk) {
            float a0 = Asrc[te * 4 + 0][kk];
            float a1 = Asrc[te * 4 + 1][kk];
            float a2 = Asrc[te * 4 + 2][kk];
            float a3 = Asrc[te * 4 + 3][kk];
            float4 bv0 = *(const float4*)&s_Bf[kk][tf * 8];
            float4 bv1 = *(const float4*)&s_Bf[kk][tf * 8 + 4];
            float b[8] = {bv0.x, bv0.y, bv0.z, bv0.w, bv1.x, bv1.y, bv1.z, bv1.w};
            #pragma unroll
            for (int j = 0; j < 8; ++j) {
                acc[0][j] += a0 * b[j];
                acc[1][j] += a1 * b[j];
                acc[2][j] += a2 * b[j];
                acc[3][j] += a3 * b[j];
            }
        }
    }

    float wsum[4];
    #pragma unroll
    for (int i = 0; i < 4; ++i) {
        float p = 0.f;
        #pragma unroll
        for (int j = 0; j < 8; ++j) {
            int f = tf * 8 + j;
            float v = acc[i][j] + be_l[f];
            float m = silu(v);
            acc[i][j] = m;
            p += m * s_wx[f];
        }
        wsum[i] = p;
    }
    #pragma unroll
    for (int off = 1; off < 16; off <<= 1) {
        #pragma unroll
        for (int i = 0; i < 4; ++i) wsum[i] += __shfl_xor(wsum[i], off);
    }
    float bxv = bx_l[0];
    if (tf < 3) {
        #pragma unroll
        for (int i = 0; i < 4; ++i) {
            int e = te * 4 + i;
            float w2 = wsum[i] + bxv;
            atomicAdd(&agg_x[s_dst[e] * 3 + tf], s_diff[e][tf] * w2);
        }
    }
    #pragma unroll
    for (int i = 0; i < 4; ++i) {
        int d = s_dst[te * 4 + i];
        #pragma unroll
        for (int j = 0; j < 8; ++j)
            atomicAdd(&agg_m[d * HID + tf * 8 + j], acc[i][j]);
    }
}

__global__ __launch_bounds__(128) void node_update_fb_kernel(
    float* __restrict__ h, float* __restrict__ x,
    const float* __restrict__ agg_m, const float* __restrict__ agg_x,
    const float* __restrict__ cnt,
    const float* __restrict__ Wh_l, const float* __restrict__ bh_l)
{
    __shared__ float s_in[256][20];
    int n0 = blockIdx.x * 16;
    int tx = threadIdx.x;
    for (int idx = tx; idx < 16 * HID; idx += 128) {
        int i = idx >> 7, k = idx & 127;
        s_in[k][i] = h[(n0 + i) * HID + k];
    }
    for (int idx = tx; idx < 16 * HID; idx += 128) {
        int i = idx >> 7, k = idx & 127;
        s_in[HID + k][i] = agg_m[(n0 + i) * HID + k];
    }
    __syncthreads();
    float acc[16];
    float bv = bh_l[tx];
    #pragma unroll
    for (int i = 0; i < 16; ++i) acc[i] = bv;
    for (int k = 0; k < 256; ++k) {
        float w = Wh_l[k * HID + tx];
        float4 f0 = *(const float4*)&s_in[k][0];
        float4 f1 = *(const float4*)&s_in[k][4];
        float4 f2 = *(const float4*)&s_in[k][8];
        float4 f3 = *(const float4*)&s_in[k][12];
        acc[0] += f0.x*w; acc[1] += f0.y*w; acc[2] += f0.z*w; acc[3] += f0.w*w;
        acc[4] += f1.x*w; acc[5] += f1.y*w; acc[6] += f1.z*w; acc[7] += f1.w*w;
        acc[8] += f2.x*w; acc[9] += f2.y*w; acc[10]+= f2.z*w; acc[11]+= f2.w*w;
        acc[12]+= f3.x*w; acc[13]+= f3.y*w; acc[14]+= f3.z*w; acc[15]+= f3.w*w;
    }
    #pragma unroll
    for (int i = 0; i < 16; ++i) {
        float v = acc[i];
        h[(n0 + i) * HID + tx] = s_in[tx][i] + silu(v);
    }
    if (tx < 48) {
        int i = tx / 3, c = tx % 3;
        int n = n0 + i;
        x[n * 3 + c] += agg_x[n * 3 + c] / (cnt[n] + 1.f);
    }
}

__global__ __launch_bounds__(64) void final_fb_kernel(
    const float* __restrict__ h, const float* __restrict__ x,
    const int* __restrict__ gmask,
    const float* __restrict__ W, const float* __restrict__ b,
    float* __restrict__ out)
{
    __shared__ float s_h[8][HID];
    int n0 = blockIdx.x * 8;
    int tx = threadIdx.x;
    for (int idx = tx; idx < 8 * HID; idx += 64) {
        int i = idx >> 7, k = idx & 127;
        s_h[i][k] = h[(n0 + i) * HID + k];
    }
    __syncthreads();
    float acc[8];
    float bv = b[tx];
    #pragma unroll
    for (int i = 0; i < 8; ++i) acc[i] = bv;
    for (int k = 0; k < HID; ++k) {
        float w = W[k * IN_DIM + tx];
        #pragma unroll
        for (int i = 0; i < 8; ++i) acc[i] += s_h[i][k] * w;
    }
    #pragma unroll
    for (int i = 0; i < 8; ++i) {
        int n = n0 + i;
        out[n * IN_DIM + tx] = gmask[n] ? acc[i] : 0.f;
    }
    if (tx < 24) {
        int i = tx / 3, c = tx % 3;
        int n = n0 + i;
        out[NN * IN_DIM + n * 3 + c] = gmask[n] ? x[n * 3 + c] : 0.f;
    }
}

extern "C" void kernel_launch(void* const* d_in, const int* in_sizes, int n_in,
                              void* d_out, int out_size, void* d_ws, size_t ws_size,
                              hipStream_t stream) {
    const float* H_t   = (const float*)d_in[0];
    const float* X_t   = (const float*)d_in[1];
    const float* cond  = (const float*)d_in[2];
    const float* t_in  = (const float*)d_in[3];
    const int*   edges = (const int*)d_in[4];
    const int*   etype = (const int*)d_in[5];
    const int*   gmask = (const int*)d_in[6];
    const float* W0 = (const float*)d_in[8];
    const float* b0 = (const float*)d_in[9];
    const float* W1 = (const float*)d_in[10];
    const float* b1 = (const float*)d_in[11];
    const float* W2 = (const float*)d_in[12];
    const float* b2 = (const float*)d_in[13];
    const float* edge_table = (const float*)d_in[14];
    const float* We = (const float*)d_in[15];
    const float* be = (const float*)d_in[16];
    const float* Wx = (const float*)d_in[17];
    const float* bx = (const float*)d_in[18];
    const float* Wh = (const float*)d_in[19];
    const float* bh = (const float*)d_in[20];
    const float* h2i_W = (const float*)d_in[21];
    const float* h2i_b = (const float*)d_in[22];

    char* p = (char*)d_ws;
    float* h = (float*)p;           p += (size_t)NN * HID * 4;
    u16* h_bf = (u16*)p;            p += (size_t)NN * HID * 2;
    float* x = (float*)p;           p += (size_t)NN * 3 * 4;
    float* wdiff = (float*)p;       p += (size_t)NE * 3 * 4;
    u16* msg = (u16*)p;             p += (size_t)NE * HID * 2;
    u16* Bpack = (u16*)p;           p += (size_t)PACK_TOT * 2;
    float* tv = (float*)p;          p += (size_t)768 * 4;
    float* wed2 = (float*)p;        p += (size_t)384 * 4;
    int* row_start = (int*)p;       p += (size_t)(NN + 4) * 4;
    int* deg = (int*)p;             p += (size_t)NN * 4;
    int* head = (int*)p;            p += (size_t)NN * 4;
    int* pos = (int*)p;             p += (size_t)NE * 4;
    size_t need = (size_t)(p - (char*)d_ws);

    if (ws_size >= need) {
        hipMemsetAsync(deg, 0, NN * sizeof(int), stream);
        hist_kernel<<<256, 256, 0, stream>>>(X_t, edges, x, deg);
        scan_kernel<<<1, 256, 0, stream>>>(deg, row_start, head);
        scatter_kernel<<<256, 256, 0, stream>>>(edges, head, pos);
        pack_all_kernel<<<(PACK_TOT + 255) / 256, 256, 0, stream>>>(
            We, W0, W1, W2, Wh, h2i_W, Bpack);
        precomp_tv_kernel<<<5, 256, 0, stream>>>(edge_table, We, be, tv, wed2);
        node_mlp_mfma_kernel<<<NB64, 256, 0, stream>>>(
            H_t, cond, t_in,
            Bpack + OFF_W0, b0, Bpack + OFF_W1, b1, Bpack + OFF_W2, b2,
            h, h_bf);
        for (int l = 0; l < 3; ++l) {
            edge_mfma_kernel<<<NE / ETE, 256, 0, stream>>>(
                h_bf, x, edges, etype,
                Bpack + OFF_WE + (size_t)l * 40960,
                tv + (size_t)l * 256, wed2 + (size_t)l * 128,
                Wx + l * HID, bx + l, pos, msg, wdiff);
            node_update_mfma_kernel<<<NN / NUB, 256, 0, stream>>>(
                h, h_bf, x, msg, wdiff, row_start,
                Bpack + OFF_WH + (size_t)l * 32768, bh + l * HID);
        }
        final_mfma_kernel<<<NB64, 256, 0, stream>>>(
            h_bf, x, gmask, Bpack + OFF_H2I, h2i_b, (float*)d_out);
    } else {
        // fallback: scalar atomic path (~21 MB)
        float* ws    = (float*)d_ws;
        float* fh    = ws;
        float* fx    = fh + NN * HID;
        float* cnt   = fx + NN * 3;
        float* agg_m = cnt + NN;
        float* agg_x = agg_m + NN * HID;

        hipMemsetAsync(cnt, 0, NN * sizeof(float), stream);
        init_fb_kernel<<<256, 256, 0, stream>>>(X_t, edges, fx, cnt);
        node_mlp_kernel<<<NN / 16, 128, 0, stream>>>(H_t, cond, t_in,
                                                     W0, b0, W1, b1, W2, b2, fh);
        for (int l = 0; l < 3; ++l) {
            hipMemsetAsync(agg_m, 0, (size_t)NN * 131 * sizeof(float), stream);
            edge_gemm_fb_kernel<<<NE / TILE_E, 256, 0, stream>>>(
                fh, fx, edges, etype, edge_table,
                We + (size_t)l * DE * HID, be + l * HID,
                Wx + l * HID, bx + l, agg_m, agg_x);
            node_update_fb_kernel<<<NN / 16, 128, 0, stream>>>(
                fh, fx, agg_m, agg_x, cnt,
                Wh + (size_t)l * 256 * HID, bh + l * HID);
        }
        final_fb_kernel<<<NN / 8, 64, 0, stream>>>(fh, fx, gmask, h2i_W, h2i_b, (float*)d_out);
    }
}

// Round 9
// 448.693 us; speedup vs baseline: 7.5113x; 1.0050x over previous
//
#include <hip/hip_runtime.h>
#include <math.h>

#define NN 20000
#define NE 256000
#define IN_DIM 64
#define HID 128
#define DE 289     // 2*HID + 1 + 32
#define D0 320     // IN_DIM + 2*HID
#define TILE_E 64
#define NB64 313   // ceil(NN/64)
#define ETE 64     // edges per block (MFMA edge kernel)
#define NUB 16     // nodes per block (node update)

typedef unsigned short u16;
typedef unsigned int u32;
typedef __attribute__((ext_vector_type(8))) short short8;
typedef __attribute__((ext_vector_type(4))) float float4v;

// Bpack layout offsets (u16 elements)
#define OFF_WE   0          // 3 x 40960 (K=289 pad 320, N=128) — only K-tiles 0..3 used
#define OFF_W0   122880     // 40960 (K=320, N=128)
#define OFF_W1   163840     // 16384 (K=128, N=128)
#define OFF_W2   180224     // 16384
#define OFF_WH   196608     // 3 x 32768 (K=256, N=128)
#define OFF_H2I  294912     // 8192 (K=128, N=64)
#define PACK_TOT 303104

static __device__ __forceinline__ u16 f2bf(float f) {
    unsigned int u = __float_as_uint(f);
    u += 0x7fffu + ((u >> 16) & 1u);
    return (u16)(u >> 16);
}
static __device__ __forceinline__ float bf2f(u16 s) {
    return __uint_as_float(((unsigned int)s) << 16);
}
static __device__ __forceinline__ uint4 pack8(const float* v) {
    uint4 r;
    r.x = (u32)f2bf(v[0]) | ((u32)f2bf(v[1]) << 16);
    r.y = (u32)f2bf(v[2]) | ((u32)f2bf(v[3]) << 16);
    r.z = (u32)f2bf(v[4]) | ((u32)f2bf(v[5]) << 16);
    r.w = (u32)f2bf(v[6]) | ((u32)f2bf(v[7]) << 16);
    return r;
}
static __device__ __forceinline__ float silu(float v) {
    return v * (1.f / (1.f + __expf(-v)));
}

// ================= CSR build =================
__global__ __launch_bounds__(256) void hist_kernel(
    const float* __restrict__ X_t, const int* __restrict__ edges,
    float* __restrict__ x, int* __restrict__ deg)
{
    int gid = blockIdx.x * blockDim.x + threadIdx.x;
    int stride = gridDim.x * blockDim.x;
    for (int i = gid; i < NN * 3; i += stride) x[i] = X_t[i];
    for (int e = gid; e < NE; e += stride)
        atomicAdd(&deg[edges[NE + e]], 1);
}

__global__ __launch_bounds__(256) void scan_kernel(
    const int* __restrict__ deg, int* __restrict__ row_start, int* __restrict__ head)
{
    __shared__ int s[256];
    int tx = threadIdx.x;
    const int per = (NN + 255) / 256;
    int st = tx * per, en = st + per;
    if (st > NN) st = NN;
    if (en > NN) en = NN;
    int sum = 0;
    for (int i = st; i < en; ++i) sum += deg[i];
    s[tx] = sum;
    __syncthreads();
    for (int off = 1; off < 256; off <<= 1) {
        int t = (tx >= off) ? s[tx - off] : 0;
        __syncthreads();
        s[tx] += t;
        __syncthreads();
    }
    int run = (tx == 0) ? 0 : s[tx - 1];
    for (int i = st; i < en; ++i) {
        row_start[i] = run; head[i] = run; run += deg[i];
    }
    if (tx == 255) row_start[NN] = run;
}

// permute edges into dst-sorted order
__global__ __launch_bounds__(256) void scatter_kernel(
    const int* __restrict__ edges, const int* __restrict__ etype,
    int* __restrict__ head,
    int* __restrict__ src_s, int* __restrict__ dst_s, int* __restrict__ et_s)
{
    int gid = blockIdx.x * blockDim.x + threadIdx.x;
    int stride = gridDim.x * blockDim.x;
    for (int e = gid; e < NE; e += stride) {
        int d = edges[NE + e];
        int p = atomicAdd(&head[d], 1);
        src_s[p] = edges[e];
        dst_s[p] = d;
        et_s[p] = etype[e];
    }
}

// ================= weight frag-order packing =================
__global__ __launch_bounds__(256) void pack_all_kernel(
    const float* __restrict__ We, const float* __restrict__ W0,
    const float* __restrict__ W1, const float* __restrict__ W2,
    const float* __restrict__ Wh, const float* __restrict__ h2i,
    u16* __restrict__ Bp)
{
    int idx = blockIdx.x * 256 + threadIdx.x;
    if (idx >= PACK_TOT) return;
    const float* src; int N = 128, Ksrc; int r;
    if (idx < OFF_W0) {
        int layer = idx / 40960; r = idx - layer * 40960;
        src = We + (size_t)layer * DE * HID; Ksrc = DE;
    } else if (idx < OFF_W1) { r = idx - OFF_W0; src = W0; Ksrc = 320; }
    else if (idx < OFF_W2)   { r = idx - OFF_W1; src = W1; Ksrc = 128; }
    else if (idx < OFF_WH)   { r = idx - OFF_W2; src = W2; Ksrc = 128; }
    else if (idx < OFF_H2I) {
        int t = idx - OFF_WH; int layer = t / 32768; r = t - layer * 32768;
        src = Wh + (size_t)layer * 256 * HID; Ksrc = 256;
    } else { r = idx - OFF_H2I; src = h2i; Ksrc = 128; N = 64; }
    int ntc = N / 16;
    int j = r & 7, lane = (r >> 3) & 63;
    int rem = r >> 9;
    int nt = rem % ntc, ks = rem / ntc;
    int k = ks * 32 + ((lane >> 4) << 3) + j;
    int c = nt * 16 + (lane & 15);
    Bp[idx] = f2bf((k < Ksrc) ? src[(size_t)k * N + c] : 0.f);
}

// ================= edge tail precompute (f32) =================
__global__ __launch_bounds__(256) void precomp_tv_kernel(
    const float* __restrict__ edge_table, const float* __restrict__ We,
    const float* __restrict__ be, float* __restrict__ tv, float* __restrict__ wed2)
{
    int idx = blockIdx.x * 256 + threadIdx.x;
    if (idx < 768) {
        int f = idx & 127, t = (idx >> 7) & 1, l = idx >> 8;
        float acc = be[l * 128 + f];
        const float* W = We + (size_t)l * DE * HID;
        #pragma unroll
        for (int k = 0; k < 32; ++k)
            acc += edge_table[t * 32 + k] * W[(size_t)(257 + k) * HID + f];
        tv[l * 256 + t * 128 + f] = acc;
    } else if (idx < 1152) {
        int r = idx - 768;
        int f = r & 127, l = r >> 7;
        wed2[l * 128 + f] = We[(size_t)l * DE * HID + (size_t)256 * HID + f];
    }
}

// ================= node MLP: MFMA, 64 nodes/block =================
__global__ __launch_bounds__(256) void node_mlp_mfma_kernel(
    const float* __restrict__ H_t, const float* __restrict__ cond,
    const float* __restrict__ t_in,
    const u16* __restrict__ W0p, const float* __restrict__ b0,
    const u16* __restrict__ W1p, const float* __restrict__ b1,
    const u16* __restrict__ W2p, const float* __restrict__ b2,
    float* __restrict__ h, u16* __restrict__ h_bf)
{
    __shared__ u16 s_A[64 * 64];
    __shared__ u16 s_B[64 * 128];
    __shared__ u16 s_h[64 * 128];
    __shared__ float s_t[64];

    int tx = threadIdx.x;
    int n0 = blockIdx.x * 64;
    int l = tx & 63, w = tx >> 6;
    int mt_base = (w & 1) * 2, nt_base = (w >> 1) * 4;
    const float cfr = -logf(10000.f) / 63.f;

    if (tx < 64) s_t[tx] = (n0 + tx < NN) ? t_in[n0 + tx] : 0.f;

    float4v acc[2][4];
    #pragma unroll
    for (int mi = 0; mi < 2; ++mi)
        #pragma unroll
        for (int ni = 0; ni < 4; ++ni) acc[mi][ni] = (float4v){0.f,0.f,0.f,0.f};

    for (int t = 0; t < 5; ++t) {
        __syncthreads();
        #pragma unroll
        for (int it = 0; it < 2; ++it) {
            int flat = it * 256 + tx;
            int n = flat >> 3, sl = flat & 7;
            int c = sl ^ (n & 7);
            int k0 = t * 64 + c * 8;
            float tv8[8];
            int gn = n0 + n;
            if (gn < NN) {
                if (k0 < 192) {
                    const float* src = (k0 < 64) ? &H_t[(size_t)gn * IN_DIM + k0]
                                                 : &cond[(size_t)gn * HID + (k0 - 64)];
                    float4 a = *(const float4*)src;
                    float4 b = *(const float4*)(src + 4);
                    tv8[0]=a.x; tv8[1]=a.y; tv8[2]=a.z; tv8[3]=a.w;
                    tv8[4]=b.x; tv8[5]=b.y; tv8[6]=b.z; tv8[7]=b.w;
                } else {
                    float tv = s_t[n];
                    int jj = (k0 - 192) & 63;
                    bool is_sin = (k0 < 256);
                    #pragma unroll
                    for (int jx = 0; jx < 8; ++jx) {
                        float ang = tv * __expf(cfr * (float)(jj + jx));
                        tv8[jx] = is_sin ? __sinf(ang) : __cosf(ang);
                    }
                }
            } else {
                #pragma unroll
                for (int jx = 0; jx < 8; ++jx) tv8[jx] = 0.f;
            }
            *(uint4*)&s_A[n * 64 + sl * 8] = pack8(tv8);
        }
        #pragma unroll
        for (int it = 0; it < 4; ++it) {
            int flat = it * 256 + tx;
            ((uint4*)s_B)[flat] = ((const uint4*)(W0p + (size_t)t * 8192))[flat];
        }
        __syncthreads();
        #pragma unroll
        for (int s = 0; s < 2; ++s) {
            short8 af[2], bfv[4];
            #pragma unroll
            for (int mi = 0; mi < 2; ++mi) {
                int m = (mt_base + mi) * 16 + (l & 15);
                int c = s * 4 + (l >> 4);
                int slot = c ^ (l & 7);
                af[mi] = *(const short8*)(s_A + m * 64 + slot * 8);
            }
            #pragma unroll
            for (int ni = 0; ni < 4; ++ni)
                bfv[ni] = *(const short8*)(s_B + ((s * 8 + nt_base + ni) * 64 + l) * 8);
            #pragma unroll
            for (int mi = 0; mi < 2; ++mi)
                #pragma unroll
                for (int ni = 0; ni < 4; ++ni)
                    acc[mi][ni] = __builtin_amdgcn_mfma_f32_16x16x32_bf16(
                        af[mi], bfv[ni], acc[mi][ni], 0, 0, 0);
        }
    }
    #pragma unroll
    for (int mi = 0; mi < 2; ++mi) {
        #pragma unroll
        for (int ni = 0; ni < 4; ++ni) {
            int f = (nt_base + ni) * 16 + (l & 15);
            float bv = b0[f];
            #pragma unroll
            for (int r = 0; r < 4; ++r) {
                int m = (mt_base + mi) * 16 + (l >> 4) * 4 + r;
                float v = fmaxf(acc[mi][ni][r] + bv, 0.f);
                int slot = (f >> 3) ^ (m & 7);
                s_h[m * 128 + slot * 8 + (f & 7)] = f2bf(v);
            }
            acc[mi][ni] = (float4v){0.f,0.f,0.f,0.f};
        }
    }
    for (int t = 0; t < 2; ++t) {
        __syncthreads();
        #pragma unroll
        for (int it = 0; it < 4; ++it) {
            int flat = it * 256 + tx;
            ((uint4*)s_B)[flat] = ((const uint4*)(W1p + (size_t)t * 8192))[flat];
        }
        __syncthreads();
        #pragma unroll
        for (int s = 0; s < 2; ++s) {
            short8 af[2], bfv[4];
            #pragma unroll
            for (int mi = 0; mi < 2; ++mi) {
                int m = (mt_base + mi) * 16 + (l & 15);
                int c = t * 8 + s * 4 + (l >> 4);
                int slot = c ^ (l & 7);
                af[mi] = *(const short8*)(s_h + m * 128 + slot * 8);
            }
            #pragma unroll
            for (int ni = 0; ni < 4; ++ni)
                bfv[ni] = *(const short8*)(s_B + ((s * 8 + nt_base + ni) * 64 + l) * 8);
            #pragma unroll
            for (int mi = 0; mi < 2; ++mi)
                #pragma unroll
                for (int ni = 0; ni < 4; ++ni)
                    acc[mi][ni] = __builtin_amdgcn_mfma_f32_16x16x32_bf16(
                        af[mi], bfv[ni], acc[mi][ni], 0, 0, 0);
        }
    }
    __syncthreads();
    #pragma unroll
    for (int mi = 0; mi < 2; ++mi) {
        #pragma unroll
        for (int ni = 0; ni < 4; ++ni) {
            int f = (nt_base + ni) * 16 + (l & 15);
            float bv = b1[f];
            #pragma unroll
            for (int r = 0; r < 4; ++r) {
                int m = (mt_base + mi) * 16 + (l >> 4) * 4 + r;
                float v = fmaxf(acc[mi][ni][r] + bv, 0.f);
                int slot = (f >> 3) ^ (m & 7);
                s_h[m * 128 + slot * 8 + (f & 7)] = f2bf(v);
            }
            acc[mi][ni] = (float4v){0.f,0.f,0.f,0.f};
        }
    }
    for (int t = 0; t < 2; ++t) {
        __syncthreads();
        #pragma unroll
        for (int it = 0; it < 4; ++it) {
            int flat = it * 256 + tx;
            ((uint4*)s_B)[flat] = ((const uint4*)(W2p + (size_t)t * 8192))[flat];
        }
        __syncthreads();
        #pragma unroll
        for (int s = 0; s < 2; ++s) {
            short8 af[2], bfv[4];
            #pragma unroll
            for (int mi = 0; mi < 2; ++mi) {
                int m = (mt_base + mi) * 16 + (l & 15);
                int c = t * 8 + s * 4 + (l >> 4);
                int slot = c ^ (l & 7);
                af[mi] = *(const short8*)(s_h + m * 128 + slot * 8);
            }
            #pragma unroll
            for (int ni = 0; ni < 4; ++ni)
                bfv[ni] = *(const short8*)(s_B + ((s * 8 + nt_base + ni) * 64 + l) * 8);
            #pragma unroll
            for (int mi = 0; mi < 2; ++mi)
                #pragma unroll
                for (int ni = 0; ni < 4; ++ni)
                    acc[mi][ni] = __builtin_amdgcn_mfma_f32_16x16x32_bf16(
                        af[mi], bfv[ni], acc[mi][ni], 0, 0, 0);
        }
    }
    #pragma unroll
    for (int mi = 0; mi < 2; ++mi) {
        #pragma unroll
        for (int ni = 0; ni < 4; ++ni) {
            int f = (nt_base + ni) * 16 + (l & 15);
            float bv = b2[f];
            #pragma unroll
            for (int r = 0; r < 4; ++r) {
                int m = (mt_base + mi) * 16 + (l >> 4) * 4 + r;
                int gn = n0 + m;
                if (gn < NN) {
                    float v = acc[mi][ni][r] + bv;
                    h[(size_t)gn * HID + f] = v;
                    h_bf[(size_t)gn * HID + f] = f2bf(v);
                }
            }
        }
    }
}

// ================= edge MFMA: dst-sorted order, 64 edges/block, K=256 =================
__global__ __launch_bounds__(256) void edge_mfma_kernel(
    const u16* __restrict__ h_bf, const float* __restrict__ x,
    const int* __restrict__ src_s, const int* __restrict__ dst_s,
    const int* __restrict__ et_s,
    const u16* __restrict__ Bpack_l,
    const float* __restrict__ tv_l,    // 2 x 128 (includes be)
    const float* __restrict__ wed2_l,  // 128
    const float* __restrict__ Wx_l, const float* __restrict__ bx_l,
    u16* __restrict__ msg, float* __restrict__ wdiff)
{
    __shared__ u16 s_AB[12288];        // A=[0,4096) B=[4096,12288); epilogue out stride 132
    __shared__ float s_tv[2][128];
    __shared__ float s_wx[128], s_wed2[128];
    __shared__ float s_wsum[2][64];
    __shared__ int s_src[64], s_dst[64], s_et[64];
    __shared__ float s_diff[64][3], s_d2[64];

    u16* s_A = s_AB;
    u16* s_B = s_AB + 4096;

    int tx = threadIdx.x;
    int e0 = blockIdx.x * ETE;
    int l = tx & 63, w = tx >> 6;
    int mt_base = (w & 1) * 2;
    int nt_base = (w >> 1) * 4;

    if (tx < 64) {
        int s = src_s[e0 + tx], d = dst_s[e0 + tx];
        s_src[tx] = s; s_dst[tx] = d;
        s_et[tx] = et_s[e0 + tx];
        float dx = x[s*3+0]-x[d*3+0], dy = x[s*3+1]-x[d*3+1], dz = x[s*3+2]-x[d*3+2];
        s_diff[tx][0] = dx; s_diff[tx][1] = dy; s_diff[tx][2] = dz;
        s_d2[tx] = dx*dx + dy*dy + dz*dz;
    }
    ((float*)s_tv)[tx] = tv_l[tx];
    if (tx < 128) s_wx[tx] = Wx_l[tx];
    else          s_wed2[tx - 128] = wed2_l[tx - 128];
    __syncthreads();

    float4v acc[2][4];
    #pragma unroll
    for (int mi = 0; mi < 2; ++mi)
        #pragma unroll
        for (int ni = 0; ni < 4; ++ni)
            acc[mi][ni] = (float4v){0.f, 0.f, 0.f, 0.f};

    for (int t = 0; t < 4; ++t) {
        __syncthreads();
        // A: gather 64 rows x 128B halves (src for t<2, dst for t>=2; dst rows cluster)
        #pragma unroll
        for (int it = 0; it < 2; ++it) {
            int flat = it * 256 + tx;
            int e = flat >> 3, sl = flat & 7;
            int c = sl ^ (e & 7);
            int row = (t < 2) ? s_src[e] : s_dst[e];
            uint4 v = *(const uint4*)(h_bf + (size_t)row * 128 + (t & 1) * 64 + c * 8);
            *(uint4*)(s_A + e * 64 + sl * 8) = v;
        }
        // B: contiguous frag-order copy
        #pragma unroll
        for (int it = 0; it < 4; ++it) {
            int flat = it * 256 + tx;
            ((uint4*)s_B)[flat] = ((const uint4*)(Bpack_l + (size_t)t * 8192))[flat];
        }
        __syncthreads();

        #pragma unroll
        for (int s = 0; s < 2; ++s) {
            short8 af[2], bfv[4];
            #pragma unroll
            for (int mi = 0; mi < 2; ++mi) {
                int m = (mt_base + mi) * 16 + (l & 15);
                int c = s * 4 + (l >> 4);
                int slot = c ^ (l & 7);
                af[mi] = *(const short8*)(s_A + m * 64 + slot * 8);
            }
            #pragma unroll
            for (int ni = 0; ni < 4; ++ni)
                bfv[ni] = *(const short8*)(s_B + ((s * 8 + nt_base + ni) * 64 + l) * 8);
            #pragma unroll
            for (int mi = 0; mi < 2; ++mi)
                #pragma unroll
                for (int ni = 0; ni < 4; ++ni)
                    acc[mi][ni] = __builtin_amdgcn_mfma_f32_16x16x32_bf16(
                        af[mi], bfv[ni], acc[mi][ni], 0, 0, 0);
        }
    }
    __syncthreads();

    // epilogue: v = acc + tv[et][f] + d2*wed2[f]; silu -> out tile (stride 132) + register wsum
    float wx4[4], wd4[4];
    #pragma unroll
    for (int ni = 0; ni < 4; ++ni) {
        int f = (nt_base + ni) * 16 + (l & 15);
        wx4[ni] = s_wx[f];
        wd4[ni] = s_wed2[f];
    }
    float pw[2][4];
    #pragma unroll
    for (int mi = 0; mi < 2; ++mi)
        #pragma unroll
        for (int r = 0; r < 4; ++r) pw[mi][r] = 0.f;

    #pragma unroll
    for (int mi = 0; mi < 2; ++mi) {
        int ebase = (mt_base + mi) * 16 + (l >> 4) * 4;
        #pragma unroll
        for (int ni = 0; ni < 4; ++ni) {
            int f = (nt_base + ni) * 16 + (l & 15);
            #pragma unroll
            for (int r = 0; r < 4; ++r) {
                int e = ebase + r;
                float v = acc[mi][ni][r] + s_tv[s_et[e]][f] + s_d2[e] * wd4[ni];
                float m = silu(v);
                s_AB[e * 132 + f] = f2bf(m);
                pw[mi][r] += m * wx4[ni];
            }
        }
    }
    #pragma unroll
    for (int off = 1; off < 16; off <<= 1) {
        #pragma unroll
        for (int mi = 0; mi < 2; ++mi)
            #pragma unroll
            for (int r = 0; r < 4; ++r)
                pw[mi][r] += __shfl_xor(pw[mi][r], off);
    }
    if ((l & 15) == 0) {
        #pragma unroll
        for (int mi = 0; mi < 2; ++mi)
            #pragma unroll
            for (int r = 0; r < 4; ++r) {
                int e = (mt_base + mi) * 16 + (l >> 4) * 4 + r;
                s_wsum[w >> 1][e] = pw[mi][r];
            }
    }
    __syncthreads();

    if (tx < 192) {
        int i = tx / 3, c = tx % 3;
        float full = s_wsum[0][i] + s_wsum[1][i] + bx_l[0];
        wdiff[(size_t)(e0 + i) * 3 + c] = s_diff[i][c] * full;
    }
    // msg stores: sequential rows [e0, e0+64)
    #pragma unroll
    for (int it = 0; it < 4; ++it) {
        int flat = it * 256 + tx;
        int e = flat >> 4, c = flat & 15;
        *((uint4*)(msg + (size_t)(e0 + e) * 128) + c) = *(const uint4*)(s_AB + e * 132 + c * 8);
    }
}

// ================= node update: CSR agg + MFMA Wh GEMM, 16 nodes/block =================
__global__ __launch_bounds__(256) void node_update_mfma_kernel(
    float* __restrict__ h, u16* __restrict__ h_bf, float* __restrict__ x,
    const u16* __restrict__ msg, const float* __restrict__ wdiff,
    const int* __restrict__ row_start,
    const u16* __restrict__ Whp_l, const float* __restrict__ bh_l)
{
    __shared__ u16 s_A[NUB * 256];   // 8 KB
    __shared__ u16 s_B[64 * 128];    // 16 KB
    __shared__ int s_rs[NUB + 1];

    int tx = threadIdx.x;
    int n0 = blockIdx.x * NUB;
    int l = tx & 63, w = tx >> 6;
    int nt_base = w * 2;

    if (tx < NUB + 1) s_rs[tx] = row_start[n0 + tx];
    {
        int n = tx >> 4, c = tx & 15;
        int slot = c ^ (n & 7);
        uint4 v = *(const uint4*)(h_bf + (size_t)(n0 + n) * 128 + c * 8);
        *(uint4*)&s_A[n * 256 + slot * 8] = v;
    }
    __syncthreads();
    {
        int i = tx >> 4, p = tx & 15;
        int rs = s_rs[i], re = s_rs[i + 1];
        float ag[8];
        #pragma unroll
        for (int q = 0; q < 8; ++q) ag[q] = 0.f;
        for (int j = rs; j < re; ++j) {
            uint4 v = *(const uint4*)(msg + (size_t)j * 128 + p * 8);
            ag[0] += bf2f((u16)(v.x & 0xffffu));
            ag[1] += bf2f((u16)(v.x >> 16));
            ag[2] += bf2f((u16)(v.y & 0xffffu));
            ag[3] += bf2f((u16)(v.y >> 16));
            ag[4] += bf2f((u16)(v.z & 0xffffu));
            ag[5] += bf2f((u16)(v.z >> 16));
            ag[6] += bf2f((u16)(v.w & 0xffffu));
            ag[7] += bf2f((u16)(v.w >> 16));
        }
        int c2 = 16 + p;
        int slot = c2 ^ (i & 7);
        *(uint4*)&s_A[i * 256 + slot * 8] = pack8(ag);
    }
    if (tx < NUB * 3) {
        int i = tx / 3, c = tx % 3;
        int gn = n0 + i;
        int rs = s_rs[i], re = s_rs[i + 1];
        float sxx = 0.f;
        for (int j = rs; j < re; ++j) sxx += wdiff[j * 3 + c];
        x[gn * 3 + c] += sxx / ((float)(re - rs) + 1.f);
    }

    float4v acc[2];
    #pragma unroll
    for (int ni = 0; ni < 2; ++ni) acc[ni] = (float4v){0.f,0.f,0.f,0.f};

    for (int t = 0; t < 4; ++t) {
        __syncthreads();
        #pragma unroll
        for (int it = 0; it < 4; ++it) {
            int flat = it * 256 + tx;
            ((uint4*)s_B)[flat] = ((const uint4*)(Whp_l + (size_t)t * 8192))[flat];
        }
        __syncthreads();
        #pragma unroll
        for (int s = 0; s < 2; ++s) {
            short8 af, bfv[2];
            {
                int m = l & 15;
                int c = t * 8 + s * 4 + (l >> 4);
                int slot = c ^ (l & 7);
                af = *(const short8*)(s_A + m * 256 + slot * 8);
            }
            #pragma unroll
            for (int ni = 0; ni < 2; ++ni)
                bfv[ni] = *(const short8*)(s_B + ((s * 8 + nt_base + ni) * 64 + l) * 8);
            #pragma unroll
            for (int ni = 0; ni < 2; ++ni)
                acc[ni] = __builtin_amdgcn_mfma_f32_16x16x32_bf16(
                    af, bfv[ni], acc[ni], 0, 0, 0);
        }
    }
    #pragma unroll
    for (int ni = 0; ni < 2; ++ni) {
        int f = (nt_base + ni) * 16 + (l & 15);
        float bv = bh_l[f];
        #pragma unroll
        for (int r = 0; r < 4; ++r) {
            int m = (l >> 4) * 4 + r;
            int gn = n0 + m;
            float v = acc[ni][r] + bv;
            float hn = h[(size_t)gn * HID + f] + silu(v);
            h[(size_t)gn * HID + f] = hn;
            h_bf[(size_t)gn * HID + f] = f2bf(hn);
        }
    }
}

// ================= final: MFMA h2i, 64 nodes/block =================
__global__ __launch_bounds__(256) void final_mfma_kernel(
    const u16* __restrict__ h_bf, const float* __restrict__ x,
    const int* __restrict__ gmask,
    const u16* __restrict__ h2ip, const float* __restrict__ b,
    float* __restrict__ out)
{
    __shared__ u16 s_A[64 * 128];
    __shared__ u16 s_B[4096];

    int tx = threadIdx.x;
    int n0 = blockIdx.x * 64;
    int l = tx & 63, w = tx >> 6;
    int mt_base = (w & 1) * 2, nt_base = (w >> 1) * 2;

    #pragma unroll
    for (int it = 0; it < 4; ++it) {
        int flat = it * 256 + tx;
        int n = flat >> 4, c = flat & 15;
        int slot = c ^ (n & 7);
        int gn = n0 + n;
        uint4 v = make_uint4(0,0,0,0);
        if (gn < NN) v = *(const uint4*)(h_bf + (size_t)gn * 128 + c * 8);
        *(uint4*)&s_A[n * 128 + slot * 8] = v;
    }

    float4v acc[2][2];
    #pragma unroll
    for (int mi = 0; mi < 2; ++mi)
        #pragma unroll
        for (int ni = 0; ni < 2; ++ni) acc[mi][ni] = (float4v){0.f,0.f,0.f,0.f};

    for (int t = 0; t < 2; ++t) {
        __syncthreads();
        #pragma unroll
        for (int it = 0; it < 2; ++it) {
            int flat = it * 256 + tx;
            ((uint4*)s_B)[flat] = ((const uint4*)(h2ip + (size_t)t * 4096))[flat];
        }
        __syncthreads();
        #pragma unroll
        for (int s = 0; s < 2; ++s) {
            short8 af[2], bfv[2];
            #pragma unroll
            for (int mi = 0; mi < 2; ++mi) {
                int m = (mt_base + mi) * 16 + (l & 15);
                int c = t * 8 + s * 4 + (l >> 4);
                int slot = c ^ (l & 7);
                af[mi] = *(const short8*)(s_A + m * 128 + slot * 8);
            }
            #pragma unroll
            for (int ni = 0; ni < 2; ++ni)
                bfv[ni] = *(const short8*)(s_B + ((s * 4 + nt_base + ni) * 64 + l) * 8);
            #pragma unroll
            for (int mi = 0; mi < 2; ++mi)
                #pragma unroll
                for (int ni = 0; ni < 2; ++ni)
                    acc[mi][ni] = __builtin_amdgcn_mfma_f32_16x16x32_bf16(
                        af[mi], bfv[ni], acc[mi][ni], 0, 0, 0);
        }
    }
    #pragma unroll
    for (int mi = 0; mi < 2; ++mi) {
        #pragma unroll
        for (int ni = 0; ni < 2; ++ni) {
            int f = (nt_base + ni) * 16 + (l & 15);
            float bv = b[f];
            #pragma unroll
            for (int r = 0; r < 4; ++r) {
                int m = (mt_base + mi) * 16 + (l >> 4) * 4 + r;
                int gn = n0 + m;
                if (gn < NN)
                    out[(size_t)gn * IN_DIM + f] = gmask[gn] ? (acc[mi][ni][r] + bv) : 0.f;
            }
        }
    }
    if (tx < 192) {
        int i = tx / 3, c = tx % 3;
        int gn = n0 + i;
        if (gn < NN)
            out[(size_t)NN * IN_DIM + gn * 3 + c] = gmask[gn] ? x[gn * 3 + c] : 0.f;
    }
}

// ================= fallback path (atomic, scalar; used only if ws too small) =================
__global__ __launch_bounds__(256) void init_fb_kernel(
    const float* __restrict__ X_t, const int* __restrict__ edges,
    float* __restrict__ x, float* __restrict__ cnt)
{
    int gid = blockIdx.x * blockDim.x + threadIdx.x;
    int stride = gridDim.x * blockDim.x;
    for (int i = gid; i < NN * 3; i += stride) x[i] = X_t[i];
    for (int e = gid; e < NE; e += stride)
        atomicAdd(&cnt[edges[NE + e]], 1.0f);
}

__global__ __launch_bounds__(128) void node_mlp_kernel(
    const float* __restrict__ H_t, const float* __restrict__ cond,
    const float* __restrict__ t_in,
    const float* __restrict__ W0, const float* __restrict__ b0,
    const float* __restrict__ W1, const float* __restrict__ b1,
    const float* __restrict__ W2, const float* __restrict__ b2,
    float* __restrict__ h)
{
    __shared__ float s_feat[D0][20];
    __shared__ float s_h0[HID][20];
    __shared__ float s_h1[HID][20];
    int n0 = blockIdx.x * 16;
    int tx = threadIdx.x;

    for (int idx = tx; idx < 16 * IN_DIM; idx += 128) {
        int i = idx >> 6, k = idx & 63;
        s_feat[k][i] = H_t[(n0 + i) * IN_DIM + k];
    }
    for (int idx = tx; idx < 16 * HID; idx += 128) {
        int i = idx >> 7, k = idx & 127;
        s_feat[IN_DIM + k][i] = cond[(n0 + i) * HID + k];
    }
    const float cfr = -logf(10000.f) / 63.f;
    for (int idx = tx; idx < 16 * HID; idx += 128) {
        int i = idx >> 7, k = idx & 127;
        float tv = t_in[n0 + i];
        int jj = k & 63;
        float ang = tv * __expf(cfr * (float)jj);
        s_feat[IN_DIM + HID + k][i] = (k < 64) ? __sinf(ang) : __cosf(ang);
    }
    __syncthreads();

    float acc[16];
    {
        float bv = b0[tx];
        #pragma unroll
        for (int i = 0; i < 16; ++i) acc[i] = bv;
        for (int k = 0; k < D0; ++k) {
            float w = W0[k * HID + tx];
            float4 f0 = *(const float4*)&s_feat[k][0];
            float4 f1 = *(const float4*)&s_feat[k][4];
            float4 f2 = *(const float4*)&s_feat[k][8];
            float4 f3 = *(const float4*)&s_feat[k][12];
            acc[0] += f0.x*w; acc[1] += f0.y*w; acc[2] += f0.z*w; acc[3] += f0.w*w;
            acc[4] += f1.x*w; acc[5] += f1.y*w; acc[6] += f1.z*w; acc[7] += f1.w*w;
            acc[8] += f2.x*w; acc[9] += f2.y*w; acc[10]+= f2.z*w; acc[11]+= f2.w*w;
            acc[12]+= f3.x*w; acc[13]+= f3.y*w; acc[14]+= f3.z*w; acc[15]+= f3.w*w;
        }
        #pragma unroll
        for (int i = 0; i < 16; ++i) s_h0[tx][i] = fmaxf(acc[i], 0.f);
    }
    __syncthreads();
    {
        float bv = b1[tx];
        #pragma unroll
        for (int i = 0; i < 16; ++i) acc[i] = bv;
        for (int k = 0; k < HID; ++k) {
            float w = W1[k * HID + tx];
            float4 f0 = *(const float4*)&s_h0[k][0];
            float4 f1 = *(const float4*)&s_h0[k][4];
            float4 f2 = *(const float4*)&s_h0[k][8];
            float4 f3 = *(const float4*)&s_h0[k][12];
            acc[0] += f0.x*w; acc[1] += f0.y*w; acc[2] += f0.z*w; acc[3] += f0.w*w;
            acc[4] += f1.x*w; acc[5] += f1.y*w; acc[6] += f1.z*w; acc[7] += f1.w*w;
            acc[8] += f2.x*w; acc[9] += f2.y*w; acc[10]+= f2.z*w; acc[11]+= f2.w*w;
            acc[12]+= f3.x*w; acc[13]+= f3.y*w; acc[14]+= f3.z*w; acc[15]+= f3.w*w;
        }
        #pragma unroll
        for (int i = 0; i < 16; ++i) s_h1[tx][i] = fmaxf(acc[i], 0.f);
    }
    __syncthreads();
    {
        float bv = b2[tx];
        #pragma unroll
        for (int i = 0; i < 16; ++i) acc[i] = bv;
        for (int k = 0; k < HID; ++k) {
            float w = W2[k * HID + tx];
            float4 f0 = *(const float4*)&s_h1[k][0];
            float4 f1 = *(const float4*)&s_h1[k][4];
            float4 f2 = *(const float4*)&s_h1[k][8];
            float4 f3 = *(const float4*)&s_h1[k][12];
            acc[0] += f0.x*w; acc[1] += f0.y*w; acc[2] += f0.z*w; acc[3] += f0.w*w;
            acc[4] += f1.x*w; acc[5] += f1.y*w; acc[6] += f1.z*w; acc[7] += f1.w*w;
            acc[8] += f2.x*w; acc[9] += f2.y*w; acc[10]+= f2.z*w; acc[11]+= f2.w*w;
            acc[12]+= f3.x*w; acc[13]+= f3.y*w; acc[14]+= f3.z*w; acc[15]+= f3.w*w;
        }
        #pragma unroll
        for (int i = 0; i < 16; ++i) h[(n0 + i) * HID + tx] = acc[i];
    }
}

__global__ __launch_bounds__(256) void edge_gemm_fb_kernel(
    const float* __restrict__ h, const float* __restrict__ x,
    const int* __restrict__ edges, const int* __restrict__ etype,
    const float* __restrict__ edge_table,
    const float* __restrict__ We_l, const float* __restrict__ be_l,
    const float* __restrict__ Wx_l, const float* __restrict__ bx_l,
    float* __restrict__ agg_m, float* __restrict__ agg_x)
{
    __shared__ int s_src[TILE_E], s_dst[TILE_E];
    __shared__ float s_diff[TILE_E][3];
    __shared__ float s_tail[TILE_E][36];
    __shared__ float s_Af[TILE_E][36];
    __shared__ float s_Bf[33][HID];
    __shared__ float s_wx[HID];

    int e0 = blockIdx.x * TILE_E;
    int tx = threadIdx.x;
    int tf = tx & 15;
    int te = tx >> 4;

    if (tx < TILE_E) {
        int s = edges[e0 + tx];
        int d = edges[NE + e0 + tx];
        s_src[tx] = s; s_dst[tx] = d;
        float dx = x[s * 3 + 0] - x[d * 3 + 0];
        float dy = x[s * 3 + 1] - x[d * 3 + 1];
        float dz = x[s * 3 + 2] - x[d * 3 + 2];
        s_diff[tx][0] = dx; s_diff[tx][1] = dy; s_diff[tx][2] = dz;
        s_tail[tx][0] = dx * dx + dy * dy + dz * dz;
        int et = etype[e0 + tx];
        #pragma unroll
        for (int j = 0; j < 32; ++j) s_tail[tx][1 + j] = edge_table[et * 32 + j];
    }
    if (tx < HID) s_wx[tx] = Wx_l[tx];
    __syncthreads();

    float acc[4][8];
    #pragma unroll
    for (int i = 0; i < 4; ++i)
        #pragma unroll
        for (int j = 0; j < 8; ++j) acc[i][j] = 0.f;

    for (int t = 0; t < 9; ++t) {
        int k0 = t * 32;
        int klen = (t == 8) ? 33 : 32;
        __syncthreads();
        if (t < 8) {
            const bool use_src = (t < 4);
            int kbase = (t & 3) * 32;
            for (int q4 = tx; q4 < TILE_E * 8; q4 += 256) {
                int e = q4 >> 3, q = q4 & 7;
                int row = use_src ? s_src[e] : s_dst[e];
                float4 v = *(const float4*)&h[row * HID + kbase + q * 4];
                *(float4*)&s_Af[e][q * 4] = v;
            }
        }
        for (int q4 = tx; q4 < klen * 32; q4 += 256) {
            int kk = q4 >> 5, c4 = q4 & 31;
            float4 v = *(const float4*)&We_l[(k0 + kk) * HID + c4 * 4];
            *(float4*)&s_Bf[kk][c4 * 4] = v;
        }
        __syncthreads();
        const float (*Asrc)[36] = (t == 8) ? (const float (*)[36])s_tail
                                           : (const float (*)[36])s_Af;
        for (int kk = 0; kk < klen; ++kk) {
            float a0 = Asrc[te * 4 + 0][kk];
            float a1 = Asrc[te * 4 + 1][kk];
            float a2 = Asrc[te * 4 + 2][kk];
            float a3 = Asrc[te * 4 + 3][kk];
            float4 bv0 = *(const float4*)&s_Bf[kk][tf * 8];
            float4 bv1 = *(const float4*)&s_Bf[kk][tf * 8 + 4];
            float b[8] = {bv0.x, bv0.y, bv0.z, bv0.w, bv1.x, bv1.y, bv1.z, bv1.w};
            #pragma unroll
            for (int j = 0; j < 8; ++j) {
                acc[0][j] += a0 * b[j];
                acc[1][j] += a1 * b[j];
                acc[2][j] += a2 * b[j];
                acc[3][j] += a3 * b[j];
            }
        }
    }

    float wsum[4];
    #pragma unroll
    for (int i = 0; i < 4; ++i) {
        float p = 0.f;
        #pragma unroll
        for (int j = 0; j < 8; ++j) {
            int f = tf * 8 + j;
            float v = acc[i][j] + be_l[f];
            float m = silu(v);
            acc[i][j] = m;
            p += m * s_wx[f];
        }
        wsum[i] = p;
    }
    #pragma unroll
    for (int off = 1; off < 16; off <<= 1) {
        #pragma unroll
        for (int i = 0; i < 4; ++i) wsum[i] += __shfl_xor(wsum[i], off);
    }
    float bxv = bx_l[0];
    if (tf < 3) {
        #pragma unroll
        for (int i = 0; i < 4; ++i) {
            int e = te * 4 + i;
            float w2 = wsum[i] + bxv;
            atomicAdd(&agg_x[s_dst[e] * 3 + tf], s_diff[e][tf] * w2);
        }
    }
    #pragma unroll
    for (int i = 0; i < 4; ++i) {
        int d = s_dst[te * 4 + i];
        #pragma unroll
        for (int j = 0; j < 8; ++j)
            atomicAdd(&agg_m[d * HID + tf * 8 + j], acc[i][j]);
    }
}

__global__ __launch_bounds__(128) void node_update_fb_kernel(
    float* __restrict__ h, float* __restrict__ x,
    const float* __restrict__ agg_m, const float* __restrict__ agg_x,
    const float* __restrict__ cnt,
    const float* __restrict__ Wh_l, const float* __restrict__ bh_l)
{
    __shared__ float s_in[256][20];
    int n0 = blockIdx.x * 16;
    int tx = threadIdx.x;
    for (int idx = tx; idx < 16 * HID; idx += 128) {
        int i = idx >> 7, k = idx & 127;
        s_in[k][i] = h[(n0 + i) * HID + k];
    }
    for (int idx = tx; idx < 16 * HID; idx += 128) {
        int i = idx >> 7, k = idx & 127;
        s_in[HID + k][i] = agg_m[(n0 + i) * HID + k];
    }
    __syncthreads();
    float acc[16];
    float bv = bh_l[tx];
    #pragma unroll
    for (int i = 0; i < 16; ++i) acc[i] = bv;
    for (int k = 0; k < 256; ++k) {
        float w = Wh_l[k * HID + tx];
        float4 f0 = *(const float4*)&s_in[k][0];
        float4 f1 = *(const float4*)&s_in[k][4];
        float4 f2 = *(const float4*)&s_in[k][8];
        float4 f3 = *(const float4*)&s_in[k][12];
        acc[0] += f0.x*w; acc[1] += f0.y*w; acc[2] += f0.z*w; acc[3] += f0.w*w;
        acc[4] += f1.x*w; acc[5] += f1.y*w; acc[6] += f1.z*w; acc[7] += f1.w*w;
        acc[8] += f2.x*w; acc[9] += f2.y*w; acc[10]+= f2.z*w; acc[11]+= f2.w*w;
        acc[12]+= f3.x*w; acc[13]+= f3.y*w; acc[14]+= f3.z*w; acc[15]+= f3.w*w;
    }
    #pragma unroll
    for (int i = 0; i < 16; ++i) {
        float v = acc[i];
        h[(n0 + i) * HID + tx] = s_in[tx][i] + silu(v);
    }
    if (tx < 48) {
        int i = tx / 3, c = tx % 3;
        int n = n0 + i;
        x[n * 3 + c] += agg_x[n * 3 + c] / (cnt[n] + 1.f);
    }
}

__global__ __launch_bounds__(64) void final_fb_kernel(
    const float* __restrict__ h, const float* __restrict__ x,
    const int* __restrict__ gmask,
    const float* __restrict__ W, const float* __restrict__ b,
    float* __restrict__ out)
{
    __shared__ float s_h[8][HID];
    int n0 = blockIdx.x * 8;
    int tx = threadIdx.x;
    for (int idx = tx; idx < 8 * HID; idx += 64) {
        int i = idx >> 7, k = idx & 127;
        s_h[i][k] = h[(n0 + i) * HID + k];
    }
    __syncthreads();
    float acc[8];
    float bv = b[tx];
    #pragma unroll
    for (int i = 0; i < 8; ++i) acc[i] = bv;
    for (int k = 0; k < HID; ++k) {
        float w = W[k * IN_DIM + tx];
        #pragma unroll
        for (int i = 0; i < 8; ++i) acc[i] += s_h[i][k] * w;
    }
    #pragma unroll
    for (int i = 0; i < 8; ++i) {
        int n = n0 + i;
        out[n * IN_DIM + tx] = gmask[n] ? acc[i] : 0.f;
    }
    if (tx < 24) {
        int i = tx / 3, c = tx % 3;
        int n = n0 + i;
        out[NN * IN_DIM + n * 3 + c] = gmask[n] ? x[n * 3 + c] : 0.f;
    }
}

extern "C" void kernel_launch(void* const* d_in, const int* in_sizes, int n_in,
                              void* d_out, int out_size, void* d_ws, size_t ws_size,
                              hipStream_t stream) {
    const float* H_t   = (const float*)d_in[0];
    const float* X_t   = (const float*)d_in[1];
    const float* cond  = (const float*)d_in[2];
    const float* t_in  = (const float*)d_in[3];
    const int*   edges = (const int*)d_in[4];
    const int*   etype = (const int*)d_in[5];
    const int*   gmask = (const int*)d_in[6];
    const float* W0 = (const float*)d_in[8];
    const float* b0 = (const float*)d_in[9];
    const float* W1 = (const float*)d_in[10];
    const float* b1 = (const float*)d_in[11];
    const float* W2 = (const float*)d_in[12];
    const float* b2 = (const float*)d_in[13];
    const float* edge_table = (const float*)d_in[14];
    const float* We = (const float*)d_in[15];
    const float* be = (const float*)d_in[16];
    const float* Wx = (const float*)d_in[17];
    const float* bx = (const float*)d_in[18];
    const float* Wh = (const float*)d_in[19];
    const float* bh = (const float*)d_in[20];
    const float* h2i_W = (const float*)d_in[21];
    const float* h2i_b = (const float*)d_in[22];

    char* p = (char*)d_ws;
    float* h = (float*)p;           p += (size_t)NN * HID * 4;
    u16* h_bf = (u16*)p;            p += (size_t)NN * HID * 2;
    float* x = (float*)p;           p += (size_t)NN * 3 * 4;
    float* wdiff = (float*)p;       p += (size_t)NE * 3 * 4;
    u16* msg = (u16*)p;             p += (size_t)NE * HID * 2;
    u16* Bpack = (u16*)p;           p += (size_t)PACK_TOT * 2;
    float* tv = (float*)p;          p += (size_t)768 * 4;
    float* wed2 = (float*)p;        p += (size_t)384 * 4;
    int* row_start = (int*)p;       p += (size_t)(NN + 4) * 4;
    int* deg = (int*)p;             p += (size_t)NN * 4;
    int* head = (int*)p;            p += (size_t)NN * 4;
    int* src_s = (int*)p;           p += (size_t)NE * 4;
    int* dst_s = (int*)p;           p += (size_t)NE * 4;
    int* et_s = (int*)p;            p += (size_t)NE * 4;
    size_t need = (size_t)(p - (char*)d_ws);

    if (ws_size >= need) {
        hipMemsetAsync(deg, 0, NN * sizeof(int), stream);
        hist_kernel<<<256, 256, 0, stream>>>(X_t, edges, x, deg);
        scan_kernel<<<1, 256, 0, stream>>>(deg, row_start, head);
        scatter_kernel<<<256, 256, 0, stream>>>(edges, etype, head, src_s, dst_s, et_s);
        pack_all_kernel<<<(PACK_TOT + 255) / 256, 256, 0, stream>>>(
            We, W0, W1, W2, Wh, h2i_W, Bpack);
        precomp_tv_kernel<<<5, 256, 0, stream>>>(edge_table, We, be, tv, wed2);
        node_mlp_mfma_kernel<<<NB64, 256, 0, stream>>>(
            H_t, cond, t_in,
            Bpack + OFF_W0, b0, Bpack + OFF_W1, b1, Bpack + OFF_W2, b2,
            h, h_bf);
        for (int l = 0; l < 3; ++l) {
            edge_mfma_kernel<<<NE / ETE, 256, 0, stream>>>(
                h_bf, x, src_s, dst_s, et_s,
                Bpack + OFF_WE + (size_t)l * 40960,
                tv + (size_t)l * 256, wed2 + (size_t)l * 128,
                Wx + l * HID, bx + l, msg, wdiff);
            node_update_mfma_kernel<<<NN / NUB, 256, 0, stream>>>(
                h, h_bf, x, msg, wdiff, row_start,
                Bpack + OFF_WH + (size_t)l * 32768, bh + l * HID);
        }
        final_mfma_kernel<<<NB64, 256, 0, stream>>>(
            h_bf, x, gmask, Bpack + OFF_H2I, h2i_b, (float*)d_out);
    } else {
        // fallback: scalar atomic path (~21 MB)
        float* ws    = (float*)d_ws;
        float* fh    = ws;
        float* fx    = fh + NN * HID;
        float* cnt   = fx + NN * 3;
        float* agg_m = cnt + NN;
        float* agg_x = agg_m + NN * HID;

        hipMemsetAsync(cnt, 0, NN * sizeof(float), stream);
        init_fb_kernel<<<256, 256, 0, stream>>>(X_t, edges, fx, cnt);
        node_mlp_kernel<<<NN / 16, 128, 0, stream>>>(H_t, cond, t_in,
                                                     W0, b0, W1, b1, W2, b2, fh);
        for (int l = 0; l < 3; ++l) {
            hipMemsetAsync(agg_m, 0, (size_t)NN * 131 * sizeof(float), stream);
            edge_gemm_fb_kernel<<<NE / TILE_E, 256, 0, stream>>>(
                fh, fx, edges, etype, edge_table,
                We + (size_t)l * DE * HID, be + l * HID,
                Wx + l * HID, bx + l, agg_m, agg_x);
            node_update_fb_kernel<<<NN / 16, 128, 0, stream>>>(
                fh, fx, agg_m, agg_x, cnt,
                Wh + (size_t)l * 256 * HID, bh + l * HID);
        }
        final_fb_kernel<<<NN / 8, 64, 0, stream>>>(fh, fx, gmask, h2i_W, h2i_b, (float*)d_out);
    }
}